// Round 3
// baseline (880.025 us; speedup 1.0000x reference)
//
#include <hip/hip_runtime.h>
#include <hip/hip_bf16.h>

#define NN 50000
#define NE 800000
#define NET (NE + NN)
#define SCAN_NB ((NN + 255) / 256)   // 196

static inline int imin(int a, int b) { return a < b ? a : b; }

typedef _Float16 half8 __attribute__((ext_vector_type(8)));
typedef _Float16 half2v __attribute__((ext_vector_type(2)));
typedef float f32x4 __attribute__((ext_vector_type(4)));

// ---------------- CSR build (graph constant across layers) ----------------
__global__ void k_count(const int* __restrict__ edst, int* __restrict__ counts) {
    int e = blockIdx.x * blockDim.x + threadIdx.x;
    if (e >= NET) return;
    int d = (e < NE) ? edst[e] : (e - NE);   // self loops appended
    atomicAdd(&counts[d], 1);
}

__global__ __launch_bounds__(256) void k_scan1(const int* __restrict__ counts,
                                               int* __restrict__ part) {
    __shared__ int s[256];
    int t = threadIdx.x, i = blockIdx.x * 256 + t;
    s[t] = (i < NN) ? counts[i] : 0;
    __syncthreads();
    for (int off = 128; off > 0; off >>= 1) {
        if (t < off) s[t] += s[t + off];
        __syncthreads();
    }
    if (t == 0) part[blockIdx.x] = s[0];
}

__global__ __launch_bounds__(256) void k_scan2(int* __restrict__ part, int* __restrict__ offs) {
    __shared__ int s[256];
    int t = threadIdx.x;
    int v = (t < SCAN_NB) ? part[t] : 0;
    s[t] = v;
    __syncthreads();
    for (int off = 1; off < 256; off <<= 1) {
        int a = (t >= off) ? s[t - off] : 0;
        __syncthreads();
        s[t] += a;
        __syncthreads();
    }
    if (t < SCAN_NB) part[t] = s[t] - v;     // exclusive block offsets
    if (t == 255) offs[NN] = s[255];         // total (= NET)
}

__global__ __launch_bounds__(256) void k_scan3(const int* __restrict__ counts,
                                               const int* __restrict__ part,
                                               int* __restrict__ offs, int* __restrict__ cursor) {
    __shared__ int s[256];
    int t = threadIdx.x, i = blockIdx.x * 256 + t;
    int v = (i < NN) ? counts[i] : 0;
    s[t] = v;
    __syncthreads();
    for (int off = 1; off < 256; off <<= 1) {
        int a = (t >= off) ? s[t - off] : 0;
        __syncthreads();
        s[t] += a;
        __syncthreads();
    }
    if (i < NN) {
        int e = part[blockIdx.x] + s[t] - v;
        offs[i] = e;
        cursor[i] = e;
    }
}

__global__ void k_scatter(const int* __restrict__ esrc, const int* __restrict__ edst,
                          int* __restrict__ cursor, int* __restrict__ csr_src) {
    int e = blockIdx.x * blockDim.x + threadIdx.x;
    if (e >= NET) return;
    int s, d;
    if (e < NE) { s = esrc[e]; d = edst[e]; } else { s = e - NE; d = s; }
    int pos = atomicAdd(&cursor[d], 1);
    csr_src[pos] = s;
}

// ---------------- split fp32 -> f16 hi/lo pair ----------------
__global__ void k_split(const float* __restrict__ in, _Float16* __restrict__ hi,
                        _Float16* __restrict__ lo, int n) {
    int i = blockIdx.x * blockDim.x + threadIdx.x;
    int st = gridDim.x * blockDim.x;
    for (; i < n; i += st) {
        float v = in[i];
        _Float16 h = (_Float16)v;
        hi[i] = h;
        lo[i] = (_Float16)(v - (float)h);
    }
}

// ---------------- transpose + split weights: W[K][N] -> T[N][K] hi/lo (LDS-tiled) ----
__global__ __launch_bounds__(256) void k_prepw(const float* __restrict__ W,
                                               _Float16* __restrict__ Th,
                                               _Float16* __restrict__ Tl, int K, int N) {
    __shared__ float tile[32][33];
    int tx = threadIdx.x & 31, ty = threadIdx.x >> 5;
    int n0 = blockIdx.x * 32, k0 = blockIdx.y * 32;
    #pragma unroll
    for (int r = ty; r < 32; r += 8)
        tile[r][tx] = W[(size_t)(k0 + r) * N + n0 + tx];   // coalesced read
    __syncthreads();
    #pragma unroll
    for (int r = ty; r < 32; r += 8) {
        int n = n0 + r, k = k0 + tx;
        float v = tile[tx][r];
        _Float16 h = (_Float16)v;
        Th[(size_t)n * K + k] = h;                          // coalesced 64B segments
        Tl[(size_t)n * K + k] = (_Float16)(v - (float)h);
    }
}

// ---------------- per-node attention scalars: s = h . a ----------------
__global__ void k_scalars(const float* __restrict__ h, const float* __restrict__ a_src,
                          const float* __restrict__ a_dst, float* __restrict__ s_src,
                          float* __restrict__ s_dst) {
    int node = blockIdx.x * 4 + (threadIdx.x >> 6);
    int lane = threadIdx.x & 63;
    if (node >= NN) return;
    const float2* hr = (const float2*)(h + (size_t)node * 128) + lane;
    float2 hv = *hr;
    float2 as = *((const float2*)a_src + lane);
    float2 ad = *((const float2*)a_dst + lane);
    float ps = hv.x * as.x + hv.y * as.y;
    float pd = hv.x * ad.x + hv.y * ad.y;
    #pragma unroll
    for (int off = 32; off > 0; off >>= 1) {
        ps += __shfl_down(ps, off);
        pd += __shfl_down(pd, off);
    }
    if (lane == 0) { s_src[node] = ps; s_dst[node] = pd; }
}

// ---------------- fused segment-softmax + aggregate + bias + leaky ----------------
// 4-edge unroll (latency-bound gather); float2 per-lane row gather (1 load not 2).
__global__ void k_aggregate(const float* __restrict__ h, const float* __restrict__ s_src,
                            const float* __restrict__ s_dst, const int* __restrict__ offs,
                            const int* __restrict__ csr_src, const float* __restrict__ bias,
                            _Float16* __restrict__ xh, _Float16* __restrict__ xl) {
    int node = blockIdx.x * 4 + (threadIdx.x >> 6);
    int lane = threadIdx.x & 63;
    if (node >= NN) return;
    int p = offs[node], pe = offs[node + 1];
    float sd = s_dst[node];
    float den = 0.f, acc0 = 0.f, acc1 = 0.f;
    for (; p + 4 <= pe; p += 4) {
        int s0 = csr_src[p + 0], s1 = csr_src[p + 1];
        int s2 = csr_src[p + 2], s3 = csr_src[p + 3];
        float e0 = s_src[s0] + sd, e1 = s_src[s1] + sd;
        float e2 = s_src[s2] + sd, e3 = s_src[s3] + sd;
        float2 a0 = *((const float2*)(h + (size_t)s0 * 128) + lane);
        float2 a1 = *((const float2*)(h + (size_t)s1 * 128) + lane);
        float2 a2 = *((const float2*)(h + (size_t)s2 * 128) + lane);
        float2 a3 = *((const float2*)(h + (size_t)s3 * 128) + lane);
        e0 = (e0 > 0.f) ? e0 : 0.2f * e0;  float w0 = __expf(e0);
        e1 = (e1 > 0.f) ? e1 : 0.2f * e1;  float w1 = __expf(e1);
        e2 = (e2 > 0.f) ? e2 : 0.2f * e2;  float w2 = __expf(e2);
        e3 = (e3 > 0.f) ? e3 : 0.2f * e3;  float w3 = __expf(e3);
        den += (w0 + w1) + (w2 + w3);
        acc0 += w0 * a0.x + w1 * a1.x + w2 * a2.x + w3 * a3.x;
        acc1 += w0 * a0.y + w1 * a1.y + w2 * a2.y + w3 * a3.y;
    }
    for (; p < pe; ++p) {
        int src = csr_src[p];
        float e = s_src[src] + sd;
        e = (e > 0.f) ? e : 0.2f * e;
        float wgt = __expf(e);
        den += wgt;
        float2 av = *((const float2*)(h + (size_t)src * 128) + lane);
        acc0 += wgt * av.x;
        acc1 += wgt * av.y;
    }
    float inv = 1.f / den;                    // self-loop guarantees den > 0
    float2 bv = *((const float2*)bias + lane);
    float v0 = acc0 * inv + bv.x;
    float v1 = acc1 * inv + bv.y;
    v0 = (v0 > 0.f) ? v0 : 0.2f * v0;
    v1 = (v1 > 0.f) ? v1 : 0.2f * v1;
    _Float16 h0 = (_Float16)v0, h1 = (_Float16)v1;
    size_t base = (size_t)node * 128 + 2 * lane;
    *(half2v*)(xh + base) = (half2v){h0, h1};
    *(half2v*)(xl + base) = (half2v){(_Float16)(v0 - (float)h0), (_Float16)(v1 - (float)h1)};
}

// ---------------- split-f16 MFMA GEMM (128² tile + dbuf covered-prefetch) ----------
// C[M][N] = act(A[M][K] @ B^T[N][K] + bias), A,B as f16 hi/lo pairs,
// A·B ≈ Ahi·Bhi + Ahi·Blo + Alo·Bhi (fp32 MFMA accumulate).
// 128x128 tile, 4 waves (2x2), each wave 64x64 = 4x4 of 16x16x32 MFMA. BK=32.
// R14: double-buffered LDS + T3 "minimum 2-phase" schedule. R2 showed all
// single-buffer variants pin at 25% MfmaUtil: the 8 gload_lds + immediate
// __syncthreads exposes ~300cy of L2 latency in EVERY K-step (stage 32 +
// drain 300 + ds_read 192 + MFMA 233 cy -> 31% MFMA ceiling, matches 25%
// measured). Fix: issue STAGE(t+1) into buf^1 BEFORE computing buf t; the
// vmcnt(0) at step end then has ~430cy of ds_read+MFMA cover -> drain ~free.
// One raw s_barrier/step (vs 2 __syncthreads). Raw barrier is safe: all
// ds_reads are consumed by MFMAs before the barrier (compiler auto-lgkmcnt),
// and staging into buf^1 at iter t is guarded by iter t-1's end barrier.
// Cost: LDS 32->64KB = 2 blocks/CU (from 5). NOT a repeat of R1's 256²
// failure (1 blk/CU, 10 barriers/step, 512-thr lockstep); scaffolding
// (raw barrier + vmcnt asm + fences) ran correct on HW in R1/R2.
// XCD-aware 1D tile order: bid -> g=(bid&7)*per+(bid>>3), row-major tiles.
__device__ __forceinline__ void gload_lds16(const void* g, void* l) {
    __builtin_amdgcn_global_load_lds(
        (const __attribute__((address_space(1))) void*)g,
        (__attribute__((address_space(3))) void*)l, 16, 0, 0);
}

__global__ __launch_bounds__(256) void k_mgemm(
    const _Float16* __restrict__ Ahi, const _Float16* __restrict__ Alo,
    const _Float16* __restrict__ Bhi, const _Float16* __restrict__ Blo,
    const float* __restrict__ bias, float* __restrict__ Cf,
    _Float16* __restrict__ Chi, _Float16* __restrict__ Clo,
    int M, int N, int K, int relu, int split, int nx, int ntiles)
{
    __shared__ _Float16 sm[2][4][128][32];   // 64 KiB: dbuf x {Ahi,Alo,Bhi,Blo}

    int bid = blockIdx.x;
    int per = (ntiles + 7) >> 3;
    int g = (bid & 7) * per + (bid >> 3);
    if (g >= ntiles) return;
    int col0 = (g % nx) * 128;
    int row0 = (g / nx) * 128;

    int t = threadIdx.x;
    int w = t >> 6, lane = t & 63;
    int wm = (w & 1) * 64, wn = (w >> 1) * 64;
    int fr = lane & 15;
    int fq = lane >> 4, fq8 = fq * 8;

    // staging: wave w owns rows [w*32, w*32+32) of each array.
    // one gload_lds: lane l -> global (row base + (l>>2), 16B seg l&3);
    // HW writes LDS base + l*16 -> same (row, seg). 2 instr x 16 rows per array.
    int srow = (w << 5) + (lane >> 2);
    int scol = (lane & 3) << 3;          // halfs

    f32x4 acc[4][4];
    #pragma unroll
    for (int i = 0; i < 4; i++)
        #pragma unroll
        for (int j = 0; j < 4; j++) acc[i][j] = (f32x4){0.f, 0.f, 0.f, 0.f};

    auto STAGE = [&](int buf, int k0) {
        #pragma unroll
        for (int i = 0; i < 2; ++i) {
            int rr = srow + i * 16;
            int ga = row0 + rr; if (ga > M - 1) ga = M - 1;  // M-tail: dup reads, rows guarded in epilogue
            int gb = col0 + rr;                               // N % 128 == 0 -> in range
            int lrow = (w << 5) + i * 16;                     // wave-uniform LDS base row
            gload_lds16(Ahi + (size_t)ga * K + k0 + scol, &sm[buf][0][lrow][0]);
            gload_lds16(Alo + (size_t)ga * K + k0 + scol, &sm[buf][1][lrow][0]);
            gload_lds16(Bhi + (size_t)gb * K + k0 + scol, &sm[buf][2][lrow][0]);
            gload_lds16(Blo + (size_t)gb * K + k0 + scol, &sm[buf][3][lrow][0]);
        }
    };

    // prologue: stage step 0, drain, sync
    STAGE(0, 0);
    asm volatile("s_waitcnt vmcnt(0)" ::: "memory");
    __builtin_amdgcn_s_barrier();
    asm volatile("" ::: "memory");

    int NT = K >> 5;
    for (int tt = 0; tt < NT; ++tt) {
        int cur = tt & 1;
        // issue next-step staging FIRST: this step's ds_read+MFMA covers its latency
        if (tt + 1 < NT) STAGE(cur ^ 1, (tt + 1) << 5);
        asm volatile("" ::: "memory");

        half8 bh[4], bl[4];
        #pragma unroll
        for (int ni = 0; ni < 4; ++ni) {
            bh[ni] = *(half8*)&sm[cur][2][wn + ni * 16 + fr][fq8];
            bl[ni] = *(half8*)&sm[cur][3][wn + ni * 16 + fr][fq8];
        }
        #pragma unroll
        for (int mi = 0; mi < 4; ++mi) {
            half8 ah = *(half8*)&sm[cur][0][wm + mi * 16 + fr][fq8];
            half8 al = *(half8*)&sm[cur][1][wm + mi * 16 + fr][fq8];
            #pragma unroll
            for (int ni = 0; ni < 4; ++ni) {
                acc[mi][ni] = __builtin_amdgcn_mfma_f32_16x16x32_f16(ah, bh[ni], acc[mi][ni], 0, 0, 0);
                acc[mi][ni] = __builtin_amdgcn_mfma_f32_16x16x32_f16(ah, bl[ni], acc[mi][ni], 0, 0, 0);
                acc[mi][ni] = __builtin_amdgcn_mfma_f32_16x16x32_f16(al, bh[ni], acc[mi][ni], 0, 0, 0);
            }
        }

        // step boundary: next-step loads done (covered by the compute above);
        // barrier publishes LDS writes + guards buffer reuse. One barrier/step.
        asm volatile("s_waitcnt vmcnt(0)" ::: "memory");
        __builtin_amdgcn_s_barrier();
        asm volatile("" ::: "memory");
    }

    // epilogue: C/D layout col=lane&15, row=quad*4+reg
    #pragma unroll
    for (int ni = 0; ni < 4; ++ni) {
        int gc = col0 + wn + ni * 16 + fr;
        float bv = bias ? bias[gc] : 0.f;
        #pragma unroll
        for (int mi = 0; mi < 4; ++mi) {
            #pragma unroll
            for (int r = 0; r < 4; ++r) {
                int gr = row0 + wm + mi * 16 + fq * 4 + r;
                if (gr >= M) continue;
                float v = acc[mi][ni][r] + bv;
                if (relu) v = (v > 0.f) ? v : 0.f;
                size_t idx = (size_t)gr * N + gc;
                if (split) {
                    _Float16 hh = (_Float16)v;
                    Chi[idx] = hh;
                    Clo[idx] = (_Float16)(v - (float)hh);
                } else {
                    Cf[idx] = v;
                }
            }
        }
    }
}

// ---------------- head: out[M x 4] = (Yh+Yl)[M x 512] @ Wo[512 x 4] + bo ----------------
__global__ __launch_bounds__(256) void k_head(const _Float16* __restrict__ Yh,
                                              const _Float16* __restrict__ Yl,
                                              const float* __restrict__ Wo,
                                              const float* __restrict__ bo,
                                              float* __restrict__ out, int M) {
    int node = blockIdx.x * 4 + (threadIdx.x >> 6);
    int lane = threadIdx.x & 63;
    if (node >= M) return;
    size_t base = (size_t)node * 512 + lane * 8;
    half8 hv = *(const half8*)(Yh + base);
    half8 lv = *(const half8*)(Yl + base);
    float a0 = 0.f, a1 = 0.f, a2 = 0.f, a3 = 0.f;
    #pragma unroll
    for (int i = 0; i < 8; i++) {
        float y = (float)hv[i] + (float)lv[i];
        float4 wv = *(const float4*)(Wo + (size_t)(lane * 8 + i) * 4);
        a0 += y * wv.x; a1 += y * wv.y;
        a2 += y * wv.z; a3 += y * wv.w;
    }
    #pragma unroll
    for (int off = 32; off > 0; off >>= 1) {
        a0 += __shfl_down(a0, off);
        a1 += __shfl_down(a1, off);
        a2 += __shfl_down(a2, off);
        a3 += __shfl_down(a3, off);
    }
    if (lane == 0) {
        float4 o;
        o.x = a0 + bo[0]; o.y = a1 + bo[1]; o.z = a2 + bo[2]; o.w = a3 + bo[3];
        *(float4*)(out + (size_t)node * 4) = o;
    }
}

extern "C" void kernel_launch(void* const* d_in, const int* in_sizes, int n_in,
                              void* d_out, int out_size, void* d_ws, size_t ws_size,
                              hipStream_t stream) {
    const float* x    = (const float*)d_in[0];
    const int*   eidx = (const int*)d_in[1];
    const float* cW   = (const float*)d_in[2];
    const float* caS  = (const float*)d_in[3];
    const float* caD  = (const float*)d_in[4];
    const float* cB   = (const float*)d_in[5];
    const float* W0   = (const float*)d_in[6];
    const float* b0   = (const float*)d_in[7];
    const float* W1   = (const float*)d_in[8];
    const float* b1   = (const float*)d_in[9];
    const float* W2   = (const float*)d_in[10];
    const float* b2   = (const float*)d_in[11];
    const float* Wo   = (const float*)d_in[12];
    const float* bo   = (const float*)d_in[13];
    (void)in_sizes; (void)n_in; (void)out_size;

    const int* esrc = eidx;
    const int* edst = eidx + NE;
    float* out = (float*)d_out;

    // ---- workspace bump allocator (256B aligned) ----
    char* w = (char*)d_ws;
    auto alloc = [&](size_t bytes) -> char* {
        char* p = w;
        w += (bytes + 255) & ~(size_t)255;
        return p;
    };
    _Float16* x0h  = (_Float16*)alloc((size_t)NN * 128 * 2);
    _Float16* x0l  = (_Float16*)alloc((size_t)NN * 128 * 2);
    _Float16* xh   = (_Float16*)alloc((size_t)NN * 128 * 2);
    _Float16* xl   = (_Float16*)alloc((size_t)NN * 128 * 2);
    float* hbuf    = (float*)alloc((size_t)NN * 128 * 4);
    float* ssrc    = (float*)alloc((size_t)NN * 4);
    float* sdst    = (float*)alloc((size_t)NN * 4);
    int*   counts  = (int*)  alloc((size_t)NN * 4);
    int*   offs    = (int*)  alloc((size_t)(NN + 1) * 4);
    int*   cursor  = (int*)  alloc((size_t)NN * 4);
    int*   csr     = (int*)  alloc((size_t)NET * 4);
    int*   part    = (int*)  alloc((size_t)SCAN_NB * 4);
    _Float16* cwh  = (_Float16*)alloc(3 * 128 * 128 * 2);
    _Float16* cwl  = (_Float16*)alloc(3 * 128 * 128 * 2);
    _Float16* w0h  = (_Float16*)alloc(512 * 128 * 2);
    _Float16* w0l  = (_Float16*)alloc(512 * 128 * 2);
    _Float16* w1h  = (_Float16*)alloc(512 * 512 * 2);
    _Float16* w1l  = (_Float16*)alloc(512 * 512 * 2);
    _Float16* w2h  = (_Float16*)alloc(512 * 512 * 2);
    _Float16* w2l  = (_Float16*)alloc(512 * 512 * 2);

    size_t used = (size_t)(w - (char*)d_ws);
    size_t rem = (ws_size > used) ? (ws_size - used) : 0;
    int chunk = (int)(rem / (4 * 512 * sizeof(_Float16)));
    if (chunk > NN) chunk = NN;
    if (chunk > 128) chunk &= ~127;
    if (chunk < 1) chunk = 1;
    _Float16* Y0h = (_Float16*)alloc((size_t)chunk * 512 * 2);
    _Float16* Y0l = (_Float16*)alloc((size_t)chunk * 512 * 2);
    _Float16* Y1h = (_Float16*)alloc((size_t)chunk * 512 * 2);
    _Float16* Y1l = (_Float16*)alloc((size_t)chunk * 512 * 2);

    auto gemm = [&](const _Float16* Ah, const _Float16* Al,
                    const _Float16* Bh, const _Float16* Bl,
                    const float* bias, float* Cf, _Float16* Ch, _Float16* Cl,
                    int M, int N, int K, int relu, int split) {
        int nx = N / 128;
        int ntiles = nx * ((M + 127) / 128);
        int nb = ((ntiles + 7) / 8) * 8;
        k_mgemm<<<nb, 256, 0, stream>>>(Ah, Al, Bh, Bl, bias, Cf, Ch, Cl,
                                        M, N, K, relu, split, nx, ntiles);
    };

    // ---- prep: split x, transpose+split weights ----
    k_split<<<2048, 256, 0, stream>>>(x, x0h, x0l, NN * 128);
    for (int L = 0; L < 3; ++L)
        k_prepw<<<dim3(128 / 32, 128 / 32), 256, 0, stream>>>(
            cW + (size_t)L * 128 * 128, cwh + (size_t)L * 128 * 128, cwl + (size_t)L * 128 * 128, 128, 128);
    k_prepw<<<dim3(512 / 32, 128 / 32), 256, 0, stream>>>(W0, w0h, w0l, 128, 512);
    k_prepw<<<dim3(512 / 32, 512 / 32), 256, 0, stream>>>(W1, w1h, w1l, 512, 512);
    k_prepw<<<dim3(512 / 32, 512 / 32), 256, 0, stream>>>(W2, w2h, w2l, 512, 512);

    // ---- build CSR once ----
    hipMemsetAsync(counts, 0, (size_t)NN * 4, stream);
    int eblocks = (NET + 255) / 256;
    k_count <<<eblocks, 256, 0, stream>>>(edst, counts);
    k_scan1 <<<SCAN_NB, 256, 0, stream>>>(counts, part);
    k_scan2 <<<1, 256, 0, stream>>>(part, offs);
    k_scan3 <<<SCAN_NB, 256, 0, stream>>>(counts, part, offs, cursor);
    k_scatter<<<eblocks, 256, 0, stream>>>(esrc, edst, cursor, csr);

    // ---- 3 GAT layers ----
    for (int L = 0; L < 3; ++L) {
        const _Float16* Ah = (L == 0) ? x0h : xh;
        const _Float16* Al = (L == 0) ? x0l : xl;
        gemm(Ah, Al, cwh + (size_t)L * 128 * 128, cwl + (size_t)L * 128 * 128,
             nullptr, hbuf, nullptr, nullptr, NN, 128, 128, 0, 0);
        k_scalars  <<<NN / 4, 256, 0, stream>>>(hbuf, caS + L * 128, caD + L * 128, ssrc, sdst);
        k_aggregate<<<NN / 4, 256, 0, stream>>>(hbuf, ssrc, sdst, offs, csr, cB + L * 128, xh, xl);
    }

    // ---- MLP head (chunked over nodes) ----
    for (int m0 = 0; m0 < NN; m0 += chunk) {
        int cm = imin(chunk, NN - m0);
        gemm(xh + (size_t)m0 * 128, xl + (size_t)m0 * 128, w0h, w0l, b0,
             nullptr, Y0h, Y0l, cm, 512, 128, 1, 1);
        gemm(Y0h, Y0l, w1h, w1l, b1, nullptr, Y1h, Y1l, cm, 512, 512, 1, 1);
        gemm(Y1h, Y1l, w2h, w2l, b2, nullptr, Y0h, Y0l, cm, 512, 512, 1, 1);
        k_head<<<(cm + 3) / 4, 256, 0, stream>>>(Y0h, Y0l, Wo, bo, out + (size_t)m0 * 4, cm);
    }
}

// Round 4
// 843.756 us; speedup vs baseline: 1.0430x; 1.0430x over previous
//
#include <hip/hip_runtime.h>
#include <hip/hip_bf16.h>

#define NN 50000
#define NE 800000
#define NET (NE + NN)
#define SCAN_NB ((NN + 255) / 256)   // 196

static inline int imin(int a, int b) { return a < b ? a : b; }

typedef _Float16 half8 __attribute__((ext_vector_type(8)));
typedef _Float16 half2v __attribute__((ext_vector_type(2)));
typedef float f32x4 __attribute__((ext_vector_type(4)));

// ---------------- CSR build (graph constant across layers) ----------------
__global__ void k_count(const int* __restrict__ edst, int* __restrict__ counts) {
    int e = blockIdx.x * blockDim.x + threadIdx.x;
    if (e >= NET) return;
    int d = (e < NE) ? edst[e] : (e - NE);   // self loops appended
    atomicAdd(&counts[d], 1);
}

__global__ __launch_bounds__(256) void k_scan1(const int* __restrict__ counts,
                                               int* __restrict__ part) {
    __shared__ int s[256];
    int t = threadIdx.x, i = blockIdx.x * 256 + t;
    s[t] = (i < NN) ? counts[i] : 0;
    __syncthreads();
    for (int off = 128; off > 0; off >>= 1) {
        if (t < off) s[t] += s[t + off];
        __syncthreads();
    }
    if (t == 0) part[blockIdx.x] = s[0];
}

__global__ __launch_bounds__(256) void k_scan2(int* __restrict__ part, int* __restrict__ offs) {
    __shared__ int s[256];
    int t = threadIdx.x;
    int v = (t < SCAN_NB) ? part[t] : 0;
    s[t] = v;
    __syncthreads();
    for (int off = 1; off < 256; off <<= 1) {
        int a = (t >= off) ? s[t - off] : 0;
        __syncthreads();
        s[t] += a;
        __syncthreads();
    }
    if (t < SCAN_NB) part[t] = s[t] - v;     // exclusive block offsets
    if (t == 255) offs[NN] = s[255];         // total (= NET)
}

__global__ __launch_bounds__(256) void k_scan3(const int* __restrict__ counts,
                                               const int* __restrict__ part,
                                               int* __restrict__ offs, int* __restrict__ cursor) {
    __shared__ int s[256];
    int t = threadIdx.x, i = blockIdx.x * 256 + t;
    int v = (i < NN) ? counts[i] : 0;
    s[t] = v;
    __syncthreads();
    for (int off = 1; off < 256; off <<= 1) {
        int a = (t >= off) ? s[t - off] : 0;
        __syncthreads();
        s[t] += a;
        __syncthreads();
    }
    if (i < NN) {
        int e = part[blockIdx.x] + s[t] - v;
        offs[i] = e;
        cursor[i] = e;
    }
}

__global__ void k_scatter(const int* __restrict__ esrc, const int* __restrict__ edst,
                          int* __restrict__ cursor, int* __restrict__ csr_src) {
    int e = blockIdx.x * blockDim.x + threadIdx.x;
    if (e >= NET) return;
    int s, d;
    if (e < NE) { s = esrc[e]; d = edst[e]; } else { s = e - NE; d = s; }
    int pos = atomicAdd(&cursor[d], 1);
    csr_src[pos] = s;
}

// ---------------- split fp32 -> f16 hi/lo pair ----------------
__global__ void k_split(const float* __restrict__ in, _Float16* __restrict__ hi,
                        _Float16* __restrict__ lo, int n) {
    int i = blockIdx.x * blockDim.x + threadIdx.x;
    int st = gridDim.x * blockDim.x;
    for (; i < n; i += st) {
        float v = in[i];
        _Float16 h = (_Float16)v;
        hi[i] = h;
        lo[i] = (_Float16)(v - (float)h);
    }
}

// ---------------- transpose + split weights: W[K][N] -> T[N][K] hi/lo (LDS-tiled) ----
__global__ __launch_bounds__(256) void k_prepw(const float* __restrict__ W,
                                               _Float16* __restrict__ Th,
                                               _Float16* __restrict__ Tl, int K, int N) {
    __shared__ float tile[32][33];
    int tx = threadIdx.x & 31, ty = threadIdx.x >> 5;
    int n0 = blockIdx.x * 32, k0 = blockIdx.y * 32;
    #pragma unroll
    for (int r = ty; r < 32; r += 8)
        tile[r][tx] = W[(size_t)(k0 + r) * N + n0 + tx];   // coalesced read
    __syncthreads();
    #pragma unroll
    for (int r = ty; r < 32; r += 8) {
        int n = n0 + r, k = k0 + tx;
        float v = tile[tx][r];
        _Float16 h = (_Float16)v;
        Th[(size_t)n * K + k] = h;                          // coalesced 64B segments
        Tl[(size_t)n * K + k] = (_Float16)(v - (float)h);
    }
}

// ---------------- fused segment-softmax + aggregate + bias + leaky ----------------
// 4-edge unroll (latency-bound gather); float2 per-lane row gather (1 load not 2).
__global__ void k_aggregate(const float* __restrict__ h, const float* __restrict__ s_src,
                            const float* __restrict__ s_dst, const int* __restrict__ offs,
                            const int* __restrict__ csr_src, const float* __restrict__ bias,
                            _Float16* __restrict__ xh, _Float16* __restrict__ xl) {
    int node = blockIdx.x * 4 + (threadIdx.x >> 6);
    int lane = threadIdx.x & 63;
    if (node >= NN) return;
    int p = offs[node], pe = offs[node + 1];
    float sd = s_dst[node];
    float den = 0.f, acc0 = 0.f, acc1 = 0.f;
    for (; p + 4 <= pe; p += 4) {
        int s0 = csr_src[p + 0], s1 = csr_src[p + 1];
        int s2 = csr_src[p + 2], s3 = csr_src[p + 3];
        float e0 = s_src[s0] + sd, e1 = s_src[s1] + sd;
        float e2 = s_src[s2] + sd, e3 = s_src[s3] + sd;
        float2 a0 = *((const float2*)(h + (size_t)s0 * 128) + lane);
        float2 a1 = *((const float2*)(h + (size_t)s1 * 128) + lane);
        float2 a2 = *((const float2*)(h + (size_t)s2 * 128) + lane);
        float2 a3 = *((const float2*)(h + (size_t)s3 * 128) + lane);
        e0 = (e0 > 0.f) ? e0 : 0.2f * e0;  float w0 = __expf(e0);
        e1 = (e1 > 0.f) ? e1 : 0.2f * e1;  float w1 = __expf(e1);
        e2 = (e2 > 0.f) ? e2 : 0.2f * e2;  float w2 = __expf(e2);
        e3 = (e3 > 0.f) ? e3 : 0.2f * e3;  float w3 = __expf(e3);
        den += (w0 + w1) + (w2 + w3);
        acc0 += w0 * a0.x + w1 * a1.x + w2 * a2.x + w3 * a3.x;
        acc1 += w0 * a0.y + w1 * a1.y + w2 * a2.y + w3 * a3.y;
    }
    for (; p < pe; ++p) {
        int src = csr_src[p];
        float e = s_src[src] + sd;
        e = (e > 0.f) ? e : 0.2f * e;
        float wgt = __expf(e);
        den += wgt;
        float2 av = *((const float2*)(h + (size_t)src * 128) + lane);
        acc0 += wgt * av.x;
        acc1 += wgt * av.y;
    }
    float inv = 1.f / den;                    // self-loop guarantees den > 0
    float2 bv = *((const float2*)bias + lane);
    float v0 = acc0 * inv + bv.x;
    float v1 = acc1 * inv + bv.y;
    v0 = (v0 > 0.f) ? v0 : 0.2f * v0;
    v1 = (v1 > 0.f) ? v1 : 0.2f * v1;
    _Float16 h0 = (_Float16)v0, h1 = (_Float16)v1;
    size_t base = (size_t)node * 128 + 2 * lane;
    *(half2v*)(xh + base) = (half2v){h0, h1};
    *(half2v*)(xl + base) = (half2v){(_Float16)(v0 - (float)h0), (_Float16)(v1 - (float)h1)};
}

// ---------------- shared GEMM machinery (R2 structure — measured best, 870 µs wall) ----
// 128x128 tile, 4 waves (2x2), each wave 64x64 = 4x4 of 16x16x32 MFMA. BK=32.
// Single-buffer LDS [4][128][32] + gload_lds width=16 staging; 2 __syncthreads
// per K-step. R3's explicit dbuf REGRESSED (125µs, WRITE 2x, 40ms outlier):
// cross-block implicit overlap at 32KB LDS beats intra-block pipelining at
// 64KB (replicates learn_hip m99/m100 null). This K-loop is the structural
// local optimum for this shape — do not touch; optimize around it.
__device__ __forceinline__ void gload_lds16(const void* g, void* l) {
    __builtin_amdgcn_global_load_lds(
        (const __attribute__((address_space(1))) void*)g,
        (__attribute__((address_space(3))) void*)l, 16, 0, 0);
}

// ---------------- generic split-f16 MFMA GEMM (gemm0/gemm1: relu+split out) ----
__global__ __launch_bounds__(256) void k_mgemm(
    const _Float16* __restrict__ Ahi, const _Float16* __restrict__ Alo,
    const _Float16* __restrict__ Bhi, const _Float16* __restrict__ Blo,
    const float* __restrict__ bias, float* __restrict__ Cf,
    _Float16* __restrict__ Chi, _Float16* __restrict__ Clo,
    int M, int N, int K, int relu, int split, int nx, int ntiles)
{
    __shared__ _Float16 sm[4][128][32];   // 32 KiB: Ahi, Alo, Bhi, Blo

    int bid = blockIdx.x;
    int per = (ntiles + 7) >> 3;
    int g = (bid & 7) * per + (bid >> 3);
    if (g >= ntiles) return;
    int col0 = (g % nx) * 128;
    int row0 = (g / nx) * 128;

    int t = threadIdx.x;
    int w = t >> 6, lane = t & 63;
    int wm = (w & 1) * 64, wn = (w >> 1) * 64;
    int fr = lane & 15;
    int fq = lane >> 4, fq8 = fq * 8;

    int srow = (w << 5) + (lane >> 2);
    int scol = (lane & 3) << 3;          // halfs

    f32x4 acc[4][4];
    #pragma unroll
    for (int i = 0; i < 4; i++)
        #pragma unroll
        for (int j = 0; j < 4; j++) acc[i][j] = (f32x4){0.f, 0.f, 0.f, 0.f};

    for (int k0 = 0; k0 < K; k0 += 32) {
        if (k0) __syncthreads();
        #pragma unroll
        for (int i = 0; i < 2; ++i) {
            int rr = srow + i * 16;
            int ga = row0 + rr; if (ga > M - 1) ga = M - 1;  // M-tail: dup reads, rows guarded in epilogue
            int gb = col0 + rr;                               // N % 128 == 0 -> in range
            int lrow = (w << 5) + i * 16;                     // wave-uniform LDS base row
            gload_lds16(Ahi + (size_t)ga * K + k0 + scol, &sm[0][lrow][0]);
            gload_lds16(Alo + (size_t)ga * K + k0 + scol, &sm[1][lrow][0]);
            gload_lds16(Bhi + (size_t)gb * K + k0 + scol, &sm[2][lrow][0]);
            gload_lds16(Blo + (size_t)gb * K + k0 + scol, &sm[3][lrow][0]);
        }
        __syncthreads();   // drains vmcnt -> gload_lds stores visible to all waves

        half8 bh[4], bl[4];
        #pragma unroll
        for (int ni = 0; ni < 4; ++ni) {
            bh[ni] = *(half8*)&sm[2][wn + ni * 16 + fr][fq8];
            bl[ni] = *(half8*)&sm[3][wn + ni * 16 + fr][fq8];
        }
        #pragma unroll
        for (int mi = 0; mi < 4; ++mi) {
            half8 ah = *(half8*)&sm[0][wm + mi * 16 + fr][fq8];
            half8 al = *(half8*)&sm[1][wm + mi * 16 + fr][fq8];
            #pragma unroll
            for (int ni = 0; ni < 4; ++ni) {
                acc[mi][ni] = __builtin_amdgcn_mfma_f32_16x16x32_f16(ah, bh[ni], acc[mi][ni], 0, 0, 0);
                acc[mi][ni] = __builtin_amdgcn_mfma_f32_16x16x32_f16(ah, bl[ni], acc[mi][ni], 0, 0, 0);
                acc[mi][ni] = __builtin_amdgcn_mfma_f32_16x16x32_f16(al, bh[ni], acc[mi][ni], 0, 0, 0);
            }
        }
    }

    // epilogue: C/D layout col=lane&15, row=quad*4+reg
    #pragma unroll
    for (int ni = 0; ni < 4; ++ni) {
        int gc = col0 + wn + ni * 16 + fr;
        float bv = bias ? bias[gc] : 0.f;
        #pragma unroll
        for (int mi = 0; mi < 4; ++mi) {
            #pragma unroll
            for (int r = 0; r < 4; ++r) {
                int gr = row0 + wm + mi * 16 + fq * 4 + r;
                if (gr >= M) continue;
                float v = acc[mi][ni][r] + bv;
                if (relu) v = (v > 0.f) ? v : 0.f;
                size_t idx = (size_t)gr * N + gc;
                if (split) {
                    _Float16 hh = (_Float16)v;
                    Chi[idx] = hh;
                    Clo[idx] = (_Float16)(v - (float)hh);
                } else {
                    Cf[idx] = v;
                }
            }
        }
    }
}

// ---------------- GAT GEMM fused with attention scalars (N=K=128) ----------------
// R15: each block holds complete 128-wide rows of h=x@W in registers, so
// s_src[r]=h[r]·a_src and s_dst[r]=h[r]·a_dst are computed in the epilogue:
// 4 FMA/lane + 16-lane shfl_xor reduce + cross-wave LDS combine. Removes the
// separate k_scalars kernel (3 launches + 3x25.6MB hbuf re-reads).
__global__ __launch_bounds__(256) void k_mgemm_gat(
    const _Float16* __restrict__ Ahi, const _Float16* __restrict__ Alo,
    const _Float16* __restrict__ Bhi, const _Float16* __restrict__ Blo,
    const float* __restrict__ a_src, const float* __restrict__ a_dst,
    float* __restrict__ hbuf, float* __restrict__ s_src, float* __restrict__ s_dst,
    int M, int ntiles)
{
    __shared__ _Float16 sm[4][128][32];   // 32 KiB
    __shared__ float sps[2][128], spd[2][128];

    const int K = 128;
    int bid = blockIdx.x;
    int per = (ntiles + 7) >> 3;
    int g = (bid & 7) * per + (bid >> 3);
    if (g >= ntiles) return;
    int row0 = g * 128;                    // nx == 1 (N = 128)

    int t = threadIdx.x;
    int w = t >> 6, lane = t & 63;
    int wm = (w & 1) * 64, wn = (w >> 1) * 64;
    int fr = lane & 15;
    int fq = lane >> 4, fq8 = fq * 8;
    int wnIdx = w >> 1;

    int srow = (w << 5) + (lane >> 2);
    int scol = (lane & 3) << 3;

    f32x4 acc[4][4];
    #pragma unroll
    for (int i = 0; i < 4; i++)
        #pragma unroll
        for (int j = 0; j < 4; j++) acc[i][j] = (f32x4){0.f, 0.f, 0.f, 0.f};

    for (int k0 = 0; k0 < K; k0 += 32) {
        if (k0) __syncthreads();
        #pragma unroll
        for (int i = 0; i < 2; ++i) {
            int rr = srow + i * 16;
            int ga = row0 + rr; if (ga > M - 1) ga = M - 1;
            int gb = rr;                                      // col0 = 0, N = 128
            int lrow = (w << 5) + i * 16;
            gload_lds16(Ahi + (size_t)ga * K + k0 + scol, &sm[0][lrow][0]);
            gload_lds16(Alo + (size_t)ga * K + k0 + scol, &sm[1][lrow][0]);
            gload_lds16(Bhi + (size_t)gb * K + k0 + scol, &sm[2][lrow][0]);
            gload_lds16(Blo + (size_t)gb * K + k0 + scol, &sm[3][lrow][0]);
        }
        __syncthreads();

        half8 bh[4], bl[4];
        #pragma unroll
        for (int ni = 0; ni < 4; ++ni) {
            bh[ni] = *(half8*)&sm[2][wn + ni * 16 + fr][fq8];
            bl[ni] = *(half8*)&sm[3][wn + ni * 16 + fr][fq8];
        }
        #pragma unroll
        for (int mi = 0; mi < 4; ++mi) {
            half8 ah = *(half8*)&sm[0][wm + mi * 16 + fr][fq8];
            half8 al = *(half8*)&sm[1][wm + mi * 16 + fr][fq8];
            #pragma unroll
            for (int ni = 0; ni < 4; ++ni) {
                acc[mi][ni] = __builtin_amdgcn_mfma_f32_16x16x32_f16(ah, bh[ni], acc[mi][ni], 0, 0, 0);
                acc[mi][ni] = __builtin_amdgcn_mfma_f32_16x16x32_f16(ah, bl[ni], acc[mi][ni], 0, 0, 0);
                acc[mi][ni] = __builtin_amdgcn_mfma_f32_16x16x32_f16(al, bh[ni], acc[mi][ni], 0, 0, 0);
            }
        }
    }

    // epilogue: write hbuf (fp32) + fused attention scalar dots
    float asv[4], adv[4];
    #pragma unroll
    for (int ni = 0; ni < 4; ++ni) {
        int gc = wn + ni * 16 + fr;
        asv[ni] = a_src[gc];
        adv[ni] = a_dst[gc];
    }
    #pragma unroll
    for (int mi = 0; mi < 4; ++mi) {
        #pragma unroll
        for (int r = 0; r < 4; ++r) {
            int lrow = wm + mi * 16 + fq * 4 + r;
            int gr = row0 + lrow;
            float vps = 0.f, vpd = 0.f;
            #pragma unroll
            for (int ni = 0; ni < 4; ++ni) {
                float v = acc[mi][ni][r];
                vps += v * asv[ni];
                vpd += v * adv[ni];
                if (gr < M) hbuf[(size_t)gr * 128 + wn + ni * 16 + fr] = v;
            }
            // reduce over 16 fr lanes (xor < 16 stays within quad group)
            #pragma unroll
            for (int off = 1; off < 16; off <<= 1) {
                vps += __shfl_xor(vps, off);
                vpd += __shfl_xor(vpd, off);
            }
            if (fr == 0) { sps[wnIdx][lrow] = vps; spd[wnIdx][lrow] = vpd; }
        }
    }
    __syncthreads();
    if (t < 128) {
        int gr = row0 + t;
        if (gr < M) {
            s_src[gr] = sps[0][t] + sps[1][t];
            s_dst[gr] = spd[0][t] + spd[1][t];
        }
    }
}

// ---------------- gemm2 fused with MLP head (N=512, out[M x 4] atomically) --------
// R15: Y2 = relu(Y1@W2+b2) existed ONLY to be re-read by k_head (102MB write +
// 102MB read). Fuse: per lane v=relu(acc+b2[gc]); o_j += v*Wo[gc][j]; 16-lane
// shfl_xor reduce; fr==0 lane atomicAdds 4 floats per row per col-tile
// (~800k atomics, k_count-scale). bo added by the (col0==0,wn==0) contribution
// exactly once per row. out must be zeroed before launch.
__global__ __launch_bounds__(256) void k_mgemm_head(
    const _Float16* __restrict__ Ahi, const _Float16* __restrict__ Alo,
    const _Float16* __restrict__ Bhi, const _Float16* __restrict__ Blo,
    const float* __restrict__ bias, const float* __restrict__ Wo,
    const float* __restrict__ bo, float* __restrict__ out,
    int M, int K, int nx, int ntiles)
{
    __shared__ _Float16 sm[4][128][32];   // 32 KiB

    int bid = blockIdx.x;
    int per = (ntiles + 7) >> 3;
    int g = (bid & 7) * per + (bid >> 3);
    if (g >= ntiles) return;
    int col0 = (g % nx) * 128;
    int row0 = (g / nx) * 128;

    int t = threadIdx.x;
    int w = t >> 6, lane = t & 63;
    int wm = (w & 1) * 64, wn = (w >> 1) * 64;
    int fr = lane & 15;
    int fq = lane >> 4, fq8 = fq * 8;

    int srow = (w << 5) + (lane >> 2);
    int scol = (lane & 3) << 3;

    f32x4 acc[4][4];
    #pragma unroll
    for (int i = 0; i < 4; i++)
        #pragma unroll
        for (int j = 0; j < 4; j++) acc[i][j] = (f32x4){0.f, 0.f, 0.f, 0.f};

    for (int k0 = 0; k0 < K; k0 += 32) {
        if (k0) __syncthreads();
        #pragma unroll
        for (int i = 0; i < 2; ++i) {
            int rr = srow + i * 16;
            int ga = row0 + rr; if (ga > M - 1) ga = M - 1;
            int gb = col0 + rr;
            int lrow = (w << 5) + i * 16;
            gload_lds16(Ahi + (size_t)ga * K + k0 + scol, &sm[0][lrow][0]);
            gload_lds16(Alo + (size_t)ga * K + k0 + scol, &sm[1][lrow][0]);
            gload_lds16(Bhi + (size_t)gb * K + k0 + scol, &sm[2][lrow][0]);
            gload_lds16(Blo + (size_t)gb * K + k0 + scol, &sm[3][lrow][0]);
        }
        __syncthreads();

        half8 bh[4], bl[4];
        #pragma unroll
        for (int ni = 0; ni < 4; ++ni) {
            bh[ni] = *(half8*)&sm[2][wn + ni * 16 + fr][fq8];
            bl[ni] = *(half8*)&sm[3][wn + ni * 16 + fr][fq8];
        }
        #pragma unroll
        for (int mi = 0; mi < 4; ++mi) {
            half8 ah = *(half8*)&sm[0][wm + mi * 16 + fr][fq8];
            half8 al = *(half8*)&sm[1][wm + mi * 16 + fr][fq8];
            #pragma unroll
            for (int ni = 0; ni < 4; ++ni) {
                acc[mi][ni] = __builtin_amdgcn_mfma_f32_16x16x32_f16(ah, bh[ni], acc[mi][ni], 0, 0, 0);
                acc[mi][ni] = __builtin_amdgcn_mfma_f32_16x16x32_f16(ah, bl[ni], acc[mi][ni], 0, 0, 0);
                acc[mi][ni] = __builtin_amdgcn_mfma_f32_16x16x32_f16(al, bh[ni], acc[mi][ni], 0, 0, 0);
            }
        }
    }

    // epilogue: relu(acc+b2) contracted with Wo -> atomic out
    float bv[4];
    float4 wv[4];
    #pragma unroll
    for (int ni = 0; ni < 4; ++ni) {
        int gc = col0 + wn + ni * 16 + fr;
        bv[ni] = bias[gc];
        wv[ni] = *(const float4*)(Wo + (size_t)gc * 4);
    }
    bool addb = (col0 == 0) && (wn == 0);   // exactly one contribution per row adds bo
    #pragma unroll
    for (int mi = 0; mi < 4; ++mi) {
        #pragma unroll
        for (int r = 0; r < 4; ++r) {
            int gr = row0 + wm + mi * 16 + fq * 4 + r;
            float o0 = 0.f, o1 = 0.f, o2 = 0.f, o3 = 0.f;
            #pragma unroll
            for (int ni = 0; ni < 4; ++ni) {
                float v = acc[mi][ni][r] + bv[ni];
                v = (v > 0.f) ? v : 0.f;
                o0 += v * wv[ni].x; o1 += v * wv[ni].y;
                o2 += v * wv[ni].z; o3 += v * wv[ni].w;
            }
            #pragma unroll
            for (int off = 1; off < 16; off <<= 1) {
                o0 += __shfl_xor(o0, off); o1 += __shfl_xor(o1, off);
                o2 += __shfl_xor(o2, off); o3 += __shfl_xor(o3, off);
            }
            if (fr == 0 && gr < M) {
                if (addb) { o0 += bo[0]; o1 += bo[1]; o2 += bo[2]; o3 += bo[3]; }
                atomicAdd(&out[(size_t)gr * 4 + 0], o0);
                atomicAdd(&out[(size_t)gr * 4 + 1], o1);
                atomicAdd(&out[(size_t)gr * 4 + 2], o2);
                atomicAdd(&out[(size_t)gr * 4 + 3], o3);
            }
        }
    }
}

extern "C" void kernel_launch(void* const* d_in, const int* in_sizes, int n_in,
                              void* d_out, int out_size, void* d_ws, size_t ws_size,
                              hipStream_t stream) {
    const float* x    = (const float*)d_in[0];
    const int*   eidx = (const int*)d_in[1];
    const float* cW   = (const float*)d_in[2];
    const float* caS  = (const float*)d_in[3];
    const float* caD  = (const float*)d_in[4];
    const float* cB   = (const float*)d_in[5];
    const float* W0   = (const float*)d_in[6];
    const float* b0   = (const float*)d_in[7];
    const float* W1   = (const float*)d_in[8];
    const float* b1   = (const float*)d_in[9];
    const float* W2   = (const float*)d_in[10];
    const float* b2   = (const float*)d_in[11];
    const float* Wo   = (const float*)d_in[12];
    const float* bo   = (const float*)d_in[13];
    (void)in_sizes; (void)n_in; (void)out_size;

    const int* esrc = eidx;
    const int* edst = eidx + NE;
    float* out = (float*)d_out;

    // ---- workspace bump allocator (256B aligned) ----
    char* w = (char*)d_ws;
    auto alloc = [&](size_t bytes) -> char* {
        char* p = w;
        w += (bytes + 255) & ~(size_t)255;
        return p;
    };
    _Float16* x0h  = (_Float16*)alloc((size_t)NN * 128 * 2);
    _Float16* x0l  = (_Float16*)alloc((size_t)NN * 128 * 2);
    _Float16* xh   = (_Float16*)alloc((size_t)NN * 128 * 2);
    _Float16* xl   = (_Float16*)alloc((size_t)NN * 128 * 2);
    float* hbuf    = (float*)alloc((size_t)NN * 128 * 4);
    float* ssrc    = (float*)alloc((size_t)NN * 4);
    float* sdst    = (float*)alloc((size_t)NN * 4);
    int*   counts  = (int*)  alloc((size_t)NN * 4);
    int*   offs    = (int*)  alloc((size_t)(NN + 1) * 4);
    int*   cursor  = (int*)  alloc((size_t)NN * 4);
    int*   csr     = (int*)  alloc((size_t)NET * 4);
    int*   part    = (int*)  alloc((size_t)SCAN_NB * 4);
    _Float16* cwh  = (_Float16*)alloc(3 * 128 * 128 * 2);
    _Float16* cwl  = (_Float16*)alloc(3 * 128 * 128 * 2);
    _Float16* w0h  = (_Float16*)alloc(512 * 128 * 2);
    _Float16* w0l  = (_Float16*)alloc(512 * 128 * 2);
    _Float16* w1h  = (_Float16*)alloc(512 * 512 * 2);
    _Float16* w1l  = (_Float16*)alloc(512 * 512 * 2);
    _Float16* w2h  = (_Float16*)alloc(512 * 512 * 2);
    _Float16* w2l  = (_Float16*)alloc(512 * 512 * 2);

    size_t used = (size_t)(w - (char*)d_ws);
    size_t rem = (ws_size > used) ? (ws_size - used) : 0;
    int chunk = (int)(rem / (4 * 512 * sizeof(_Float16)));
    if (chunk > NN) chunk = NN;
    if (chunk > 128) chunk &= ~127;
    if (chunk < 1) chunk = 1;
    _Float16* Y0h = (_Float16*)alloc((size_t)chunk * 512 * 2);
    _Float16* Y0l = (_Float16*)alloc((size_t)chunk * 512 * 2);
    _Float16* Y1h = (_Float16*)alloc((size_t)chunk * 512 * 2);
    _Float16* Y1l = (_Float16*)alloc((size_t)chunk * 512 * 2);

    auto gemm = [&](const _Float16* Ah, const _Float16* Al,
                    const _Float16* Bh, const _Float16* Bl,
                    const float* bias, float* Cf, _Float16* Ch, _Float16* Cl,
                    int M, int N, int K, int relu, int split) {
        int nx = N / 128;
        int ntiles = nx * ((M + 127) / 128);
        int nb = ((ntiles + 7) / 8) * 8;
        k_mgemm<<<nb, 256, 0, stream>>>(Ah, Al, Bh, Bl, bias, Cf, Ch, Cl,
                                        M, N, K, relu, split, nx, ntiles);
    };

    // ---- prep: split x, transpose+split weights ----
    k_split<<<2048, 256, 0, stream>>>(x, x0h, x0l, NN * 128);
    for (int L = 0; L < 3; ++L)
        k_prepw<<<dim3(128 / 32, 128 / 32), 256, 0, stream>>>(
            cW + (size_t)L * 128 * 128, cwh + (size_t)L * 128 * 128, cwl + (size_t)L * 128 * 128, 128, 128);
    k_prepw<<<dim3(512 / 32, 128 / 32), 256, 0, stream>>>(W0, w0h, w0l, 128, 512);
    k_prepw<<<dim3(512 / 32, 512 / 32), 256, 0, stream>>>(W1, w1h, w1l, 512, 512);
    k_prepw<<<dim3(512 / 32, 512 / 32), 256, 0, stream>>>(W2, w2h, w2l, 512, 512);

    // ---- build CSR once ----
    hipMemsetAsync(counts, 0, (size_t)NN * 4, stream);
    int eblocks = (NET + 255) / 256;
    k_count <<<eblocks, 256, 0, stream>>>(edst, counts);
    k_scan1 <<<SCAN_NB, 256, 0, stream>>>(counts, part);
    k_scan2 <<<1, 256, 0, stream>>>(part, offs);
    k_scan3 <<<SCAN_NB, 256, 0, stream>>>(counts, part, offs, cursor);
    k_scatter<<<eblocks, 256, 0, stream>>>(esrc, edst, cursor, csr);

    // ---- 3 GAT layers (GEMM fused with attention scalars) ----
    int gat_tiles = (NN + 127) / 128;
    int gat_nb = ((gat_tiles + 7) / 8) * 8;
    for (int L = 0; L < 3; ++L) {
        const _Float16* Ah = (L == 0) ? x0h : xh;
        const _Float16* Al = (L == 0) ? x0l : xl;
        k_mgemm_gat<<<gat_nb, 256, 0, stream>>>(
            Ah, Al, cwh + (size_t)L * 128 * 128, cwl + (size_t)L * 128 * 128,
            caS + L * 128, caD + L * 128, hbuf, ssrc, sdst, NN, gat_tiles);
        k_aggregate<<<NN / 4, 256, 0, stream>>>(hbuf, ssrc, sdst, offs, csr, cB + L * 128, xh, xl);
    }

    // ---- MLP head (chunked over nodes; gemm2 fused with output head) ----
    hipMemsetAsync(out, 0, (size_t)NN * 4 * sizeof(float), stream);
    for (int m0 = 0; m0 < NN; m0 += chunk) {
        int cm = imin(chunk, NN - m0);
        gemm(xh + (size_t)m0 * 128, xl + (size_t)m0 * 128, w0h, w0l, b0,
             nullptr, Y0h, Y0l, cm, 512, 128, 1, 1);
        gemm(Y0h, Y0l, w1h, w1l, b1, nullptr, Y1h, Y1l, cm, 512, 512, 1, 1);
        int nx = 4;
        int ntiles = nx * ((cm + 127) / 128);
        int nb = ((ntiles + 7) / 8) * 8;
        k_mgemm_head<<<nb, 256, 0, stream>>>(Y1h, Y1l, w2h, w2l, b2, Wo, bo,
                                             out + (size_t)m0 * 4, cm, 512, nx, ntiles);
    }
}

// Round 5
// 758.917 us; speedup vs baseline: 1.1596x; 1.1118x over previous
//
#include <hip/hip_runtime.h>
#include <hip/hip_bf16.h>

#define NN 50000
#define NE 800000
#define NET (NE + NN)
#define SCAN_NB ((NN + 255) / 256)   // 196

static inline int imin(int a, int b) { return a < b ? a : b; }

typedef _Float16 half8 __attribute__((ext_vector_type(8)));
typedef _Float16 half2v __attribute__((ext_vector_type(2)));
typedef float f32x4 __attribute__((ext_vector_type(4)));

// ---------------- CSR build (graph constant across layers) ----------------
__global__ void k_count(const int* __restrict__ edst, int* __restrict__ counts) {
    int e = blockIdx.x * blockDim.x + threadIdx.x;
    if (e >= NET) return;
    int d = (e < NE) ? edst[e] : (e - NE);   // self loops appended
    atomicAdd(&counts[d], 1);
}

__global__ __launch_bounds__(256) void k_scan1(const int* __restrict__ counts,
                                               int* __restrict__ part) {
    __shared__ int s[256];
    int t = threadIdx.x, i = blockIdx.x * 256 + t;
    s[t] = (i < NN) ? counts[i] : 0;
    __syncthreads();
    for (int off = 128; off > 0; off >>= 1) {
        if (t < off) s[t] += s[t + off];
        __syncthreads();
    }
    if (t == 0) part[blockIdx.x] = s[0];
}

__global__ __launch_bounds__(256) void k_scan2(int* __restrict__ part, int* __restrict__ offs) {
    __shared__ int s[256];
    int t = threadIdx.x;
    int v = (t < SCAN_NB) ? part[t] : 0;
    s[t] = v;
    __syncthreads();
    for (int off = 1; off < 256; off <<= 1) {
        int a = (t >= off) ? s[t - off] : 0;
        __syncthreads();
        s[t] += a;
        __syncthreads();
    }
    if (t < SCAN_NB) part[t] = s[t] - v;     // exclusive block offsets
    if (t == 255) offs[NN] = s[255];         // total (= NET)
}

__global__ __launch_bounds__(256) void k_scan3(const int* __restrict__ counts,
                                               const int* __restrict__ part,
                                               int* __restrict__ offs, int* __restrict__ cursor) {
    __shared__ int s[256];
    int t = threadIdx.x, i = blockIdx.x * 256 + t;
    int v = (i < NN) ? counts[i] : 0;
    s[t] = v;
    __syncthreads();
    for (int off = 1; off < 256; off <<= 1) {
        int a = (t >= off) ? s[t - off] : 0;
        __syncthreads();
        s[t] += a;
        __syncthreads();
    }
    if (i < NN) {
        int e = part[blockIdx.x] + s[t] - v;
        offs[i] = e;
        cursor[i] = e;
    }
}

__global__ void k_scatter(const int* __restrict__ esrc, const int* __restrict__ edst,
                          int* __restrict__ cursor, int* __restrict__ csr_src) {
    int e = blockIdx.x * blockDim.x + threadIdx.x;
    if (e >= NET) return;
    int s, d;
    if (e < NE) { s = esrc[e]; d = edst[e]; } else { s = e - NE; d = s; }
    int pos = atomicAdd(&cursor[d], 1);
    csr_src[pos] = s;
}

// ---------------- split fp32 -> f16 hi/lo pair ----------------
__global__ void k_split(const float* __restrict__ in, _Float16* __restrict__ hi,
                        _Float16* __restrict__ lo, int n) {
    int i = blockIdx.x * blockDim.x + threadIdx.x;
    int st = gridDim.x * blockDim.x;
    for (; i < n; i += st) {
        float v = in[i];
        _Float16 h = (_Float16)v;
        hi[i] = h;
        lo[i] = (_Float16)(v - (float)h);
    }
}

// ---------------- transpose + split weights: W[K][N] -> T[N][K] hi/lo (LDS-tiled) ----
__global__ __launch_bounds__(256) void k_prepw(const float* __restrict__ W,
                                               _Float16* __restrict__ Th,
                                               _Float16* __restrict__ Tl, int K, int N) {
    __shared__ float tile[32][33];
    int tx = threadIdx.x & 31, ty = threadIdx.x >> 5;
    int n0 = blockIdx.x * 32, k0 = blockIdx.y * 32;
    #pragma unroll
    for (int r = ty; r < 32; r += 8)
        tile[r][tx] = W[(size_t)(k0 + r) * N + n0 + tx];   // coalesced read
    __syncthreads();
    #pragma unroll
    for (int r = ty; r < 32; r += 8) {
        int n = n0 + r, k = k0 + tx;
        float v = tile[tx][r];
        _Float16 h = (_Float16)v;
        Th[(size_t)n * K + k] = h;                          // coalesced 64B segments
        Tl[(size_t)n * K + k] = (_Float16)(v - (float)h);
    }
}

// ---------------- fused segment-softmax + aggregate + bias + leaky ----------------
// 4-edge unroll (latency-bound gather); float2 per-lane row gather (1 load not 2).
__global__ void k_aggregate(const float* __restrict__ h, const float* __restrict__ s_src,
                            const float* __restrict__ s_dst, const int* __restrict__ offs,
                            const int* __restrict__ csr_src, const float* __restrict__ bias,
                            _Float16* __restrict__ xh, _Float16* __restrict__ xl) {
    int node = blockIdx.x * 4 + (threadIdx.x >> 6);
    int lane = threadIdx.x & 63;
    if (node >= NN) return;
    int p = offs[node], pe = offs[node + 1];
    float sd = s_dst[node];
    float den = 0.f, acc0 = 0.f, acc1 = 0.f;
    for (; p + 4 <= pe; p += 4) {
        int s0 = csr_src[p + 0], s1 = csr_src[p + 1];
        int s2 = csr_src[p + 2], s3 = csr_src[p + 3];
        float e0 = s_src[s0] + sd, e1 = s_src[s1] + sd;
        float e2 = s_src[s2] + sd, e3 = s_src[s3] + sd;
        float2 a0 = *((const float2*)(h + (size_t)s0 * 128) + lane);
        float2 a1 = *((const float2*)(h + (size_t)s1 * 128) + lane);
        float2 a2 = *((const float2*)(h + (size_t)s2 * 128) + lane);
        float2 a3 = *((const float2*)(h + (size_t)s3 * 128) + lane);
        e0 = (e0 > 0.f) ? e0 : 0.2f * e0;  float w0 = __expf(e0);
        e1 = (e1 > 0.f) ? e1 : 0.2f * e1;  float w1 = __expf(e1);
        e2 = (e2 > 0.f) ? e2 : 0.2f * e2;  float w2 = __expf(e2);
        e3 = (e3 > 0.f) ? e3 : 0.2f * e3;  float w3 = __expf(e3);
        den += (w0 + w1) + (w2 + w3);
        acc0 += w0 * a0.x + w1 * a1.x + w2 * a2.x + w3 * a3.x;
        acc1 += w0 * a0.y + w1 * a1.y + w2 * a2.y + w3 * a3.y;
    }
    for (; p < pe; ++p) {
        int src = csr_src[p];
        float e = s_src[src] + sd;
        e = (e > 0.f) ? e : 0.2f * e;
        float wgt = __expf(e);
        den += wgt;
        float2 av = *((const float2*)(h + (size_t)src * 128) + lane);
        acc0 += wgt * av.x;
        acc1 += wgt * av.y;
    }
    float inv = 1.f / den;                    // self-loop guarantees den > 0
    float2 bv = *((const float2*)bias + lane);
    float v0 = acc0 * inv + bv.x;
    float v1 = acc1 * inv + bv.y;
    v0 = (v0 > 0.f) ? v0 : 0.2f * v0;
    v1 = (v1 > 0.f) ? v1 : 0.2f * v1;
    _Float16 h0 = (_Float16)v0, h1 = (_Float16)v1;
    size_t base = (size_t)node * 128 + 2 * lane;
    *(half2v*)(xh + base) = (half2v){h0, h1};
    *(half2v*)(xl + base) = (half2v){(_Float16)(v0 - (float)h0), (_Float16)(v1 - (float)h1)};
}

// ---------------- shared GEMM machinery (R2 structure — measured best) ----------
// 128x128 tile, 4 waves (2x2), each wave 64x64 = 4x4 of 16x16x32 MFMA. BK=32.
// Single-buffer LDS [4][128][32] + gload_lds width=16 staging; 2 __syncthreads
// per K-step. R3's explicit dbuf REGRESSED (125µs, WRITE 2x, 40ms outlier):
// cross-block implicit overlap at 32KB LDS beats intra-block pipelining at
// 64KB (replicates learn_hip m99/m100 null). This K-loop is the structural
// local optimum for this shape — do not touch; optimize around it.
__device__ __forceinline__ void gload_lds16(const void* g, void* l) {
    __builtin_amdgcn_global_load_lds(
        (const __attribute__((address_space(1))) void*)g,
        (__attribute__((address_space(3))) void*)l, 16, 0, 0);
}

// ---------------- generic split-f16 MFMA GEMM (gemm0/gemm1: relu+split out) ----
__global__ __launch_bounds__(256) void k_mgemm(
    const _Float16* __restrict__ Ahi, const _Float16* __restrict__ Alo,
    const _Float16* __restrict__ Bhi, const _Float16* __restrict__ Blo,
    const float* __restrict__ bias, float* __restrict__ Cf,
    _Float16* __restrict__ Chi, _Float16* __restrict__ Clo,
    int M, int N, int K, int relu, int split, int nx, int ntiles)
{
    __shared__ _Float16 sm[4][128][32];   // 32 KiB: Ahi, Alo, Bhi, Blo

    int bid = blockIdx.x;
    int per = (ntiles + 7) >> 3;
    int g = (bid & 7) * per + (bid >> 3);
    if (g >= ntiles) return;
    int col0 = (g % nx) * 128;
    int row0 = (g / nx) * 128;

    int t = threadIdx.x;
    int w = t >> 6, lane = t & 63;
    int wm = (w & 1) * 64, wn = (w >> 1) * 64;
    int fr = lane & 15;
    int fq = lane >> 4, fq8 = fq * 8;

    int srow = (w << 5) + (lane >> 2);
    int scol = (lane & 3) << 3;          // halfs

    f32x4 acc[4][4];
    #pragma unroll
    for (int i = 0; i < 4; i++)
        #pragma unroll
        for (int j = 0; j < 4; j++) acc[i][j] = (f32x4){0.f, 0.f, 0.f, 0.f};

    for (int k0 = 0; k0 < K; k0 += 32) {
        if (k0) __syncthreads();
        #pragma unroll
        for (int i = 0; i < 2; ++i) {
            int rr = srow + i * 16;
            int ga = row0 + rr; if (ga > M - 1) ga = M - 1;  // M-tail: dup reads, rows guarded in epilogue
            int gb = col0 + rr;                               // N % 128 == 0 -> in range
            int lrow = (w << 5) + i * 16;                     // wave-uniform LDS base row
            gload_lds16(Ahi + (size_t)ga * K + k0 + scol, &sm[0][lrow][0]);
            gload_lds16(Alo + (size_t)ga * K + k0 + scol, &sm[1][lrow][0]);
            gload_lds16(Bhi + (size_t)gb * K + k0 + scol, &sm[2][lrow][0]);
            gload_lds16(Blo + (size_t)gb * K + k0 + scol, &sm[3][lrow][0]);
        }
        __syncthreads();   // drains vmcnt -> gload_lds stores visible to all waves

        half8 bh[4], bl[4];
        #pragma unroll
        for (int ni = 0; ni < 4; ++ni) {
            bh[ni] = *(half8*)&sm[2][wn + ni * 16 + fr][fq8];
            bl[ni] = *(half8*)&sm[3][wn + ni * 16 + fr][fq8];
        }
        #pragma unroll
        for (int mi = 0; mi < 4; ++mi) {
            half8 ah = *(half8*)&sm[0][wm + mi * 16 + fr][fq8];
            half8 al = *(half8*)&sm[1][wm + mi * 16 + fr][fq8];
            #pragma unroll
            for (int ni = 0; ni < 4; ++ni) {
                acc[mi][ni] = __builtin_amdgcn_mfma_f32_16x16x32_f16(ah, bh[ni], acc[mi][ni], 0, 0, 0);
                acc[mi][ni] = __builtin_amdgcn_mfma_f32_16x16x32_f16(ah, bl[ni], acc[mi][ni], 0, 0, 0);
                acc[mi][ni] = __builtin_amdgcn_mfma_f32_16x16x32_f16(al, bh[ni], acc[mi][ni], 0, 0, 0);
            }
        }
    }

    // epilogue: C/D layout col=lane&15, row=quad*4+reg
    #pragma unroll
    for (int ni = 0; ni < 4; ++ni) {
        int gc = col0 + wn + ni * 16 + fr;
        float bv = bias ? bias[gc] : 0.f;
        #pragma unroll
        for (int mi = 0; mi < 4; ++mi) {
            #pragma unroll
            for (int r = 0; r < 4; ++r) {
                int gr = row0 + wm + mi * 16 + fq * 4 + r;
                if (gr >= M) continue;
                float v = acc[mi][ni][r] + bv;
                if (relu) v = (v > 0.f) ? v : 0.f;
                size_t idx = (size_t)gr * N + gc;
                if (split) {
                    _Float16 hh = (_Float16)v;
                    Chi[idx] = hh;
                    Clo[idx] = (_Float16)(v - (float)hh);
                } else {
                    Cf[idx] = v;
                }
            }
        }
    }
}

// ---------------- GAT GEMM fused with attention scalars (N=K=128) ----------------
// R15: each block holds complete 128-wide rows of h=x@W in registers, so
// s_src[r]=h[r]·a_src and s_dst[r]=h[r]·a_dst are computed in the epilogue:
// 4 FMA/lane + 16-lane shfl_xor reduce + cross-wave LDS combine. Removes the
// separate k_scalars kernel (3 launches + 3x25.6MB hbuf re-reads).
__global__ __launch_bounds__(256) void k_mgemm_gat(
    const _Float16* __restrict__ Ahi, const _Float16* __restrict__ Alo,
    const _Float16* __restrict__ Bhi, const _Float16* __restrict__ Blo,
    const float* __restrict__ a_src, const float* __restrict__ a_dst,
    float* __restrict__ hbuf, float* __restrict__ s_src, float* __restrict__ s_dst,
    int M, int ntiles)
{
    __shared__ _Float16 sm[4][128][32];   // 32 KiB
    __shared__ float sps[2][128], spd[2][128];

    const int K = 128;
    int bid = blockIdx.x;
    int per = (ntiles + 7) >> 3;
    int g = (bid & 7) * per + (bid >> 3);
    if (g >= ntiles) return;
    int row0 = g * 128;                    // nx == 1 (N = 128)

    int t = threadIdx.x;
    int w = t >> 6, lane = t & 63;
    int wm = (w & 1) * 64, wn = (w >> 1) * 64;
    int fr = lane & 15;
    int fq = lane >> 4, fq8 = fq * 8;
    int wnIdx = w >> 1;

    int srow = (w << 5) + (lane >> 2);
    int scol = (lane & 3) << 3;

    f32x4 acc[4][4];
    #pragma unroll
    for (int i = 0; i < 4; i++)
        #pragma unroll
        for (int j = 0; j < 4; j++) acc[i][j] = (f32x4){0.f, 0.f, 0.f, 0.f};

    for (int k0 = 0; k0 < K; k0 += 32) {
        if (k0) __syncthreads();
        #pragma unroll
        for (int i = 0; i < 2; ++i) {
            int rr = srow + i * 16;
            int ga = row0 + rr; if (ga > M - 1) ga = M - 1;
            int gb = rr;                                      // col0 = 0, N = 128
            int lrow = (w << 5) + i * 16;
            gload_lds16(Ahi + (size_t)ga * K + k0 + scol, &sm[0][lrow][0]);
            gload_lds16(Alo + (size_t)ga * K + k0 + scol, &sm[1][lrow][0]);
            gload_lds16(Bhi + (size_t)gb * K + k0 + scol, &sm[2][lrow][0]);
            gload_lds16(Blo + (size_t)gb * K + k0 + scol, &sm[3][lrow][0]);
        }
        __syncthreads();

        half8 bh[4], bl[4];
        #pragma unroll
        for (int ni = 0; ni < 4; ++ni) {
            bh[ni] = *(half8*)&sm[2][wn + ni * 16 + fr][fq8];
            bl[ni] = *(half8*)&sm[3][wn + ni * 16 + fr][fq8];
        }
        #pragma unroll
        for (int mi = 0; mi < 4; ++mi) {
            half8 ah = *(half8*)&sm[0][wm + mi * 16 + fr][fq8];
            half8 al = *(half8*)&sm[1][wm + mi * 16 + fr][fq8];
            #pragma unroll
            for (int ni = 0; ni < 4; ++ni) {
                acc[mi][ni] = __builtin_amdgcn_mfma_f32_16x16x32_f16(ah, bh[ni], acc[mi][ni], 0, 0, 0);
                acc[mi][ni] = __builtin_amdgcn_mfma_f32_16x16x32_f16(ah, bl[ni], acc[mi][ni], 0, 0, 0);
                acc[mi][ni] = __builtin_amdgcn_mfma_f32_16x16x32_f16(al, bh[ni], acc[mi][ni], 0, 0, 0);
            }
        }
    }

    // epilogue: write hbuf (fp32) + fused attention scalar dots
    float asv[4], adv[4];
    #pragma unroll
    for (int ni = 0; ni < 4; ++ni) {
        int gc = wn + ni * 16 + fr;
        asv[ni] = a_src[gc];
        adv[ni] = a_dst[gc];
    }
    #pragma unroll
    for (int mi = 0; mi < 4; ++mi) {
        #pragma unroll
        for (int r = 0; r < 4; ++r) {
            int lrow = wm + mi * 16 + fq * 4 + r;
            int gr = row0 + lrow;
            float vps = 0.f, vpd = 0.f;
            #pragma unroll
            for (int ni = 0; ni < 4; ++ni) {
                float v = acc[mi][ni][r];
                vps += v * asv[ni];
                vpd += v * adv[ni];
                if (gr < M) hbuf[(size_t)gr * 128 + wn + ni * 16 + fr] = v;
            }
            // reduce over 16 fr lanes (xor < 16 stays within quad group)
            #pragma unroll
            for (int off = 1; off < 16; off <<= 1) {
                vps += __shfl_xor(vps, off);
                vpd += __shfl_xor(vpd, off);
            }
            if (fr == 0) { sps[wnIdx][lrow] = vps; spd[wnIdx][lrow] = vpd; }
        }
    }
    __syncthreads();
    if (t < 128) {
        int gr = row0 + t;
        if (gr < M) {
            s_src[gr] = sps[0][t] + sps[1][t];
            s_dst[gr] = spd[0][t] + spd[1][t];
        }
    }
}

// ---------------- gemm2 fused with MLP head (N=512, partials out, NO atomics) -----
// R16: R4's atomicAdd epilogue cost 27µs net (WRITE 45MB: 1.6M device-scope
// atomics execute past L2 -> one fabric transaction each). Each (row-panel,
// col-tile) cell is owned by exactly ONE block -> write per-block partials
// non-atomically (coalesced float4), reduce in tiny k_headred kernel.
// partial layout: [ct][M][4] floats (ct = col-tile 0..3), 3.2MB total.
__global__ __launch_bounds__(256) void k_mgemm_head(
    const _Float16* __restrict__ Ahi, const _Float16* __restrict__ Alo,
    const _Float16* __restrict__ Bhi, const _Float16* __restrict__ Blo,
    const float* __restrict__ bias, const float* __restrict__ Wo,
    float* __restrict__ partial,
    int M, int K, int nx, int ntiles)
{
    __shared__ _Float16 sm[4][128][32];   // 32 KiB
    __shared__ float4 sacc[2][128];       // 4 KiB: per-wn-half row partials

    int bid = blockIdx.x;
    int per = (ntiles + 7) >> 3;
    int g = (bid & 7) * per + (bid >> 3);
    if (g >= ntiles) return;
    int ct = g % nx;
    int col0 = ct * 128;
    int row0 = (g / nx) * 128;

    int t = threadIdx.x;
    int w = t >> 6, lane = t & 63;
    int wm = (w & 1) * 64, wn = (w >> 1) * 64;
    int fr = lane & 15;
    int fq = lane >> 4, fq8 = fq * 8;

    int srow = (w << 5) + (lane >> 2);
    int scol = (lane & 3) << 3;

    f32x4 acc[4][4];
    #pragma unroll
    for (int i = 0; i < 4; i++)
        #pragma unroll
        for (int j = 0; j < 4; j++) acc[i][j] = (f32x4){0.f, 0.f, 0.f, 0.f};

    for (int k0 = 0; k0 < K; k0 += 32) {
        if (k0) __syncthreads();
        #pragma unroll
        for (int i = 0; i < 2; ++i) {
            int rr = srow + i * 16;
            int ga = row0 + rr; if (ga > M - 1) ga = M - 1;
            int gb = col0 + rr;
            int lrow = (w << 5) + i * 16;
            gload_lds16(Ahi + (size_t)ga * K + k0 + scol, &sm[0][lrow][0]);
            gload_lds16(Alo + (size_t)ga * K + k0 + scol, &sm[1][lrow][0]);
            gload_lds16(Bhi + (size_t)gb * K + k0 + scol, &sm[2][lrow][0]);
            gload_lds16(Blo + (size_t)gb * K + k0 + scol, &sm[3][lrow][0]);
        }
        __syncthreads();

        half8 bh[4], bl[4];
        #pragma unroll
        for (int ni = 0; ni < 4; ++ni) {
            bh[ni] = *(half8*)&sm[2][wn + ni * 16 + fr][fq8];
            bl[ni] = *(half8*)&sm[3][wn + ni * 16 + fr][fq8];
        }
        #pragma unroll
        for (int mi = 0; mi < 4; ++mi) {
            half8 ah = *(half8*)&sm[0][wm + mi * 16 + fr][fq8];
            half8 al = *(half8*)&sm[1][wm + mi * 16 + fr][fq8];
            #pragma unroll
            for (int ni = 0; ni < 4; ++ni) {
                acc[mi][ni] = __builtin_amdgcn_mfma_f32_16x16x32_f16(ah, bh[ni], acc[mi][ni], 0, 0, 0);
                acc[mi][ni] = __builtin_amdgcn_mfma_f32_16x16x32_f16(ah, bl[ni], acc[mi][ni], 0, 0, 0);
                acc[mi][ni] = __builtin_amdgcn_mfma_f32_16x16x32_f16(al, bh[ni], acc[mi][ni], 0, 0, 0);
            }
        }
    }

    // epilogue: relu(acc+b2) contracted with Wo -> LDS combine -> partial write
    float bv[4];
    float4 wv[4];
    #pragma unroll
    for (int ni = 0; ni < 4; ++ni) {
        int gc = col0 + wn + ni * 16 + fr;
        bv[ni] = bias[gc];
        wv[ni] = *(const float4*)(Wo + (size_t)gc * 4);
    }
    #pragma unroll
    for (int mi = 0; mi < 4; ++mi) {
        #pragma unroll
        for (int r = 0; r < 4; ++r) {
            int lrow = wm + mi * 16 + fq * 4 + r;
            float o0 = 0.f, o1 = 0.f, o2 = 0.f, o3 = 0.f;
            #pragma unroll
            for (int ni = 0; ni < 4; ++ni) {
                float v = acc[mi][ni][r] + bv[ni];
                v = (v > 0.f) ? v : 0.f;
                o0 += v * wv[ni].x; o1 += v * wv[ni].y;
                o2 += v * wv[ni].z; o3 += v * wv[ni].w;
            }
            #pragma unroll
            for (int off = 1; off < 16; off <<= 1) {
                o0 += __shfl_xor(o0, off); o1 += __shfl_xor(o1, off);
                o2 += __shfl_xor(o2, off); o3 += __shfl_xor(o3, off);
            }
            if (fr == 0) sacc[w >> 1][lrow] = (float4){o0, o1, o2, o3};
        }
    }
    __syncthreads();
    if (t < 128) {
        int gr = row0 + t;
        if (gr < M) {
            float4 s0 = sacc[0][t], s1 = sacc[1][t];
            float4 o = (float4){s0.x + s1.x, s0.y + s1.y, s0.z + s1.z, s0.w + s1.w};
            *(float4*)(partial + ((size_t)ct * M + gr) * 4) = o;
        }
    }
}

// ---------------- reduce 4 col-tile partials -> out (adds bo) ----------------
__global__ __launch_bounds__(256) void k_headred(const float* __restrict__ partial,
                                                 const float* __restrict__ bo,
                                                 float* __restrict__ out, int M) {
    int r = blockIdx.x * 256 + threadIdx.x;
    if (r >= M) return;
    float4 a = *(const float4*)(partial + ((size_t)0 * M + r) * 4);
    float4 b = *(const float4*)(partial + ((size_t)1 * M + r) * 4);
    float4 c = *(const float4*)(partial + ((size_t)2 * M + r) * 4);
    float4 d = *(const float4*)(partial + ((size_t)3 * M + r) * 4);
    float4 o;
    o.x = a.x + b.x + c.x + d.x + bo[0];
    o.y = a.y + b.y + c.y + d.y + bo[1];
    o.z = a.z + b.z + c.z + d.z + bo[2];
    o.w = a.w + b.w + c.w + d.w + bo[3];
    *(float4*)(out + (size_t)r * 4) = o;
}

extern "C" void kernel_launch(void* const* d_in, const int* in_sizes, int n_in,
                              void* d_out, int out_size, void* d_ws, size_t ws_size,
                              hipStream_t stream) {
    const float* x    = (const float*)d_in[0];
    const int*   eidx = (const int*)d_in[1];
    const float* cW   = (const float*)d_in[2];
    const float* caS  = (const float*)d_in[3];
    const float* caD  = (const float*)d_in[4];
    const float* cB   = (const float*)d_in[5];
    const float* W0   = (const float*)d_in[6];
    const float* b0   = (const float*)d_in[7];
    const float* W1   = (const float*)d_in[8];
    const float* b1   = (const float*)d_in[9];
    const float* W2   = (const float*)d_in[10];
    const float* b2   = (const float*)d_in[11];
    const float* Wo   = (const float*)d_in[12];
    const float* bo   = (const float*)d_in[13];
    (void)in_sizes; (void)n_in; (void)out_size;

    const int* esrc = eidx;
    const int* edst = eidx + NE;
    float* out = (float*)d_out;

    // ---- workspace bump allocator (256B aligned) ----
    char* w = (char*)d_ws;
    auto alloc = [&](size_t bytes) -> char* {
        char* p = w;
        w += (bytes + 255) & ~(size_t)255;
        return p;
    };
    _Float16* x0h  = (_Float16*)alloc((size_t)NN * 128 * 2);
    _Float16* x0l  = (_Float16*)alloc((size_t)NN * 128 * 2);
    _Float16* xh   = (_Float16*)alloc((size_t)NN * 128 * 2);
    _Float16* xl   = (_Float16*)alloc((size_t)NN * 128 * 2);
    float* hbuf    = (float*)alloc((size_t)NN * 128 * 4);
    float* ssrc    = (float*)alloc((size_t)NN * 4);
    float* sdst    = (float*)alloc((size_t)NN * 4);
    int*   counts  = (int*)  alloc((size_t)NN * 4);
    int*   offs    = (int*)  alloc((size_t)(NN + 1) * 4);
    int*   cursor  = (int*)  alloc((size_t)NN * 4);
    int*   csr     = (int*)  alloc((size_t)NET * 4);
    int*   part    = (int*)  alloc((size_t)SCAN_NB * 4);
    _Float16* cwh  = (_Float16*)alloc(3 * 128 * 128 * 2);
    _Float16* cwl  = (_Float16*)alloc(3 * 128 * 128 * 2);
    _Float16* w0h  = (_Float16*)alloc(512 * 128 * 2);
    _Float16* w0l  = (_Float16*)alloc(512 * 128 * 2);
    _Float16* w1h  = (_Float16*)alloc(512 * 512 * 2);
    _Float16* w1l  = (_Float16*)alloc(512 * 512 * 2);
    _Float16* w2h  = (_Float16*)alloc(512 * 512 * 2);
    _Float16* w2l  = (_Float16*)alloc(512 * 512 * 2);
    float* hpart   = (float*)alloc((size_t)4 * NN * 4 * 4);   // head partials [4][NN][4]

    size_t used = (size_t)(w - (char*)d_ws);
    size_t rem = (ws_size > used) ? (ws_size - used) : 0;
    int chunk = (int)(rem / (4 * 512 * sizeof(_Float16)));
    if (chunk > NN) chunk = NN;
    if (chunk > 128) chunk &= ~127;
    if (chunk < 1) chunk = 1;
    _Float16* Y0h = (_Float16*)alloc((size_t)chunk * 512 * 2);
    _Float16* Y0l = (_Float16*)alloc((size_t)chunk * 512 * 2);
    _Float16* Y1h = (_Float16*)alloc((size_t)chunk * 512 * 2);
    _Float16* Y1l = (_Float16*)alloc((size_t)chunk * 512 * 2);

    auto gemm = [&](const _Float16* Ah, const _Float16* Al,
                    const _Float16* Bh, const _Float16* Bl,
                    const float* bias, float* Cf, _Float16* Ch, _Float16* Cl,
                    int M, int N, int K, int relu, int split) {
        int nx = N / 128;
        int ntiles = nx * ((M + 127) / 128);
        int nb = ((ntiles + 7) / 8) * 8;
        k_mgemm<<<nb, 256, 0, stream>>>(Ah, Al, Bh, Bl, bias, Cf, Ch, Cl,
                                        M, N, K, relu, split, nx, ntiles);
    };

    // ---- prep: split x, transpose+split weights ----
    k_split<<<2048, 256, 0, stream>>>(x, x0h, x0l, NN * 128);
    for (int L = 0; L < 3; ++L)
        k_prepw<<<dim3(128 / 32, 128 / 32), 256, 0, stream>>>(
            cW + (size_t)L * 128 * 128, cwh + (size_t)L * 128 * 128, cwl + (size_t)L * 128 * 128, 128, 128);
    k_prepw<<<dim3(512 / 32, 128 / 32), 256, 0, stream>>>(W0, w0h, w0l, 128, 512);
    k_prepw<<<dim3(512 / 32, 512 / 32), 256, 0, stream>>>(W1, w1h, w1l, 512, 512);
    k_prepw<<<dim3(512 / 32, 512 / 32), 256, 0, stream>>>(W2, w2h, w2l, 512, 512);

    // ---- build CSR once ----
    hipMemsetAsync(counts, 0, (size_t)NN * 4, stream);
    int eblocks = (NET + 255) / 256;
    k_count <<<eblocks, 256, 0, stream>>>(edst, counts);
    k_scan1 <<<SCAN_NB, 256, 0, stream>>>(counts, part);
    k_scan2 <<<1, 256, 0, stream>>>(part, offs);
    k_scan3 <<<SCAN_NB, 256, 0, stream>>>(counts, part, offs, cursor);
    k_scatter<<<eblocks, 256, 0, stream>>>(esrc, edst, cursor, csr);

    // ---- 3 GAT layers (GEMM fused with attention scalars) ----
    int gat_tiles = (NN + 127) / 128;
    int gat_nb = ((gat_tiles + 7) / 8) * 8;
    for (int L = 0; L < 3; ++L) {
        const _Float16* Ah = (L == 0) ? x0h : xh;
        const _Float16* Al = (L == 0) ? x0l : xl;
        k_mgemm_gat<<<gat_nb, 256, 0, stream>>>(
            Ah, Al, cwh + (size_t)L * 128 * 128, cwl + (size_t)L * 128 * 128,
            caS + L * 128, caD + L * 128, hbuf, ssrc, sdst, NN, gat_tiles);
        k_aggregate<<<NN / 4, 256, 0, stream>>>(hbuf, ssrc, sdst, offs, csr, cB + L * 128, xh, xl);
    }

    // ---- MLP head (chunked over nodes; gemm2 fused with output head) ----
    for (int m0 = 0; m0 < NN; m0 += chunk) {
        int cm = imin(chunk, NN - m0);
        gemm(xh + (size_t)m0 * 128, xl + (size_t)m0 * 128, w0h, w0l, b0,
             nullptr, Y0h, Y0l, cm, 512, 128, 1, 1);
        gemm(Y0h, Y0l, w1h, w1l, b1, nullptr, Y1h, Y1l, cm, 512, 512, 1, 1);
        int nx = 4;
        int ntiles = nx * ((cm + 127) / 128);
        int nb = ((ntiles + 7) / 8) * 8;
        k_mgemm_head<<<nb, 256, 0, stream>>>(Y1h, Y1l, w2h, w2l, b2, Wo,
                                             hpart, cm, 512, nx, ntiles);
        k_headred<<<(cm + 255) / 256, 256, 0, stream>>>(hpart, bo, out + (size_t)m0 * 4, cm);
    }
}

// Round 6
// 747.726 us; speedup vs baseline: 1.1769x; 1.0150x over previous
//
#include <hip/hip_runtime.h>
#include <hip/hip_bf16.h>

#define NN 50000
#define NE 800000
#define NET (NE + NN)
#define SCAN_NB ((NN + 255) / 256)   // 196

static inline int imin(int a, int b) { return a < b ? a : b; }

typedef _Float16 half8 __attribute__((ext_vector_type(8)));
typedef _Float16 half2v __attribute__((ext_vector_type(2)));
typedef float f32x4 __attribute__((ext_vector_type(4)));

// ---------------- CSR build (graph constant across layers) ----------------
__global__ void k_count(const int* __restrict__ edst, int* __restrict__ counts) {
    int e = blockIdx.x * blockDim.x + threadIdx.x;
    if (e >= NET) return;
    int d = (e < NE) ? edst[e] : (e - NE);   // self loops appended
    atomicAdd(&counts[d], 1);
}

__global__ __launch_bounds__(256) void k_scan1(const int* __restrict__ counts,
                                               int* __restrict__ part) {
    __shared__ int s[256];
    int t = threadIdx.x, i = blockIdx.x * 256 + t;
    s[t] = (i < NN) ? counts[i] : 0;
    __syncthreads();
    for (int off = 128; off > 0; off >>= 1) {
        if (t < off) s[t] += s[t + off];
        __syncthreads();
    }
    if (t == 0) part[blockIdx.x] = s[0];
}

__global__ __launch_bounds__(256) void k_scan2(int* __restrict__ part, int* __restrict__ offs) {
    __shared__ int s[256];
    int t = threadIdx.x;
    int v = (t < SCAN_NB) ? part[t] : 0;
    s[t] = v;
    __syncthreads();
    for (int off = 1; off < 256; off <<= 1) {
        int a = (t >= off) ? s[t - off] : 0;
        __syncthreads();
        s[t] += a;
        __syncthreads();
    }
    if (t < SCAN_NB) part[t] = s[t] - v;     // exclusive block offsets
    if (t == 255) offs[NN] = s[255];         // total (= NET)
}

__global__ __launch_bounds__(256) void k_scan3(const int* __restrict__ counts,
                                               const int* __restrict__ part,
                                               int* __restrict__ offs, int* __restrict__ cursor) {
    __shared__ int s[256];
    int t = threadIdx.x, i = blockIdx.x * 256 + t;
    int v = (i < NN) ? counts[i] : 0;
    s[t] = v;
    __syncthreads();
    for (int off = 1; off < 256; off <<= 1) {
        int a = (t >= off) ? s[t - off] : 0;
        __syncthreads();
        s[t] += a;
        __syncthreads();
    }
    if (i < NN) {
        int e = part[blockIdx.x] + s[t] - v;
        offs[i] = e;
        cursor[i] = e;
    }
}

__global__ void k_scatter(const int* __restrict__ esrc, const int* __restrict__ edst,
                          int* __restrict__ cursor, int* __restrict__ csr_src) {
    int e = blockIdx.x * blockDim.x + threadIdx.x;
    if (e >= NET) return;
    int s, d;
    if (e < NE) { s = esrc[e]; d = edst[e]; } else { s = e - NE; d = s; }
    int pos = atomicAdd(&cursor[d], 1);
    csr_src[pos] = s;
}

// ---------------- split fp32 -> f16 hi/lo pair ----------------
__global__ void k_split(const float* __restrict__ in, _Float16* __restrict__ hi,
                        _Float16* __restrict__ lo, int n) {
    int i = blockIdx.x * blockDim.x + threadIdx.x;
    int st = gridDim.x * blockDim.x;
    for (; i < n; i += st) {
        float v = in[i];
        _Float16 h = (_Float16)v;
        hi[i] = h;
        lo[i] = (_Float16)(v - (float)h);
    }
}

// ---------------- transpose + split weights: W[K][N] -> T[N][K] hi/lo (LDS-tiled) ----
__global__ __launch_bounds__(256) void k_prepw(const float* __restrict__ W,
                                               _Float16* __restrict__ Th,
                                               _Float16* __restrict__ Tl, int K, int N) {
    __shared__ float tile[32][33];
    int tx = threadIdx.x & 31, ty = threadIdx.x >> 5;
    int n0 = blockIdx.x * 32, k0 = blockIdx.y * 32;
    #pragma unroll
    for (int r = ty; r < 32; r += 8)
        tile[r][tx] = W[(size_t)(k0 + r) * N + n0 + tx];   // coalesced read
    __syncthreads();
    #pragma unroll
    for (int r = ty; r < 32; r += 8) {
        int n = n0 + r, k = k0 + tx;
        float v = tile[tx][r];
        _Float16 h = (_Float16)v;
        Th[(size_t)n * K + k] = h;                          // coalesced 64B segments
        Tl[(size_t)n * K + k] = (_Float16)(v - (float)h);
    }
}

// ---------------- fused segment-softmax + aggregate + bias + leaky ----------------
// 4-edge unroll (latency-bound gather); float2 per-lane row gather (1 load not 2).
__global__ void k_aggregate(const float* __restrict__ h, const float* __restrict__ s_src,
                            const float* __restrict__ s_dst, const int* __restrict__ offs,
                            const int* __restrict__ csr_src, const float* __restrict__ bias,
                            _Float16* __restrict__ xh, _Float16* __restrict__ xl) {
    int node = blockIdx.x * 4 + (threadIdx.x >> 6);
    int lane = threadIdx.x & 63;
    if (node >= NN) return;
    int p = offs[node], pe = offs[node + 1];
    float sd = s_dst[node];
    float den = 0.f, acc0 = 0.f, acc1 = 0.f;
    for (; p + 4 <= pe; p += 4) {
        int s0 = csr_src[p + 0], s1 = csr_src[p + 1];
        int s2 = csr_src[p + 2], s3 = csr_src[p + 3];
        float e0 = s_src[s0] + sd, e1 = s_src[s1] + sd;
        float e2 = s_src[s2] + sd, e3 = s_src[s3] + sd;
        float2 a0 = *((const float2*)(h + (size_t)s0 * 128) + lane);
        float2 a1 = *((const float2*)(h + (size_t)s1 * 128) + lane);
        float2 a2 = *((const float2*)(h + (size_t)s2 * 128) + lane);
        float2 a3 = *((const float2*)(h + (size_t)s3 * 128) + lane);
        e0 = (e0 > 0.f) ? e0 : 0.2f * e0;  float w0 = __expf(e0);
        e1 = (e1 > 0.f) ? e1 : 0.2f * e1;  float w1 = __expf(e1);
        e2 = (e2 > 0.f) ? e2 : 0.2f * e2;  float w2 = __expf(e2);
        e3 = (e3 > 0.f) ? e3 : 0.2f * e3;  float w3 = __expf(e3);
        den += (w0 + w1) + (w2 + w3);
        acc0 += w0 * a0.x + w1 * a1.x + w2 * a2.x + w3 * a3.x;
        acc1 += w0 * a0.y + w1 * a1.y + w2 * a2.y + w3 * a3.y;
    }
    for (; p < pe; ++p) {
        int src = csr_src[p];
        float e = s_src[src] + sd;
        e = (e > 0.f) ? e : 0.2f * e;
        float wgt = __expf(e);
        den += wgt;
        float2 av = *((const float2*)(h + (size_t)src * 128) + lane);
        acc0 += wgt * av.x;
        acc1 += wgt * av.y;
    }
    float inv = 1.f / den;                    // self-loop guarantees den > 0
    float2 bv = *((const float2*)bias + lane);
    float v0 = acc0 * inv + bv.x;
    float v1 = acc1 * inv + bv.y;
    v0 = (v0 > 0.f) ? v0 : 0.2f * v0;
    v1 = (v1 > 0.f) ? v1 : 0.2f * v1;
    _Float16 h0 = (_Float16)v0, h1 = (_Float16)v1;
    size_t base = (size_t)node * 128 + 2 * lane;
    *(half2v*)(xh + base) = (half2v){h0, h1};
    *(half2v*)(xl + base) = (half2v){(_Float16)(v0 - (float)h0), (_Float16)(v1 - (float)h1)};
}

// ---------------- shared GEMM machinery (R2 structure — measured best) ----------
// 128x128 tile, 4 waves (2x2), each wave 64x64 = 4x4 of 16x16x32 MFMA. BK=32.
// Single-buffer LDS [4][128][32] + gload_lds width=16 staging; 2 __syncthreads
// per K-step. R3 dbuf regressed (m99/m100 null replicated). R6: counters show
// MfmaUtil+VALUBusy = 44% across 4 schedule variants -> 56% is wait; per-step
// 2700cy vs ~800cy intra-block path. Theory: co-resident blocks (5/CU at 32KB)
// are dispatched simultaneously with identical step lengths -> drains align ->
// CU-wide stall windows. Fix: pseudo-random per-block phase delay (s_sleep) so
// one block's MFMA covers another's drain.
__device__ __forceinline__ void gload_lds16(const void* g, void* l) {
    __builtin_amdgcn_global_load_lds(
        (const __attribute__((address_space(1))) void*)g,
        (__attribute__((address_space(3))) void*)l, 16, 0, 0);
}

// per-block phase stagger: hash(bid) -> 0..7 sleeps of ~512cy (spread ~0-3.6k cy
// ~ 0-2.7 K-steps). Pure timing, no correctness impact; ~0.4µs mean cost.
__device__ __forceinline__ void phase_stagger(int bid) {
    int ph = (int)(((unsigned)bid * 2654435761u) >> 29);
    for (int i = 0; i < ph; ++i) __builtin_amdgcn_s_sleep(8);
}

// ---------------- generic split-f16 MFMA GEMM (gemm0/gemm1: relu+split out) ----
__global__ __launch_bounds__(256) void k_mgemm(
    const _Float16* __restrict__ Ahi, const _Float16* __restrict__ Alo,
    const _Float16* __restrict__ Bhi, const _Float16* __restrict__ Blo,
    const float* __restrict__ bias, float* __restrict__ Cf,
    _Float16* __restrict__ Chi, _Float16* __restrict__ Clo,
    int M, int N, int K, int relu, int split, int nx, int ntiles)
{
    __shared__ _Float16 sm[4][128][32];   // 32 KiB: Ahi, Alo, Bhi, Blo

    int bid = blockIdx.x;
    int per = (ntiles + 7) >> 3;
    int g = (bid & 7) * per + (bid >> 3);
    if (g >= ntiles) return;
    int col0 = (g % nx) * 128;
    int row0 = (g / nx) * 128;

    phase_stagger(bid);

    int t = threadIdx.x;
    int w = t >> 6, lane = t & 63;
    int wm = (w & 1) * 64, wn = (w >> 1) * 64;
    int fr = lane & 15;
    int fq = lane >> 4, fq8 = fq * 8;

    int srow = (w << 5) + (lane >> 2);
    int scol = (lane & 3) << 3;          // halfs

    f32x4 acc[4][4];
    #pragma unroll
    for (int i = 0; i < 4; i++)
        #pragma unroll
        for (int j = 0; j < 4; j++) acc[i][j] = (f32x4){0.f, 0.f, 0.f, 0.f};

    for (int k0 = 0; k0 < K; k0 += 32) {
        if (k0) __syncthreads();
        #pragma unroll
        for (int i = 0; i < 2; ++i) {
            int rr = srow + i * 16;
            int ga = row0 + rr; if (ga > M - 1) ga = M - 1;  // M-tail: dup reads, rows guarded in epilogue
            int gb = col0 + rr;                               // N % 128 == 0 -> in range
            int lrow = (w << 5) + i * 16;                     // wave-uniform LDS base row
            gload_lds16(Ahi + (size_t)ga * K + k0 + scol, &sm[0][lrow][0]);
            gload_lds16(Alo + (size_t)ga * K + k0 + scol, &sm[1][lrow][0]);
            gload_lds16(Bhi + (size_t)gb * K + k0 + scol, &sm[2][lrow][0]);
            gload_lds16(Blo + (size_t)gb * K + k0 + scol, &sm[3][lrow][0]);
        }
        __syncthreads();   // drains vmcnt -> gload_lds stores visible to all waves

        half8 bh[4], bl[4];
        #pragma unroll
        for (int ni = 0; ni < 4; ++ni) {
            bh[ni] = *(half8*)&sm[2][wn + ni * 16 + fr][fq8];
            bl[ni] = *(half8*)&sm[3][wn + ni * 16 + fr][fq8];
        }
        #pragma unroll
        for (int mi = 0; mi < 4; ++mi) {
            half8 ah = *(half8*)&sm[0][wm + mi * 16 + fr][fq8];
            half8 al = *(half8*)&sm[1][wm + mi * 16 + fr][fq8];
            #pragma unroll
            for (int ni = 0; ni < 4; ++ni) {
                acc[mi][ni] = __builtin_amdgcn_mfma_f32_16x16x32_f16(ah, bh[ni], acc[mi][ni], 0, 0, 0);
                acc[mi][ni] = __builtin_amdgcn_mfma_f32_16x16x32_f16(ah, bl[ni], acc[mi][ni], 0, 0, 0);
                acc[mi][ni] = __builtin_amdgcn_mfma_f32_16x16x32_f16(al, bh[ni], acc[mi][ni], 0, 0, 0);
            }
        }
    }

    // epilogue: C/D layout col=lane&15, row=quad*4+reg
    #pragma unroll
    for (int ni = 0; ni < 4; ++ni) {
        int gc = col0 + wn + ni * 16 + fr;
        float bv = bias ? bias[gc] : 0.f;
        #pragma unroll
        for (int mi = 0; mi < 4; ++mi) {
            #pragma unroll
            for (int r = 0; r < 4; ++r) {
                int gr = row0 + wm + mi * 16 + fq * 4 + r;
                if (gr >= M) continue;
                float v = acc[mi][ni][r] + bv;
                if (relu) v = (v > 0.f) ? v : 0.f;
                size_t idx = (size_t)gr * N + gc;
                if (split) {
                    _Float16 hh = (_Float16)v;
                    Chi[idx] = hh;
                    Clo[idx] = (_Float16)(v - (float)hh);
                } else {
                    Cf[idx] = v;
                }
            }
        }
    }
}

// ---------------- GAT GEMM fused with attention scalars (N=K=128) ----------------
// R15: each block holds complete 128-wide rows of h=x@W in registers, so
// s_src[r]=h[r]·a_src and s_dst[r]=h[r]·a_dst are computed in the epilogue.
// No stagger here: 391 blocks = 1.5/CU (residency-starved regime, control).
__global__ __launch_bounds__(256) void k_mgemm_gat(
    const _Float16* __restrict__ Ahi, const _Float16* __restrict__ Alo,
    const _Float16* __restrict__ Bhi, const _Float16* __restrict__ Blo,
    const float* __restrict__ a_src, const float* __restrict__ a_dst,
    float* __restrict__ hbuf, float* __restrict__ s_src, float* __restrict__ s_dst,
    int M, int ntiles)
{
    __shared__ _Float16 sm[4][128][32];   // 32 KiB
    __shared__ float sps[2][128], spd[2][128];

    const int K = 128;
    int bid = blockIdx.x;
    int per = (ntiles + 7) >> 3;
    int g = (bid & 7) * per + (bid >> 3);
    if (g >= ntiles) return;
    int row0 = g * 128;                    // nx == 1 (N = 128)

    int t = threadIdx.x;
    int w = t >> 6, lane = t & 63;
    int wm = (w & 1) * 64, wn = (w >> 1) * 64;
    int fr = lane & 15;
    int fq = lane >> 4, fq8 = fq * 8;
    int wnIdx = w >> 1;

    int srow = (w << 5) + (lane >> 2);
    int scol = (lane & 3) << 3;

    f32x4 acc[4][4];
    #pragma unroll
    for (int i = 0; i < 4; i++)
        #pragma unroll
        for (int j = 0; j < 4; j++) acc[i][j] = (f32x4){0.f, 0.f, 0.f, 0.f};

    for (int k0 = 0; k0 < K; k0 += 32) {
        if (k0) __syncthreads();
        #pragma unroll
        for (int i = 0; i < 2; ++i) {
            int rr = srow + i * 16;
            int ga = row0 + rr; if (ga > M - 1) ga = M - 1;
            int gb = rr;                                      // col0 = 0, N = 128
            int lrow = (w << 5) + i * 16;
            gload_lds16(Ahi + (size_t)ga * K + k0 + scol, &sm[0][lrow][0]);
            gload_lds16(Alo + (size_t)ga * K + k0 + scol, &sm[1][lrow][0]);
            gload_lds16(Bhi + (size_t)gb * K + k0 + scol, &sm[2][lrow][0]);
            gload_lds16(Blo + (size_t)gb * K + k0 + scol, &sm[3][lrow][0]);
        }
        __syncthreads();

        half8 bh[4], bl[4];
        #pragma unroll
        for (int ni = 0; ni < 4; ++ni) {
            bh[ni] = *(half8*)&sm[2][wn + ni * 16 + fr][fq8];
            bl[ni] = *(half8*)&sm[3][wn + ni * 16 + fr][fq8];
        }
        #pragma unroll
        for (int mi = 0; mi < 4; ++mi) {
            half8 ah = *(half8*)&sm[0][wm + mi * 16 + fr][fq8];
            half8 al = *(half8*)&sm[1][wm + mi * 16 + fr][fq8];
            #pragma unroll
            for (int ni = 0; ni < 4; ++ni) {
                acc[mi][ni] = __builtin_amdgcn_mfma_f32_16x16x32_f16(ah, bh[ni], acc[mi][ni], 0, 0, 0);
                acc[mi][ni] = __builtin_amdgcn_mfma_f32_16x16x32_f16(ah, bl[ni], acc[mi][ni], 0, 0, 0);
                acc[mi][ni] = __builtin_amdgcn_mfma_f32_16x16x32_f16(al, bh[ni], acc[mi][ni], 0, 0, 0);
            }
        }
    }

    // epilogue: write hbuf (fp32) + fused attention scalar dots
    float asv[4], adv[4];
    #pragma unroll
    for (int ni = 0; ni < 4; ++ni) {
        int gc = wn + ni * 16 + fr;
        asv[ni] = a_src[gc];
        adv[ni] = a_dst[gc];
    }
    #pragma unroll
    for (int mi = 0; mi < 4; ++mi) {
        #pragma unroll
        for (int r = 0; r < 4; ++r) {
            int lrow = wm + mi * 16 + fq * 4 + r;
            int gr = row0 + lrow;
            float vps = 0.f, vpd = 0.f;
            #pragma unroll
            for (int ni = 0; ni < 4; ++ni) {
                float v = acc[mi][ni][r];
                vps += v * asv[ni];
                vpd += v * adv[ni];
                if (gr < M) hbuf[(size_t)gr * 128 + wn + ni * 16 + fr] = v;
            }
            // reduce over 16 fr lanes (xor < 16 stays within quad group)
            #pragma unroll
            for (int off = 1; off < 16; off <<= 1) {
                vps += __shfl_xor(vps, off);
                vpd += __shfl_xor(vpd, off);
            }
            if (fr == 0) { sps[wnIdx][lrow] = vps; spd[wnIdx][lrow] = vpd; }
        }
    }
    __syncthreads();
    if (t < 128) {
        int gr = row0 + t;
        if (gr < M) {
            s_src[gr] = sps[0][t] + sps[1][t];
            s_dst[gr] = spd[0][t] + spd[1][t];
        }
    }
}

// ---------------- gemm2 fused with MLP head (N=512, partials out, NO atomics) -----
// R16: per-block partials (coalesced float4) + k_headred reduce; R4's atomic
// epilogue cost 27µs (WRITE 45MB fabric traffic). partial: [ct][M][4] floats.
__global__ __launch_bounds__(256) void k_mgemm_head(
    const _Float16* __restrict__ Ahi, const _Float16* __restrict__ Alo,
    const _Float16* __restrict__ Bhi, const _Float16* __restrict__ Blo,
    const float* __restrict__ bias, const float* __restrict__ Wo,
    float* __restrict__ partial,
    int M, int K, int nx, int ntiles)
{
    __shared__ _Float16 sm[4][128][32];   // 32 KiB
    __shared__ float4 sacc[2][128];       // 4 KiB: per-wn-half row partials

    int bid = blockIdx.x;
    int per = (ntiles + 7) >> 3;
    int g = (bid & 7) * per + (bid >> 3);
    if (g >= ntiles) return;
    int ct = g % nx;
    int col0 = ct * 128;
    int row0 = (g / nx) * 128;

    phase_stagger(bid);

    int t = threadIdx.x;
    int w = t >> 6, lane = t & 63;
    int wm = (w & 1) * 64, wn = (w >> 1) * 64;
    int fr = lane & 15;
    int fq = lane >> 4, fq8 = fq * 8;

    int srow = (w << 5) + (lane >> 2);
    int scol = (lane & 3) << 3;

    f32x4 acc[4][4];
    #pragma unroll
    for (int i = 0; i < 4; i++)
        #pragma unroll
        for (int j = 0; j < 4; j++) acc[i][j] = (f32x4){0.f, 0.f, 0.f, 0.f};

    for (int k0 = 0; k0 < K; k0 += 32) {
        if (k0) __syncthreads();
        #pragma unroll
        for (int i = 0; i < 2; ++i) {
            int rr = srow + i * 16;
            int ga = row0 + rr; if (ga > M - 1) ga = M - 1;
            int gb = col0 + rr;
            int lrow = (w << 5) + i * 16;
            gload_lds16(Ahi + (size_t)ga * K + k0 + scol, &sm[0][lrow][0]);
            gload_lds16(Alo + (size_t)ga * K + k0 + scol, &sm[1][lrow][0]);
            gload_lds16(Bhi + (size_t)gb * K + k0 + scol, &sm[2][lrow][0]);
            gload_lds16(Blo + (size_t)gb * K + k0 + scol, &sm[3][lrow][0]);
        }
        __syncthreads();

        half8 bh[4], bl[4];
        #pragma unroll
        for (int ni = 0; ni < 4; ++ni) {
            bh[ni] = *(half8*)&sm[2][wn + ni * 16 + fr][fq8];
            bl[ni] = *(half8*)&sm[3][wn + ni * 16 + fr][fq8];
        }
        #pragma unroll
        for (int mi = 0; mi < 4; ++mi) {
            half8 ah = *(half8*)&sm[0][wm + mi * 16 + fr][fq8];
            half8 al = *(half8*)&sm[1][wm + mi * 16 + fr][fq8];
            #pragma unroll
            for (int ni = 0; ni < 4; ++ni) {
                acc[mi][ni] = __builtin_amdgcn_mfma_f32_16x16x32_f16(ah, bh[ni], acc[mi][ni], 0, 0, 0);
                acc[mi][ni] = __builtin_amdgcn_mfma_f32_16x16x32_f16(ah, bl[ni], acc[mi][ni], 0, 0, 0);
                acc[mi][ni] = __builtin_amdgcn_mfma_f32_16x16x32_f16(al, bh[ni], acc[mi][ni], 0, 0, 0);
            }
        }
    }

    // epilogue: relu(acc+b2) contracted with Wo -> LDS combine -> partial write
    float bv[4];
    float4 wv[4];
    #pragma unroll
    for (int ni = 0; ni < 4; ++ni) {
        int gc = col0 + wn + ni * 16 + fr;
        bv[ni] = bias[gc];
        wv[ni] = *(const float4*)(Wo + (size_t)gc * 4);
    }
    #pragma unroll
    for (int mi = 0; mi < 4; ++mi) {
        #pragma unroll
        for (int r = 0; r < 4; ++r) {
            int lrow = wm + mi * 16 + fq * 4 + r;
            float o0 = 0.f, o1 = 0.f, o2 = 0.f, o3 = 0.f;
            #pragma unroll
            for (int ni = 0; ni < 4; ++ni) {
                float v = acc[mi][ni][r] + bv[ni];
                v = (v > 0.f) ? v : 0.f;
                o0 += v * wv[ni].x; o1 += v * wv[ni].y;
                o2 += v * wv[ni].z; o3 += v * wv[ni].w;
            }
            #pragma unroll
            for (int off = 1; off < 16; off <<= 1) {
                o0 += __shfl_xor(o0, off); o1 += __shfl_xor(o1, off);
                o2 += __shfl_xor(o2, off); o3 += __shfl_xor(o3, off);
            }
            if (fr == 0) sacc[w >> 1][lrow] = (float4){o0, o1, o2, o3};
        }
    }
    __syncthreads();
    if (t < 128) {
        int gr = row0 + t;
        if (gr < M) {
            float4 s0 = sacc[0][t], s1 = sacc[1][t];
            float4 o = (float4){s0.x + s1.x, s0.y + s1.y, s0.z + s1.z, s0.w + s1.w};
            *(float4*)(partial + ((size_t)ct * M + gr) * 4) = o;
        }
    }
}

// ---------------- reduce 4 col-tile partials -> out (adds bo) ----------------
__global__ __launch_bounds__(256) void k_headred(const float* __restrict__ partial,
                                                 const float* __restrict__ bo,
                                                 float* __restrict__ out, int M) {
    int r = blockIdx.x * 256 + threadIdx.x;
    if (r >= M) return;
    float4 a = *(const float4*)(partial + ((size_t)0 * M + r) * 4);
    float4 b = *(const float4*)(partial + ((size_t)1 * M + r) * 4);
    float4 c = *(const float4*)(partial + ((size_t)2 * M + r) * 4);
    float4 d = *(const float4*)(partial + ((size_t)3 * M + r) * 4);
    float4 o;
    o.x = a.x + b.x + c.x + d.x + bo[0];
    o.y = a.y + b.y + c.y + d.y + bo[1];
    o.z = a.z + b.z + c.z + d.z + bo[2];
    o.w = a.w + b.w + c.w + d.w + bo[3];
    *(float4*)(out + (size_t)r * 4) = o;
}

extern "C" void kernel_launch(void* const* d_in, const int* in_sizes, int n_in,
                              void* d_out, int out_size, void* d_ws, size_t ws_size,
                              hipStream_t stream) {
    const float* x    = (const float*)d_in[0];
    const int*   eidx = (const int*)d_in[1];
    const float* cW   = (const float*)d_in[2];
    const float* caS  = (const float*)d_in[3];
    const float* caD  = (const float*)d_in[4];
    const float* cB   = (const float*)d_in[5];
    const float* W0   = (const float*)d_in[6];
    const float* b0   = (const float*)d_in[7];
    const float* W1   = (const float*)d_in[8];
    const float* b1   = (const float*)d_in[9];
    const float* W2   = (const float*)d_in[10];
    const float* b2   = (const float*)d_in[11];
    const float* Wo   = (const float*)d_in[12];
    const float* bo   = (const float*)d_in[13];
    (void)in_sizes; (void)n_in; (void)out_size;

    const int* esrc = eidx;
    const int* edst = eidx + NE;
    float* out = (float*)d_out;

    // ---- workspace bump allocator (256B aligned) ----
    char* w = (char*)d_ws;
    auto alloc = [&](size_t bytes) -> char* {
        char* p = w;
        w += (bytes + 255) & ~(size_t)255;
        return p;
    };
    _Float16* x0h  = (_Float16*)alloc((size_t)NN * 128 * 2);
    _Float16* x0l  = (_Float16*)alloc((size_t)NN * 128 * 2);
    _Float16* xh   = (_Float16*)alloc((size_t)NN * 128 * 2);
    _Float16* xl   = (_Float16*)alloc((size_t)NN * 128 * 2);
    float* hbuf    = (float*)alloc((size_t)NN * 128 * 4);
    float* ssrc    = (float*)alloc((size_t)NN * 4);
    float* sdst    = (float*)alloc((size_t)NN * 4);
    int*   counts  = (int*)  alloc((size_t)NN * 4);
    int*   offs    = (int*)  alloc((size_t)(NN + 1) * 4);
    int*   cursor  = (int*)  alloc((size_t)NN * 4);
    int*   csr     = (int*)  alloc((size_t)NET * 4);
    int*   part    = (int*)  alloc((size_t)SCAN_NB * 4);
    _Float16* cwh  = (_Float16*)alloc(3 * 128 * 128 * 2);
    _Float16* cwl  = (_Float16*)alloc(3 * 128 * 128 * 2);
    _Float16* w0h  = (_Float16*)alloc(512 * 128 * 2);
    _Float16* w0l  = (_Float16*)alloc(512 * 128 * 2);
    _Float16* w1h  = (_Float16*)alloc(512 * 512 * 2);
    _Float16* w1l  = (_Float16*)alloc(512 * 512 * 2);
    _Float16* w2h  = (_Float16*)alloc(512 * 512 * 2);
    _Float16* w2l  = (_Float16*)alloc(512 * 512 * 2);
    float* hpart   = (float*)alloc((size_t)4 * NN * 4 * 4);   // head partials [4][NN][4]

    size_t used = (size_t)(w - (char*)d_ws);
    size_t rem = (ws_size > used) ? (ws_size - used) : 0;
    int chunk = (int)(rem / (4 * 512 * sizeof(_Float16)));
    if (chunk > NN) chunk = NN;
    if (chunk > 128) chunk &= ~127;
    if (chunk < 1) chunk = 1;
    _Float16* Y0h = (_Float16*)alloc((size_t)chunk * 512 * 2);
    _Float16* Y0l = (_Float16*)alloc((size_t)chunk * 512 * 2);
    _Float16* Y1h = (_Float16*)alloc((size_t)chunk * 512 * 2);
    _Float16* Y1l = (_Float16*)alloc((size_t)chunk * 512 * 2);

    auto gemm = [&](const _Float16* Ah, const _Float16* Al,
                    const _Float16* Bh, const _Float16* Bl,
                    const float* bias, float* Cf, _Float16* Ch, _Float16* Cl,
                    int M, int N, int K, int relu, int split) {
        int nx = N / 128;
        int ntiles = nx * ((M + 127) / 128);
        int nb = ((ntiles + 7) / 8) * 8;
        k_mgemm<<<nb, 256, 0, stream>>>(Ah, Al, Bh, Bl, bias, Cf, Ch, Cl,
                                        M, N, K, relu, split, nx, ntiles);
    };

    // ---- prep: split x, transpose+split weights ----
    k_split<<<2048, 256, 0, stream>>>(x, x0h, x0l, NN * 128);
    for (int L = 0; L < 3; ++L)
        k_prepw<<<dim3(128 / 32, 128 / 32), 256, 0, stream>>>(
            cW + (size_t)L * 128 * 128, cwh + (size_t)L * 128 * 128, cwl + (size_t)L * 128 * 128, 128, 128);
    k_prepw<<<dim3(512 / 32, 128 / 32), 256, 0, stream>>>(W0, w0h, w0l, 128, 512);
    k_prepw<<<dim3(512 / 32, 512 / 32), 256, 0, stream>>>(W1, w1h, w1l, 512, 512);
    k_prepw<<<dim3(512 / 32, 512 / 32), 256, 0, stream>>>(W2, w2h, w2l, 512, 512);

    // ---- build CSR once ----
    hipMemsetAsync(counts, 0, (size_t)NN * 4, stream);
    int eblocks = (NET + 255) / 256;
    k_count <<<eblocks, 256, 0, stream>>>(edst, counts);
    k_scan1 <<<SCAN_NB, 256, 0, stream>>>(counts, part);
    k_scan2 <<<1, 256, 0, stream>>>(part, offs);
    k_scan3 <<<SCAN_NB, 256, 0, stream>>>(counts, part, offs, cursor);
    k_scatter<<<eblocks, 256, 0, stream>>>(esrc, edst, cursor, csr);

    // ---- 3 GAT layers (GEMM fused with attention scalars) ----
    int gat_tiles = (NN + 127) / 128;
    int gat_nb = ((gat_tiles + 7) / 8) * 8;
    for (int L = 0; L < 3; ++L) {
        const _Float16* Ah = (L == 0) ? x0h : xh;
        const _Float16* Al = (L == 0) ? x0l : xl;
        k_mgemm_gat<<<gat_nb, 256, 0, stream>>>(
            Ah, Al, cwh + (size_t)L * 128 * 128, cwl + (size_t)L * 128 * 128,
            caS + L * 128, caD + L * 128, hbuf, ssrc, sdst, NN, gat_tiles);
        k_aggregate<<<NN / 4, 256, 0, stream>>>(hbuf, ssrc, sdst, offs, csr, cB + L * 128, xh, xl);
    }

    // ---- MLP head (chunked over nodes; gemm2 fused with output head) ----
    for (int m0 = 0; m0 < NN; m0 += chunk) {
        int cm = imin(chunk, NN - m0);
        gemm(xh + (size_t)m0 * 128, xl + (size_t)m0 * 128, w0h, w0l, b0,
             nullptr, Y0h, Y0l, cm, 512, 128, 1, 1);
        gemm(Y0h, Y0l, w1h, w1l, b1, nullptr, Y1h, Y1l, cm, 512, 512, 1, 1);
        int nx = 4;
        int ntiles = nx * ((cm + 127) / 128);
        int nb = ((ntiles + 7) / 8) * 8;
        k_mgemm_head<<<nb, 256, 0, stream>>>(Y1h, Y1l, w2h, w2l, b2, Wo,
                                             hpart, cm, 512, nx, ntiles);
        k_headred<<<(cm + 255) / 256, 256, 0, stream>>>(hpart, bo, out + (size_t)m0 * 4, cm);
    }
}

// Round 7
// 708.242 us; speedup vs baseline: 1.2425x; 1.0557x over previous
//
#include <hip/hip_runtime.h>
#include <hip/hip_bf16.h>

#define NN 50000
#define NE 800000
#define NET (NE + NN)
#define SCAN_NB ((NN + 255) / 256)   // 196

static inline int imin(int a, int b) { return a < b ? a : b; }

typedef _Float16 half8 __attribute__((ext_vector_type(8)));
typedef _Float16 half2v __attribute__((ext_vector_type(2)));
typedef float f32x4 __attribute__((ext_vector_type(4)));

// ---------------- CSR build (graph constant across layers) ----------------
__global__ void k_count(const int* __restrict__ edst, int* __restrict__ counts) {
    int e = blockIdx.x * blockDim.x + threadIdx.x;
    if (e >= NET) return;
    int d = (e < NE) ? edst[e] : (e - NE);   // self loops appended
    atomicAdd(&counts[d], 1);
}

__global__ __launch_bounds__(256) void k_scan1(const int* __restrict__ counts,
                                               int* __restrict__ part) {
    __shared__ int s[256];
    int t = threadIdx.x, i = blockIdx.x * 256 + t;
    s[t] = (i < NN) ? counts[i] : 0;
    __syncthreads();
    for (int off = 128; off > 0; off >>= 1) {
        if (t < off) s[t] += s[t + off];
        __syncthreads();
    }
    if (t == 0) part[blockIdx.x] = s[0];
}

__global__ __launch_bounds__(256) void k_scan2(int* __restrict__ part, int* __restrict__ offs) {
    __shared__ int s[256];
    int t = threadIdx.x;
    int v = (t < SCAN_NB) ? part[t] : 0;
    s[t] = v;
    __syncthreads();
    for (int off = 1; off < 256; off <<= 1) {
        int a = (t >= off) ? s[t - off] : 0;
        __syncthreads();
        s[t] += a;
        __syncthreads();
    }
    if (t < SCAN_NB) part[t] = s[t] - v;     // exclusive block offsets
    if (t == 255) offs[NN] = s[255];         // total (= NET)
}

__global__ __launch_bounds__(256) void k_scan3(const int* __restrict__ counts,
                                               const int* __restrict__ part,
                                               int* __restrict__ offs, int* __restrict__ cursor) {
    __shared__ int s[256];
    int t = threadIdx.x, i = blockIdx.x * 256 + t;
    int v = (i < NN) ? counts[i] : 0;
    s[t] = v;
    __syncthreads();
    for (int off = 1; off < 256; off <<= 1) {
        int a = (t >= off) ? s[t - off] : 0;
        __syncthreads();
        s[t] += a;
        __syncthreads();
    }
    if (i < NN) {
        int e = part[blockIdx.x] + s[t] - v;
        offs[i] = e;
        cursor[i] = e;
    }
}

__global__ void k_scatter(const int* __restrict__ esrc, const int* __restrict__ edst,
                          int* __restrict__ cursor, int* __restrict__ csr_src) {
    int e = blockIdx.x * blockDim.x + threadIdx.x;
    if (e >= NET) return;
    int s, d;
    if (e < NE) { s = esrc[e]; d = edst[e]; } else { s = e - NE; d = s; }
    int pos = atomicAdd(&cursor[d], 1);
    csr_src[pos] = s;
}

// ---------------- split fp32 -> f16 hi/lo pair ----------------
__global__ void k_split(const float* __restrict__ in, _Float16* __restrict__ hi,
                        _Float16* __restrict__ lo, int n) {
    int i = blockIdx.x * blockDim.x + threadIdx.x;
    int st = gridDim.x * blockDim.x;
    for (; i < n; i += st) {
        float v = in[i];
        _Float16 h = (_Float16)v;
        hi[i] = h;
        lo[i] = (_Float16)(v - (float)h);
    }
}

// ---------------- transpose + split weights: W[K][N] -> T[N][K] hi/lo (LDS-tiled) ----
__global__ __launch_bounds__(256) void k_prepw(const float* __restrict__ W,
                                               _Float16* __restrict__ Th,
                                               _Float16* __restrict__ Tl, int K, int N) {
    __shared__ float tile[32][33];
    int tx = threadIdx.x & 31, ty = threadIdx.x >> 5;
    int n0 = blockIdx.x * 32, k0 = blockIdx.y * 32;
    #pragma unroll
    for (int r = ty; r < 32; r += 8)
        tile[r][tx] = W[(size_t)(k0 + r) * N + n0 + tx];   // coalesced read
    __syncthreads();
    #pragma unroll
    for (int r = ty; r < 32; r += 8) {
        int n = n0 + r, k = k0 + tx;
        float v = tile[tx][r];
        _Float16 h = (_Float16)v;
        Th[(size_t)n * K + k] = h;                          // coalesced 64B segments
        Tl[(size_t)n * K + k] = (_Float16)(v - (float)h);
    }
}

// ---------------- fused segment-softmax + aggregate + bias + leaky ----------------
// R17: hbuf is f16 (was fp32). hbuf's ONLY consumer is this weighted sum
// (scalars moved into the GEMM epilogue in R4, read acc not hbuf), so the
// precision cost is ~2.8e-4 RMS on h -> est ~1e-3 final absmax. Traffic:
// gather 435->218 MB/layer, hbuf write 51->26 MB/layer. Sum stays fp32.
__global__ void k_aggregate(const _Float16* __restrict__ h, const float* __restrict__ s_src,
                            const float* __restrict__ s_dst, const int* __restrict__ offs,
                            const int* __restrict__ csr_src, const float* __restrict__ bias,
                            _Float16* __restrict__ xh, _Float16* __restrict__ xl) {
    int node = blockIdx.x * 4 + (threadIdx.x >> 6);
    int lane = threadIdx.x & 63;
    if (node >= NN) return;
    int p = offs[node], pe = offs[node + 1];
    float sd = s_dst[node];
    float den = 0.f, acc0 = 0.f, acc1 = 0.f;
    for (; p + 4 <= pe; p += 4) {
        int s0 = csr_src[p + 0], s1 = csr_src[p + 1];
        int s2 = csr_src[p + 2], s3 = csr_src[p + 3];
        float e0 = s_src[s0] + sd, e1 = s_src[s1] + sd;
        float e2 = s_src[s2] + sd, e3 = s_src[s3] + sd;
        half2v a0 = *((const half2v*)(h + (size_t)s0 * 128) + lane);
        half2v a1 = *((const half2v*)(h + (size_t)s1 * 128) + lane);
        half2v a2 = *((const half2v*)(h + (size_t)s2 * 128) + lane);
        half2v a3 = *((const half2v*)(h + (size_t)s3 * 128) + lane);
        e0 = (e0 > 0.f) ? e0 : 0.2f * e0;  float w0 = __expf(e0);
        e1 = (e1 > 0.f) ? e1 : 0.2f * e1;  float w1 = __expf(e1);
        e2 = (e2 > 0.f) ? e2 : 0.2f * e2;  float w2 = __expf(e2);
        e3 = (e3 > 0.f) ? e3 : 0.2f * e3;  float w3 = __expf(e3);
        den += (w0 + w1) + (w2 + w3);
        acc0 += w0 * (float)a0[0] + w1 * (float)a1[0] + w2 * (float)a2[0] + w3 * (float)a3[0];
        acc1 += w0 * (float)a0[1] + w1 * (float)a1[1] + w2 * (float)a2[1] + w3 * (float)a3[1];
    }
    for (; p < pe; ++p) {
        int src = csr_src[p];
        float e = s_src[src] + sd;
        e = (e > 0.f) ? e : 0.2f * e;
        float wgt = __expf(e);
        den += wgt;
        half2v av = *((const half2v*)(h + (size_t)src * 128) + lane);
        acc0 += wgt * (float)av[0];
        acc1 += wgt * (float)av[1];
    }
    float inv = 1.f / den;                    // self-loop guarantees den > 0
    float2 bv = *((const float2*)bias + lane);
    float v0 = acc0 * inv + bv.x;
    float v1 = acc1 * inv + bv.y;
    v0 = (v0 > 0.f) ? v0 : 0.2f * v0;
    v1 = (v1 > 0.f) ? v1 : 0.2f * v1;
    _Float16 h0 = (_Float16)v0, h1 = (_Float16)v1;
    size_t base = (size_t)node * 128 + 2 * lane;
    *(half2v*)(xh + base) = (half2v){h0, h1};
    *(half2v*)(xl + base) = (half2v){(_Float16)(v0 - (float)h0), (_Float16)(v1 - (float)h1)};
}

// ---------------- shared GEMM machinery (R2 structure — measured best) ----------
// 128x128 tile, 4 waves (2x2), each wave 64x64 = 4x4 of 16x16x32 MFMA. BK=32.
// Single-buffer LDS [4][128][32] + gload_lds width=16 staging; 2 __syncthreads
// per K-step. R3 dbuf regressed (m99/m100 null replicated). R6 stagger ~null
// (-11µs wall): lockstep theory not confirmed; kept (free).
__device__ __forceinline__ void gload_lds16(const void* g, void* l) {
    __builtin_amdgcn_global_load_lds(
        (const __attribute__((address_space(1))) void*)g,
        (__attribute__((address_space(3))) void*)l, 16, 0, 0);
}

// per-block phase stagger: hash(bid) -> 0..7 sleeps of ~512cy. ~free, tiny win.
__device__ __forceinline__ void phase_stagger(int bid) {
    int ph = (int)(((unsigned)bid * 2654435761u) >> 29);
    for (int i = 0; i < ph; ++i) __builtin_amdgcn_s_sleep(8);
}

// ---------------- generic split-f16 MFMA GEMM (gemm0/gemm1: relu+split out) ----
__global__ __launch_bounds__(256) void k_mgemm(
    const _Float16* __restrict__ Ahi, const _Float16* __restrict__ Alo,
    const _Float16* __restrict__ Bhi, const _Float16* __restrict__ Blo,
    const float* __restrict__ bias, float* __restrict__ Cf,
    _Float16* __restrict__ Chi, _Float16* __restrict__ Clo,
    int M, int N, int K, int relu, int split, int nx, int ntiles)
{
    __shared__ _Float16 sm[4][128][32];   // 32 KiB: Ahi, Alo, Bhi, Blo

    int bid = blockIdx.x;
    int per = (ntiles + 7) >> 3;
    int g = (bid & 7) * per + (bid >> 3);
    if (g >= ntiles) return;
    int col0 = (g % nx) * 128;
    int row0 = (g / nx) * 128;

    phase_stagger(bid);

    int t = threadIdx.x;
    int w = t >> 6, lane = t & 63;
    int wm = (w & 1) * 64, wn = (w >> 1) * 64;
    int fr = lane & 15;
    int fq = lane >> 4, fq8 = fq * 8;

    int srow = (w << 5) + (lane >> 2);
    int scol = (lane & 3) << 3;          // halfs

    f32x4 acc[4][4];
    #pragma unroll
    for (int i = 0; i < 4; i++)
        #pragma unroll
        for (int j = 0; j < 4; j++) acc[i][j] = (f32x4){0.f, 0.f, 0.f, 0.f};

    for (int k0 = 0; k0 < K; k0 += 32) {
        if (k0) __syncthreads();
        #pragma unroll
        for (int i = 0; i < 2; ++i) {
            int rr = srow + i * 16;
            int ga = row0 + rr; if (ga > M - 1) ga = M - 1;  // M-tail: dup reads, rows guarded in epilogue
            int gb = col0 + rr;                               // N % 128 == 0 -> always in range
            int lrow = (w << 5) + i * 16;                     // wave-uniform LDS base row
            gload_lds16(Ahi + (size_t)ga * K + k0 + scol, &sm[0][lrow][0]);
            gload_lds16(Alo + (size_t)ga * K + k0 + scol, &sm[1][lrow][0]);
            gload_lds16(Bhi + (size_t)gb * K + k0 + scol, &sm[2][lrow][0]);
            gload_lds16(Blo + (size_t)gb * K + k0 + scol, &sm[3][lrow][0]);
        }
        __syncthreads();   // drains vmcnt -> gload_lds stores visible to all waves

        half8 bh[4], bl[4];
        #pragma unroll
        for (int ni = 0; ni < 4; ++ni) {
            bh[ni] = *(half8*)&sm[2][wn + ni * 16 + fr][fq8];
            bl[ni] = *(half8*)&sm[3][wn + ni * 16 + fr][fq8];
        }
        #pragma unroll
        for (int mi = 0; mi < 4; ++mi) {
            half8 ah = *(half8*)&sm[0][wm + mi * 16 + fr][fq8];
            half8 al = *(half8*)&sm[1][wm + mi * 16 + fr][fq8];
            #pragma unroll
            for (int ni = 0; ni < 4; ++ni) {
                acc[mi][ni] = __builtin_amdgcn_mfma_f32_16x16x32_f16(ah, bh[ni], acc[mi][ni], 0, 0, 0);
                acc[mi][ni] = __builtin_amdgcn_mfma_f32_16x16x32_f16(ah, bl[ni], acc[mi][ni], 0, 0, 0);
                acc[mi][ni] = __builtin_amdgcn_mfma_f32_16x16x32_f16(al, bh[ni], acc[mi][ni], 0, 0, 0);
            }
        }
    }

    // epilogue: C/D layout col=lane&15, row=quad*4+reg
    #pragma unroll
    for (int ni = 0; ni < 4; ++ni) {
        int gc = col0 + wn + ni * 16 + fr;
        float bv = bias ? bias[gc] : 0.f;
        #pragma unroll
        for (int mi = 0; mi < 4; ++mi) {
            #pragma unroll
            for (int r = 0; r < 4; ++r) {
                int gr = row0 + wm + mi * 16 + fq * 4 + r;
                if (gr >= M) continue;
                float v = acc[mi][ni][r] + bv;
                if (relu) v = (v > 0.f) ? v : 0.f;
                size_t idx = (size_t)gr * N + gc;
                if (split) {
                    _Float16 hh = (_Float16)v;
                    Chi[idx] = hh;
                    Clo[idx] = (_Float16)(v - (float)hh);
                } else {
                    Cf[idx] = v;
                }
            }
        }
    }
}

// ---------------- GAT GEMM fused with attention scalars (N=K=128) ----------------
// R15: scalars in epilogue (4 FMA/lane + 16-lane reduce + LDS combine).
// R17: hbuf stored f16 (write traffic 51->26 MB/layer).
__global__ __launch_bounds__(256) void k_mgemm_gat(
    const _Float16* __restrict__ Ahi, const _Float16* __restrict__ Alo,
    const _Float16* __restrict__ Bhi, const _Float16* __restrict__ Blo,
    const float* __restrict__ a_src, const float* __restrict__ a_dst,
    _Float16* __restrict__ hbuf, float* __restrict__ s_src, float* __restrict__ s_dst,
    int M, int ntiles)
{
    __shared__ _Float16 sm[4][128][32];   // 32 KiB
    __shared__ float sps[2][128], spd[2][128];

    const int K = 128;
    int bid = blockIdx.x;
    int per = (ntiles + 7) >> 3;
    int g = (bid & 7) * per + (bid >> 3);
    if (g >= ntiles) return;
    int row0 = g * 128;                    // nx == 1 (N = 128)

    int t = threadIdx.x;
    int w = t >> 6, lane = t & 63;
    int wm = (w & 1) * 64, wn = (w >> 1) * 64;
    int fr = lane & 15;
    int fq = lane >> 4, fq8 = fq * 8;
    int wnIdx = w >> 1;

    int srow = (w << 5) + (lane >> 2);
    int scol = (lane & 3) << 3;

    f32x4 acc[4][4];
    #pragma unroll
    for (int i = 0; i < 4; i++)
        #pragma unroll
        for (int j = 0; j < 4; j++) acc[i][j] = (f32x4){0.f, 0.f, 0.f, 0.f};

    for (int k0 = 0; k0 < K; k0 += 32) {
        if (k0) __syncthreads();
        #pragma unroll
        for (int i = 0; i < 2; ++i) {
            int rr = srow + i * 16;
            int ga = row0 + rr; if (ga > M - 1) ga = M - 1;
            int gb = rr;                                      // col0 = 0, N = 128
            int lrow = (w << 5) + i * 16;
            gload_lds16(Ahi + (size_t)ga * K + k0 + scol, &sm[0][lrow][0]);
            gload_lds16(Alo + (size_t)ga * K + k0 + scol, &sm[1][lrow][0]);
            gload_lds16(Bhi + (size_t)gb * K + k0 + scol, &sm[2][lrow][0]);
            gload_lds16(Blo + (size_t)gb * K + k0 + scol, &sm[3][lrow][0]);
        }
        __syncthreads();

        half8 bh[4], bl[4];
        #pragma unroll
        for (int ni = 0; ni < 4; ++ni) {
            bh[ni] = *(half8*)&sm[2][wn + ni * 16 + fr][fq8];
            bl[ni] = *(half8*)&sm[3][wn + ni * 16 + fr][fq8];
        }
        #pragma unroll
        for (int mi = 0; mi < 4; ++mi) {
            half8 ah = *(half8*)&sm[0][wm + mi * 16 + fr][fq8];
            half8 al = *(half8*)&sm[1][wm + mi * 16 + fr][fq8];
            #pragma unroll
            for (int ni = 0; ni < 4; ++ni) {
                acc[mi][ni] = __builtin_amdgcn_mfma_f32_16x16x32_f16(ah, bh[ni], acc[mi][ni], 0, 0, 0);
                acc[mi][ni] = __builtin_amdgcn_mfma_f32_16x16x32_f16(ah, bl[ni], acc[mi][ni], 0, 0, 0);
                acc[mi][ni] = __builtin_amdgcn_mfma_f32_16x16x32_f16(al, bh[ni], acc[mi][ni], 0, 0, 0);
            }
        }
    }

    // epilogue: write hbuf (f16) + fused attention scalar dots (fp32 from acc)
    float asv[4], adv[4];
    #pragma unroll
    for (int ni = 0; ni < 4; ++ni) {
        int gc = wn + ni * 16 + fr;
        asv[ni] = a_src[gc];
        adv[ni] = a_dst[gc];
    }
    #pragma unroll
    for (int mi = 0; mi < 4; ++mi) {
        #pragma unroll
        for (int r = 0; r < 4; ++r) {
            int lrow = wm + mi * 16 + fq * 4 + r;
            int gr = row0 + lrow;
            float vps = 0.f, vpd = 0.f;
            #pragma unroll
            for (int ni = 0; ni < 4; ++ni) {
                float v = acc[mi][ni][r];
                vps += v * asv[ni];
                vpd += v * adv[ni];
                if (gr < M) hbuf[(size_t)gr * 128 + wn + ni * 16 + fr] = (_Float16)v;
            }
            // reduce over 16 fr lanes (xor < 16 stays within quad group)
            #pragma unroll
            for (int off = 1; off < 16; off <<= 1) {
                vps += __shfl_xor(vps, off);
                vpd += __shfl_xor(vpd, off);
            }
            if (fr == 0) { sps[wnIdx][lrow] = vps; spd[wnIdx][lrow] = vpd; }
        }
    }
    __syncthreads();
    if (t < 128) {
        int gr = row0 + t;
        if (gr < M) {
            s_src[gr] = sps[0][t] + sps[1][t];
            s_dst[gr] = spd[0][t] + spd[1][t];
        }
    }
}

// ---------------- gemm2 fused with MLP head (N=512, partials out, NO atomics) -----
// R16: per-block partials (coalesced float4) + k_headred reduce; R4's atomic
// epilogue cost 27µs (WRITE 45MB fabric traffic). partial: [ct][M][4] floats.
__global__ __launch_bounds__(256) void k_mgemm_head(
    const _Float16* __restrict__ Ahi, const _Float16* __restrict__ Alo,
    const _Float16* __restrict__ Bhi, const _Float16* __restrict__ Blo,
    const float* __restrict__ bias, const float* __restrict__ Wo,
    float* __restrict__ partial,
    int M, int K, int nx, int ntiles)
{
    __shared__ _Float16 sm[4][128][32];   // 32 KiB
    __shared__ float4 sacc[2][128];       // 4 KiB: per-wn-half row partials

    int bid = blockIdx.x;
    int per = (ntiles + 7) >> 3;
    int g = (bid & 7) * per + (bid >> 3);
    if (g >= ntiles) return;
    int ct = g % nx;
    int col0 = ct * 128;
    int row0 = (g / nx) * 128;

    phase_stagger(bid);

    int t = threadIdx.x;
    int w = t >> 6, lane = t & 63;
    int wm = (w & 1) * 64, wn = (w >> 1) * 64;
    int fr = lane & 15;
    int fq = lane >> 4, fq8 = fq * 8;

    int srow = (w << 5) + (lane >> 2);
    int scol = (lane & 3) << 3;

    f32x4 acc[4][4];
    #pragma unroll
    for (int i = 0; i < 4; i++)
        #pragma unroll
        for (int j = 0; j < 4; j++) acc[i][j] = (f32x4){0.f, 0.f, 0.f, 0.f};

    for (int k0 = 0; k0 < K; k0 += 32) {
        if (k0) __syncthreads();
        #pragma unroll
        for (int i = 0; i < 2; ++i) {
            int rr = srow + i * 16;
            int ga = row0 + rr; if (ga > M - 1) ga = M - 1;
            int gb = col0 + rr;
            int lrow = (w << 5) + i * 16;
            gload_lds16(Ahi + (size_t)ga * K + k0 + scol, &sm[0][lrow][0]);
            gload_lds16(Alo + (size_t)ga * K + k0 + scol, &sm[1][lrow][0]);
            gload_lds16(Bhi + (size_t)gb * K + k0 + scol, &sm[2][lrow][0]);
            gload_lds16(Blo + (size_t)gb * K + k0 + scol, &sm[3][lrow][0]);
        }
        __syncthreads();

        half8 bh[4], bl[4];
        #pragma unroll
        for (int ni = 0; ni < 4; ++ni) {
            bh[ni] = *(half8*)&sm[2][wn + ni * 16 + fr][fq8];
            bl[ni] = *(half8*)&sm[3][wn + ni * 16 + fr][fq8];
        }
        #pragma unroll
        for (int mi = 0; mi < 4; ++mi) {
            half8 ah = *(half8*)&sm[0][wm + mi * 16 + fr][fq8];
            half8 al = *(half8*)&sm[1][wm + mi * 16 + fr][fq8];
            #pragma unroll
            for (int ni = 0; ni < 4; ++ni) {
                acc[mi][ni] = __builtin_amdgcn_mfma_f32_16x16x32_f16(ah, bh[ni], acc[mi][ni], 0, 0, 0);
                acc[mi][ni] = __builtin_amdgcn_mfma_f32_16x16x32_f16(ah, bl[ni], acc[mi][ni], 0, 0, 0);
                acc[mi][ni] = __builtin_amdgcn_mfma_f32_16x16x32_f16(al, bh[ni], acc[mi][ni], 0, 0, 0);
            }
        }
    }

    // epilogue: relu(acc+b2) contracted with Wo -> LDS combine -> partial write
    float bv[4];
    float4 wv[4];
    #pragma unroll
    for (int ni = 0; ni < 4; ++ni) {
        int gc = col0 + wn + ni * 16 + fr;
        bv[ni] = bias[gc];
        wv[ni] = *(const float4*)(Wo + (size_t)gc * 4);
    }
    #pragma unroll
    for (int mi = 0; mi < 4; ++mi) {
        #pragma unroll
        for (int r = 0; r < 4; ++r) {
            int lrow = wm + mi * 16 + fq * 4 + r;
            float o0 = 0.f, o1 = 0.f, o2 = 0.f, o3 = 0.f;
            #pragma unroll
            for (int ni = 0; ni < 4; ++ni) {
                float v = acc[mi][ni][r] + bv[ni];
                v = (v > 0.f) ? v : 0.f;
                o0 += v * wv[ni].x; o1 += v * wv[ni].y;
                o2 += v * wv[ni].z; o3 += v * wv[ni].w;
            }
            #pragma unroll
            for (int off = 1; off < 16; off <<= 1) {
                o0 += __shfl_xor(o0, off); o1 += __shfl_xor(o1, off);
                o2 += __shfl_xor(o2, off); o3 += __shfl_xor(o3, off);
            }
            if (fr == 0) sacc[w >> 1][lrow] = (float4){o0, o1, o2, o3};
        }
    }
    __syncthreads();
    if (t < 128) {
        int gr = row0 + t;
        if (gr < M) {
            float4 s0 = sacc[0][t], s1 = sacc[1][t];
            float4 o = (float4){s0.x + s1.x, s0.y + s1.y, s0.z + s1.z, s0.w + s1.w};
            *(float4*)(partial + ((size_t)ct * M + gr) * 4) = o;
        }
    }
}

// ---------------- reduce 4 col-tile partials -> out (adds bo) ----------------
__global__ __launch_bounds__(256) void k_headred(const float* __restrict__ partial,
                                                 const float* __restrict__ bo,
                                                 float* __restrict__ out, int M) {
    int r = blockIdx.x * 256 + threadIdx.x;
    if (r >= M) return;
    float4 a = *(const float4*)(partial + ((size_t)0 * M + r) * 4);
    float4 b = *(const float4*)(partial + ((size_t)1 * M + r) * 4);
    float4 c = *(const float4*)(partial + ((size_t)2 * M + r) * 4);
    float4 d = *(const float4*)(partial + ((size_t)3 * M + r) * 4);
    float4 o;
    o.x = a.x + b.x + c.x + d.x + bo[0];
    o.y = a.y + b.y + c.y + d.y + bo[1];
    o.z = a.z + b.z + c.z + d.z + bo[2];
    o.w = a.w + b.w + c.w + d.w + bo[3];
    *(float4*)(out + (size_t)r * 4) = o;
}

extern "C" void kernel_launch(void* const* d_in, const int* in_sizes, int n_in,
                              void* d_out, int out_size, void* d_ws, size_t ws_size,
                              hipStream_t stream) {
    const float* x    = (const float*)d_in[0];
    const int*   eidx = (const int*)d_in[1];
    const float* cW   = (const float*)d_in[2];
    const float* caS  = (const float*)d_in[3];
    const float* caD  = (const float*)d_in[4];
    const float* cB   = (const float*)d_in[5];
    const float* W0   = (const float*)d_in[6];
    const float* b0   = (const float*)d_in[7];
    const float* W1   = (const float*)d_in[8];
    const float* b1   = (const float*)d_in[9];
    const float* W2   = (const float*)d_in[10];
    const float* b2   = (const float*)d_in[11];
    const float* Wo   = (const float*)d_in[12];
    const float* bo   = (const float*)d_in[13];
    (void)in_sizes; (void)n_in; (void)out_size;

    const int* esrc = eidx;
    const int* edst = eidx + NE;
    float* out = (float*)d_out;

    // ---- workspace bump allocator (256B aligned) ----
    char* w = (char*)d_ws;
    auto alloc = [&](size_t bytes) -> char* {
        char* p = w;
        w += (bytes + 255) & ~(size_t)255;
        return p;
    };
    _Float16* x0h  = (_Float16*)alloc((size_t)NN * 128 * 2);
    _Float16* x0l  = (_Float16*)alloc((size_t)NN * 128 * 2);
    _Float16* xh   = (_Float16*)alloc((size_t)NN * 128 * 2);
    _Float16* xl   = (_Float16*)alloc((size_t)NN * 128 * 2);
    _Float16* hbuf = (_Float16*)alloc((size_t)NN * 128 * 2);   // f16 (R17)
    float* ssrc    = (float*)alloc((size_t)NN * 4);
    float* sdst    = (float*)alloc((size_t)NN * 4);
    int*   counts  = (int*)  alloc((size_t)NN * 4);
    int*   offs    = (int*)  alloc((size_t)(NN + 1) * 4);
    int*   cursor  = (int*)  alloc((size_t)NN * 4);
    int*   csr     = (int*)  alloc((size_t)NET * 4);
    int*   part    = (int*)  alloc((size_t)SCAN_NB * 4);
    _Float16* cwh  = (_Float16*)alloc(3 * 128 * 128 * 2);
    _Float16* cwl  = (_Float16*)alloc(3 * 128 * 128 * 2);
    _Float16* w0h  = (_Float16*)alloc(512 * 128 * 2);
    _Float16* w0l  = (_Float16*)alloc(512 * 128 * 2);
    _Float16* w1h  = (_Float16*)alloc(512 * 512 * 2);
    _Float16* w1l  = (_Float16*)alloc(512 * 512 * 2);
    _Float16* w2h  = (_Float16*)alloc(512 * 512 * 2);
    _Float16* w2l  = (_Float16*)alloc(512 * 512 * 2);
    float* hpart   = (float*)alloc((size_t)4 * NN * 4 * 4);   // head partials [4][NN][4]

    size_t used = (size_t)(w - (char*)d_ws);
    size_t rem = (ws_size > used) ? (ws_size - used) : 0;
    int chunk = (int)(rem / (4 * 512 * sizeof(_Float16)));
    if (chunk > NN) chunk = NN;
    if (chunk > 128) chunk &= ~127;
    if (chunk < 1) chunk = 1;
    _Float16* Y0h = (_Float16*)alloc((size_t)chunk * 512 * 2);
    _Float16* Y0l = (_Float16*)alloc((size_t)chunk * 512 * 2);
    _Float16* Y1h = (_Float16*)alloc((size_t)chunk * 512 * 2);
    _Float16* Y1l = (_Float16*)alloc((size_t)chunk * 512 * 2);

    auto gemm = [&](const _Float16* Ah, const _Float16* Al,
                    const _Float16* Bh, const _Float16* Bl,
                    const float* bias, float* Cf, _Float16* Ch, _Float16* Cl,
                    int M, int N, int K, int relu, int split) {
        int nx = N / 128;
        int ntiles = nx * ((M + 127) / 128);
        int nb = ((ntiles + 7) / 8) * 8;
        k_mgemm<<<nb, 256, 0, stream>>>(Ah, Al, Bh, Bl, bias, Cf, Ch, Cl,
                                        M, N, K, relu, split, nx, ntiles);
    };

    // ---- prep: split x, transpose+split weights ----
    k_split<<<2048, 256, 0, stream>>>(x, x0h, x0l, NN * 128);
    for (int L = 0; L < 3; ++L)
        k_prepw<<<dim3(128 / 32, 128 / 32), 256, 0, stream>>>(
            cW + (size_t)L * 128 * 128, cwh + (size_t)L * 128 * 128, cwl + (size_t)L * 128 * 128, 128, 128);
    k_prepw<<<dim3(512 / 32, 128 / 32), 256, 0, stream>>>(W0, w0h, w0l, 128, 512);
    k_prepw<<<dim3(512 / 32, 512 / 32), 256, 0, stream>>>(W1, w1h, w1l, 512, 512);
    k_prepw<<<dim3(512 / 32, 512 / 32), 256, 0, stream>>>(W2, w2h, w2l, 512, 512);

    // ---- build CSR once ----
    hipMemsetAsync(counts, 0, (size_t)NN * 4, stream);
    int eblocks = (NET + 255) / 256;
    k_count <<<eblocks, 256, 0, stream>>>(edst, counts);
    k_scan1 <<<SCAN_NB, 256, 0, stream>>>(counts, part);
    k_scan2 <<<1, 256, 0, stream>>>(part, offs);
    k_scan3 <<<SCAN_NB, 256, 0, stream>>>(counts, part, offs, cursor);
    k_scatter<<<eblocks, 256, 0, stream>>>(esrc, edst, cursor, csr);

    // ---- 3 GAT layers (GEMM fused with attention scalars) ----
    int gat_tiles = (NN + 127) / 128;
    int gat_nb = ((gat_tiles + 7) / 8) * 8;
    for (int L = 0; L < 3; ++L) {
        const _Float16* Ah = (L == 0) ? x0h : xh;
        const _Float16* Al = (L == 0) ? x0l : xl;
        k_mgemm_gat<<<gat_nb, 256, 0, stream>>>(
            Ah, Al, cwh + (size_t)L * 128 * 128, cwl + (size_t)L * 128 * 128,
            caS + L * 128, caD + L * 128, hbuf, ssrc, sdst, NN, gat_tiles);
        k_aggregate<<<NN / 4, 256, 0, stream>>>(hbuf, ssrc, sdst, offs, csr, cB + L * 128, xh, xl);
    }

    // ---- MLP head (chunked over nodes; gemm2 fused with output head) ----
    for (int m0 = 0; m0 < NN; m0 += chunk) {
        int cm = imin(chunk, NN - m0);
        gemm(xh + (size_t)m0 * 128, xl + (size_t)m0 * 128, w0h, w0l, b0,
             nullptr, Y0h, Y0l, cm, 512, 128, 1, 1);
        gemm(Y0h, Y0l, w1h, w1l, b1, nullptr, Y1h, Y1l, cm, 512, 512, 1, 1);
        int nx = 4;
        int ntiles = nx * ((cm + 127) / 128);
        int nb = ((ntiles + 7) / 8) * 8;
        k_mgemm_head<<<nb, 256, 0, stream>>>(Y1h, Y1l, w2h, w2l, b2, Wo,
                                             hpart, cm, 512, nx, ntiles);
        k_headred<<<(cm + 255) / 256, 256, 0, stream>>>(hpart, bo, out + (size_t)m0 * 4, cm);
    }
}

// Round 8
// 700.417 us; speedup vs baseline: 1.2564x; 1.0112x over previous
//
#include <hip/hip_runtime.h>
#include <hip/hip_bf16.h>

#define NN 50000
#define NE 800000
#define NET (NE + NN)
#define SCAN_NB ((NN + 255) / 256)   // 196

static inline int imin(int a, int b) { return a < b ? a : b; }

typedef _Float16 half8 __attribute__((ext_vector_type(8)));
typedef _Float16 half2v __attribute__((ext_vector_type(2)));
typedef float f32x4 __attribute__((ext_vector_type(4)));

// ---------------- CSR build (graph constant across layers) ----------------
__global__ void k_count(const int* __restrict__ edst, int* __restrict__ counts) {
    int e = blockIdx.x * blockDim.x + threadIdx.x;
    if (e >= NET) return;
    int d = (e < NE) ? edst[e] : (e - NE);   // self loops appended
    atomicAdd(&counts[d], 1);
}

__global__ __launch_bounds__(256) void k_scan1(const int* __restrict__ counts,
                                               int* __restrict__ part) {
    __shared__ int s[256];
    int t = threadIdx.x, i = blockIdx.x * 256 + t;
    s[t] = (i < NN) ? counts[i] : 0;
    __syncthreads();
    for (int off = 128; off > 0; off >>= 1) {
        if (t < off) s[t] += s[t + off];
        __syncthreads();
    }
    if (t == 0) part[blockIdx.x] = s[0];
}

__global__ __launch_bounds__(256) void k_scan2(int* __restrict__ part, int* __restrict__ offs) {
    __shared__ int s[256];
    int t = threadIdx.x;
    int v = (t < SCAN_NB) ? part[t] : 0;
    s[t] = v;
    __syncthreads();
    for (int off = 1; off < 256; off <<= 1) {
        int a = (t >= off) ? s[t - off] : 0;
        __syncthreads();
        s[t] += a;
        __syncthreads();
    }
    if (t < SCAN_NB) part[t] = s[t] - v;     // exclusive block offsets
    if (t == 255) offs[NN] = s[255];         // total (= NET)
}

__global__ __launch_bounds__(256) void k_scan3(const int* __restrict__ counts,
                                               const int* __restrict__ part,
                                               int* __restrict__ offs, int* __restrict__ cursor) {
    __shared__ int s[256];
    int t = threadIdx.x, i = blockIdx.x * 256 + t;
    int v = (i < NN) ? counts[i] : 0;
    s[t] = v;
    __syncthreads();
    for (int off = 1; off < 256; off <<= 1) {
        int a = (t >= off) ? s[t - off] : 0;
        __syncthreads();
        s[t] += a;
        __syncthreads();
    }
    if (i < NN) {
        int e = part[blockIdx.x] + s[t] - v;
        offs[i] = e;
        cursor[i] = e;
    }
}

__global__ void k_scatter(const int* __restrict__ esrc, const int* __restrict__ edst,
                          int* __restrict__ cursor, int* __restrict__ csr_src) {
    int e = blockIdx.x * blockDim.x + threadIdx.x;
    if (e >= NET) return;
    int s, d;
    if (e < NE) { s = esrc[e]; d = edst[e]; } else { s = e - NE; d = s; }
    int pos = atomicAdd(&cursor[d], 1);
    csr_src[pos] = s;
}

// ---------------- split fp32 -> f16 hi/lo pair ----------------
__global__ void k_split(const float* __restrict__ in, _Float16* __restrict__ hi,
                        _Float16* __restrict__ lo, int n) {
    int i = blockIdx.x * blockDim.x + threadIdx.x;
    int st = gridDim.x * blockDim.x;
    for (; i < n; i += st) {
        float v = in[i];
        _Float16 h = (_Float16)v;
        hi[i] = h;
        lo[i] = (_Float16)(v - (float)h);
    }
}

// ---------------- transpose + split weights: W[K][N] -> T[N][K] hi/lo (LDS-tiled) ----
__global__ __launch_bounds__(256) void k_prepw(const float* __restrict__ W,
                                               _Float16* __restrict__ Th,
                                               _Float16* __restrict__ Tl, int K, int N) {
    __shared__ float tile[32][33];
    int tx = threadIdx.x & 31, ty = threadIdx.x >> 5;
    int n0 = blockIdx.x * 32, k0 = blockIdx.y * 32;
    #pragma unroll
    for (int r = ty; r < 32; r += 8)
        tile[r][tx] = W[(size_t)(k0 + r) * N + n0 + tx];   // coalesced read
    __syncthreads();
    #pragma unroll
    for (int r = ty; r < 32; r += 8) {
        int n = n0 + r, k = k0 + tx;
        float v = tile[tx][r];
        _Float16 h = (_Float16)v;
        Th[(size_t)n * K + k] = h;                          // coalesced 64B segments
        Tl[(size_t)n * K + k] = (_Float16)(v - (float)h);
    }
}

// ---------------- fused segment-softmax + aggregate + bias + leaky ----------------
// R17: hbuf f16 (gather 435->218 MB/layer; absmax unchanged -> free).
__global__ void k_aggregate(const _Float16* __restrict__ h, const float* __restrict__ s_src,
                            const float* __restrict__ s_dst, const int* __restrict__ offs,
                            const int* __restrict__ csr_src, const float* __restrict__ bias,
                            _Float16* __restrict__ xh, _Float16* __restrict__ xl) {
    int node = blockIdx.x * 4 + (threadIdx.x >> 6);
    int lane = threadIdx.x & 63;
    if (node >= NN) return;
    int p = offs[node], pe = offs[node + 1];
    float sd = s_dst[node];
    float den = 0.f, acc0 = 0.f, acc1 = 0.f;
    for (; p + 4 <= pe; p += 4) {
        int s0 = csr_src[p + 0], s1 = csr_src[p + 1];
        int s2 = csr_src[p + 2], s3 = csr_src[p + 3];
        float e0 = s_src[s0] + sd, e1 = s_src[s1] + sd;
        float e2 = s_src[s2] + sd, e3 = s_src[s3] + sd;
        half2v a0 = *((const half2v*)(h + (size_t)s0 * 128) + lane);
        half2v a1 = *((const half2v*)(h + (size_t)s1 * 128) + lane);
        half2v a2 = *((const half2v*)(h + (size_t)s2 * 128) + lane);
        half2v a3 = *((const half2v*)(h + (size_t)s3 * 128) + lane);
        e0 = (e0 > 0.f) ? e0 : 0.2f * e0;  float w0 = __expf(e0);
        e1 = (e1 > 0.f) ? e1 : 0.2f * e1;  float w1 = __expf(e1);
        e2 = (e2 > 0.f) ? e2 : 0.2f * e2;  float w2 = __expf(e2);
        e3 = (e3 > 0.f) ? e3 : 0.2f * e3;  float w3 = __expf(e3);
        den += (w0 + w1) + (w2 + w3);
        acc0 += w0 * (float)a0[0] + w1 * (float)a1[0] + w2 * (float)a2[0] + w3 * (float)a3[0];
        acc1 += w0 * (float)a0[1] + w1 * (float)a1[1] + w2 * (float)a2[1] + w3 * (float)a3[1];
    }
    for (; p < pe; ++p) {
        int src = csr_src[p];
        float e = s_src[src] + sd;
        e = (e > 0.f) ? e : 0.2f * e;
        float wgt = __expf(e);
        den += wgt;
        half2v av = *((const half2v*)(h + (size_t)src * 128) + lane);
        acc0 += wgt * (float)av[0];
        acc1 += wgt * (float)av[1];
    }
    float inv = 1.f / den;                    // self-loop guarantees den > 0
    float2 bv = *((const float2*)bias + lane);
    float v0 = acc0 * inv + bv.x;
    float v1 = acc1 * inv + bv.y;
    v0 = (v0 > 0.f) ? v0 : 0.2f * v0;
    v1 = (v1 > 0.f) ? v1 : 0.2f * v1;
    _Float16 h0 = (_Float16)v0, h1 = (_Float16)v1;
    size_t base = (size_t)node * 128 + 2 * lane;
    *(half2v*)(xh + base) = (half2v){h0, h1};
    *(half2v*)(xl + base) = (half2v){(_Float16)(v0 - (float)h0), (_Float16)(v1 - (float)h1)};
}

// ---------------- shared GEMM machinery ----------
// R18: unified-RF accounting showed the 4-wave kernel at 76 VGPR + 64 AGPR
// (acc[4][4] f32x4) = 140 regs/wave -> 3 waves/SIMD = 12 waves/CU; achieved
// occupancy ~25% -> REGISTERS, not LDS (32KB allows 5 blocks) and not the
// schedule, cap residency. That is why R1/R2/R3/R6 all pinned at ~25% Mfma.
// Fix: same K-loop, same 128² tile, but 8 waves (512 thr), per-wave 32x64 ->
// acc[2][4] = 32 AGPR, ~100 regs/wave -> 5 waves/SIMD -> 2 blocks x 8 =
// 16 waves/CU (+33%). Staging becomes exactly 1 gload_lds per thread/array.
__device__ __forceinline__ void gload_lds16(const void* g, void* l) {
    __builtin_amdgcn_global_load_lds(
        (const __attribute__((address_space(1))) void*)g,
        (__attribute__((address_space(3))) void*)l, 16, 0, 0);
}

// per-block phase stagger: hash(bid) -> 0..7 sleeps of ~512cy. ~free, tiny win.
__device__ __forceinline__ void phase_stagger(int bid) {
    int ph = (int)(((unsigned)bid * 2654435761u) >> 29);
    for (int i = 0; i < ph; ++i) __builtin_amdgcn_s_sleep(8);
}

// ---------------- generic split-f16 MFMA GEMM (8-wave; gemm0/gemm1) ----
__global__ __launch_bounds__(512) void k_mgemm(
    const _Float16* __restrict__ Ahi, const _Float16* __restrict__ Alo,
    const _Float16* __restrict__ Bhi, const _Float16* __restrict__ Blo,
    const float* __restrict__ bias, float* __restrict__ Cf,
    _Float16* __restrict__ Chi, _Float16* __restrict__ Clo,
    int M, int N, int K, int relu, int split, int nx, int ntiles)
{
    __shared__ _Float16 sm[4][128][32];   // 32 KiB: Ahi, Alo, Bhi, Blo

    int bid = blockIdx.x;
    int per = (ntiles + 7) >> 3;
    int g = (bid & 7) * per + (bid >> 3);
    if (g >= ntiles) return;
    int col0 = (g % nx) * 128;
    int row0 = (g / nx) * 128;

    phase_stagger(bid);

    int t = threadIdx.x;
    int w = t >> 6, lane = t & 63;
    int wm = (w & 3) * 32, wn = (w >> 2) * 64;   // 8 waves = 4M x 2N, wave tile 32x64
    int fr = lane & 15;
    int fq = lane >> 4, fq8 = fq * 8;

    // staging: 512 threads -> 1 gload_lds per thread per array.
    // thread t covers global (row srow, 16B seg t&3); wave w's 64 lanes land
    // linearly at LDS rows [w*16, w*16+16) (lane l -> row w*16+(l>>2), seg l&3).
    int srow = t >> 2;                // 0..127
    int scol = (t & 3) << 3;          // halfs
    int lrow = w << 4;                // wave-uniform LDS base row

    f32x4 acc[2][4];
    #pragma unroll
    for (int i = 0; i < 2; i++)
        #pragma unroll
        for (int j = 0; j < 4; j++) acc[i][j] = (f32x4){0.f, 0.f, 0.f, 0.f};

    for (int k0 = 0; k0 < K; k0 += 32) {
        if (k0) __syncthreads();
        {
            int ga = row0 + srow; if (ga > M - 1) ga = M - 1;  // M-tail: dup reads, guarded in epilogue
            int gb = col0 + srow;                               // N % 128 == 0 -> in range
            gload_lds16(Ahi + (size_t)ga * K + k0 + scol, &sm[0][lrow][0]);
            gload_lds16(Alo + (size_t)ga * K + k0 + scol, &sm[1][lrow][0]);
            gload_lds16(Bhi + (size_t)gb * K + k0 + scol, &sm[2][lrow][0]);
            gload_lds16(Blo + (size_t)gb * K + k0 + scol, &sm[3][lrow][0]);
        }
        __syncthreads();   // drains vmcnt -> gload_lds stores visible to all waves

        half8 bh[4], bl[4];
        #pragma unroll
        for (int ni = 0; ni < 4; ++ni) {
            bh[ni] = *(half8*)&sm[2][wn + ni * 16 + fr][fq8];
            bl[ni] = *(half8*)&sm[3][wn + ni * 16 + fr][fq8];
        }
        #pragma unroll
        for (int mi = 0; mi < 2; ++mi) {
            half8 ah = *(half8*)&sm[0][wm + mi * 16 + fr][fq8];
            half8 al = *(half8*)&sm[1][wm + mi * 16 + fr][fq8];
            #pragma unroll
            for (int ni = 0; ni < 4; ++ni) {
                acc[mi][ni] = __builtin_amdgcn_mfma_f32_16x16x32_f16(ah, bh[ni], acc[mi][ni], 0, 0, 0);
                acc[mi][ni] = __builtin_amdgcn_mfma_f32_16x16x32_f16(ah, bl[ni], acc[mi][ni], 0, 0, 0);
                acc[mi][ni] = __builtin_amdgcn_mfma_f32_16x16x32_f16(al, bh[ni], acc[mi][ni], 0, 0, 0);
            }
        }
    }

    // epilogue: C/D layout col=lane&15, row=quad*4+reg
    #pragma unroll
    for (int ni = 0; ni < 4; ++ni) {
        int gc = col0 + wn + ni * 16 + fr;
        float bv = bias ? bias[gc] : 0.f;
        #pragma unroll
        for (int mi = 0; mi < 2; ++mi) {
            #pragma unroll
            for (int r = 0; r < 4; ++r) {
                int gr = row0 + wm + mi * 16 + fq * 4 + r;
                if (gr >= M) continue;
                float v = acc[mi][ni][r] + bv;
                if (relu) v = (v > 0.f) ? v : 0.f;
                size_t idx = (size_t)gr * N + gc;
                if (split) {
                    _Float16 hh = (_Float16)v;
                    Chi[idx] = hh;
                    Clo[idx] = (_Float16)(v - (float)hh);
                } else {
                    Cf[idx] = v;
                }
            }
        }
    }
}

// ---------------- GAT GEMM fused with attention scalars (N=K=128, 4-wave control) ----
__global__ __launch_bounds__(256) void k_mgemm_gat(
    const _Float16* __restrict__ Ahi, const _Float16* __restrict__ Alo,
    const _Float16* __restrict__ Bhi, const _Float16* __restrict__ Blo,
    const float* __restrict__ a_src, const float* __restrict__ a_dst,
    _Float16* __restrict__ hbuf, float* __restrict__ s_src, float* __restrict__ s_dst,
    int M, int ntiles)
{
    __shared__ _Float16 sm[4][128][32];   // 32 KiB
    __shared__ float sps[2][128], spd[2][128];

    const int K = 128;
    int bid = blockIdx.x;
    int per = (ntiles + 7) >> 3;
    int g = (bid & 7) * per + (bid >> 3);
    if (g >= ntiles) return;
    int row0 = g * 128;                    // nx == 1 (N = 128)

    int t = threadIdx.x;
    int w = t >> 6, lane = t & 63;
    int wm = (w & 1) * 64, wn = (w >> 1) * 64;
    int fr = lane & 15;
    int fq = lane >> 4, fq8 = fq * 8;
    int wnIdx = w >> 1;

    int srow = (w << 5) + (lane >> 2);
    int scol = (lane & 3) << 3;

    f32x4 acc[4][4];
    #pragma unroll
    for (int i = 0; i < 4; i++)
        #pragma unroll
        for (int j = 0; j < 4; j++) acc[i][j] = (f32x4){0.f, 0.f, 0.f, 0.f};

    for (int k0 = 0; k0 < K; k0 += 32) {
        if (k0) __syncthreads();
        #pragma unroll
        for (int i = 0; i < 2; ++i) {
            int rr = srow + i * 16;
            int ga = row0 + rr; if (ga > M - 1) ga = M - 1;
            int gb = rr;                                      // col0 = 0, N = 128
            int lr = (w << 5) + i * 16;
            gload_lds16(Ahi + (size_t)ga * K + k0 + scol, &sm[0][lr][0]);
            gload_lds16(Alo + (size_t)ga * K + k0 + scol, &sm[1][lr][0]);
            gload_lds16(Bhi + (size_t)gb * K + k0 + scol, &sm[2][lr][0]);
            gload_lds16(Blo + (size_t)gb * K + k0 + scol, &sm[3][lr][0]);
        }
        __syncthreads();

        half8 bh[4], bl[4];
        #pragma unroll
        for (int ni = 0; ni < 4; ++ni) {
            bh[ni] = *(half8*)&sm[2][wn + ni * 16 + fr][fq8];
            bl[ni] = *(half8*)&sm[3][wn + ni * 16 + fr][fq8];
        }
        #pragma unroll
        for (int mi = 0; mi < 4; ++mi) {
            half8 ah = *(half8*)&sm[0][wm + mi * 16 + fr][fq8];
            half8 al = *(half8*)&sm[1][wm + mi * 16 + fr][fq8];
            #pragma unroll
            for (int ni = 0; ni < 4; ++ni) {
                acc[mi][ni] = __builtin_amdgcn_mfma_f32_16x16x32_f16(ah, bh[ni], acc[mi][ni], 0, 0, 0);
                acc[mi][ni] = __builtin_amdgcn_mfma_f32_16x16x32_f16(ah, bl[ni], acc[mi][ni], 0, 0, 0);
                acc[mi][ni] = __builtin_amdgcn_mfma_f32_16x16x32_f16(al, bh[ni], acc[mi][ni], 0, 0, 0);
            }
        }
    }

    // epilogue: write hbuf (f16) + fused attention scalar dots (fp32 from acc)
    float asv[4], adv[4];
    #pragma unroll
    for (int ni = 0; ni < 4; ++ni) {
        int gc = wn + ni * 16 + fr;
        asv[ni] = a_src[gc];
        adv[ni] = a_dst[gc];
    }
    #pragma unroll
    for (int mi = 0; mi < 4; ++mi) {
        #pragma unroll
        for (int r = 0; r < 4; ++r) {
            int lr = wm + mi * 16 + fq * 4 + r;
            int gr = row0 + lr;
            float vps = 0.f, vpd = 0.f;
            #pragma unroll
            for (int ni = 0; ni < 4; ++ni) {
                float v = acc[mi][ni][r];
                vps += v * asv[ni];
                vpd += v * adv[ni];
                if (gr < M) hbuf[(size_t)gr * 128 + wn + ni * 16 + fr] = (_Float16)v;
            }
            #pragma unroll
            for (int off = 1; off < 16; off <<= 1) {
                vps += __shfl_xor(vps, off);
                vpd += __shfl_xor(vpd, off);
            }
            if (fr == 0) { sps[wnIdx][lr] = vps; spd[wnIdx][lr] = vpd; }
        }
    }
    __syncthreads();
    if (t < 128) {
        int gr = row0 + t;
        if (gr < M) {
            s_src[gr] = sps[0][t] + sps[1][t];
            s_dst[gr] = spd[0][t] + spd[1][t];
        }
    }
}

// ---------------- gemm2 fused with MLP head (N=512, partials out, NO atomics) -----
__global__ __launch_bounds__(256) void k_mgemm_head(
    const _Float16* __restrict__ Ahi, const _Float16* __restrict__ Alo,
    const _Float16* __restrict__ Bhi, const _Float16* __restrict__ Blo,
    const float* __restrict__ bias, const float* __restrict__ Wo,
    float* __restrict__ partial,
    int M, int K, int nx, int ntiles)
{
    __shared__ _Float16 sm[4][128][32];   // 32 KiB
    __shared__ float4 sacc[2][128];       // 4 KiB: per-wn-half row partials

    int bid = blockIdx.x;
    int per = (ntiles + 7) >> 3;
    int g = (bid & 7) * per + (bid >> 3);
    if (g >= ntiles) return;
    int ct = g % nx;
    int col0 = ct * 128;
    int row0 = (g / nx) * 128;

    phase_stagger(bid);

    int t = threadIdx.x;
    int w = t >> 6, lane = t & 63;
    int wm = (w & 1) * 64, wn = (w >> 1) * 64;
    int fr = lane & 15;
    int fq = lane >> 4, fq8 = fq * 8;

    int srow = (w << 5) + (lane >> 2);
    int scol = (lane & 3) << 3;

    f32x4 acc[4][4];
    #pragma unroll
    for (int i = 0; i < 4; i++)
        #pragma unroll
        for (int j = 0; j < 4; j++) acc[i][j] = (f32x4){0.f, 0.f, 0.f, 0.f};

    for (int k0 = 0; k0 < K; k0 += 32) {
        if (k0) __syncthreads();
        #pragma unroll
        for (int i = 0; i < 2; ++i) {
            int rr = srow + i * 16;
            int ga = row0 + rr; if (ga > M - 1) ga = M - 1;
            int gb = col0 + rr;
            int lr = (w << 5) + i * 16;
            gload_lds16(Ahi + (size_t)ga * K + k0 + scol, &sm[0][lr][0]);
            gload_lds16(Alo + (size_t)ga * K + k0 + scol, &sm[1][lr][0]);
            gload_lds16(Bhi + (size_t)gb * K + k0 + scol, &sm[2][lr][0]);
            gload_lds16(Blo + (size_t)gb * K + k0 + scol, &sm[3][lr][0]);
        }
        __syncthreads();

        half8 bh[4], bl[4];
        #pragma unroll
        for (int ni = 0; ni < 4; ++ni) {
            bh[ni] = *(half8*)&sm[2][wn + ni * 16 + fr][fq8];
            bl[ni] = *(half8*)&sm[3][wn + ni * 16 + fr][fq8];
        }
        #pragma unroll
        for (int mi = 0; mi < 4; ++mi) {
            half8 ah = *(half8*)&sm[0][wm + mi * 16 + fr][fq8];
            half8 al = *(half8*)&sm[1][wm + mi * 16 + fr][fq8];
            #pragma unroll
            for (int ni = 0; ni < 4; ++ni) {
                acc[mi][ni] = __builtin_amdgcn_mfma_f32_16x16x32_f16(ah, bh[ni], acc[mi][ni], 0, 0, 0);
                acc[mi][ni] = __builtin_amdgcn_mfma_f32_16x16x32_f16(ah, bl[ni], acc[mi][ni], 0, 0, 0);
                acc[mi][ni] = __builtin_amdgcn_mfma_f32_16x16x32_f16(al, bh[ni], acc[mi][ni], 0, 0, 0);
            }
        }
    }

    // epilogue: relu(acc+b2) contracted with Wo -> LDS combine -> partial write
    float bv[4];
    float4 wv[4];
    #pragma unroll
    for (int ni = 0; ni < 4; ++ni) {
        int gc = col0 + wn + ni * 16 + fr;
        bv[ni] = bias[gc];
        wv[ni] = *(const float4*)(Wo + (size_t)gc * 4);
    }
    #pragma unroll
    for (int mi = 0; mi < 4; ++mi) {
        #pragma unroll
        for (int r = 0; r < 4; ++r) {
            int lr = wm + mi * 16 + fq * 4 + r;
            float o0 = 0.f, o1 = 0.f, o2 = 0.f, o3 = 0.f;
            #pragma unroll
            for (int ni = 0; ni < 4; ++ni) {
                float v = acc[mi][ni][r] + bv[ni];
                v = (v > 0.f) ? v : 0.f;
                o0 += v * wv[ni].x; o1 += v * wv[ni].y;
                o2 += v * wv[ni].z; o3 += v * wv[ni].w;
            }
            #pragma unroll
            for (int off = 1; off < 16; off <<= 1) {
                o0 += __shfl_xor(o0, off); o1 += __shfl_xor(o1, off);
                o2 += __shfl_xor(o2, off); o3 += __shfl_xor(o3, off);
            }
            if (fr == 0) sacc[w >> 1][lr] = (float4){o0, o1, o2, o3};
        }
    }
    __syncthreads();
    if (t < 128) {
        int gr = row0 + t;
        if (gr < M) {
            float4 s0 = sacc[0][t], s1 = sacc[1][t];
            float4 o = (float4){s0.x + s1.x, s0.y + s1.y, s0.z + s1.z, s0.w + s1.w};
            *(float4*)(partial + ((size_t)ct * M + gr) * 4) = o;
        }
    }
}

// ---------------- reduce 4 col-tile partials -> out (adds bo) ----------------
__global__ __launch_bounds__(256) void k_headred(const float* __restrict__ partial,
                                                 const float* __restrict__ bo,
                                                 float* __restrict__ out, int M) {
    int r = blockIdx.x * 256 + threadIdx.x;
    if (r >= M) return;
    float4 a = *(const float4*)(partial + ((size_t)0 * M + r) * 4);
    float4 b = *(const float4*)(partial + ((size_t)1 * M + r) * 4);
    float4 c = *(const float4*)(partial + ((size_t)2 * M + r) * 4);
    float4 d = *(const float4*)(partial + ((size_t)3 * M + r) * 4);
    float4 o;
    o.x = a.x + b.x + c.x + d.x + bo[0];
    o.y = a.y + b.y + c.y + d.y + bo[1];
    o.z = a.z + b.z + c.z + d.z + bo[2];
    o.w = a.w + b.w + c.w + d.w + bo[3];
    *(float4*)(out + (size_t)r * 4) = o;
}

extern "C" void kernel_launch(void* const* d_in, const int* in_sizes, int n_in,
                              void* d_out, int out_size, void* d_ws, size_t ws_size,
                              hipStream_t stream) {
    const float* x    = (const float*)d_in[0];
    const int*   eidx = (const int*)d_in[1];
    const float* cW   = (const float*)d_in[2];
    const float* caS  = (const float*)d_in[3];
    const float* caD  = (const float*)d_in[4];
    const float* cB   = (const float*)d_in[5];
    const float* W0   = (const float*)d_in[6];
    const float* b0   = (const float*)d_in[7];
    const float* W1   = (const float*)d_in[8];
    const float* b1   = (const float*)d_in[9];
    const float* W2   = (const float*)d_in[10];
    const float* b2   = (const float*)d_in[11];
    const float* Wo   = (const float*)d_in[12];
    const float* bo   = (const float*)d_in[13];
    (void)in_sizes; (void)n_in; (void)out_size;

    const int* esrc = eidx;
    const int* edst = eidx + NE;
    float* out = (float*)d_out;

    // ---- workspace bump allocator (256B aligned) ----
    char* w = (char*)d_ws;
    auto alloc = [&](size_t bytes) -> char* {
        char* p = w;
        w += (bytes + 255) & ~(size_t)255;
        return p;
    };
    _Float16* x0h  = (_Float16*)alloc((size_t)NN * 128 * 2);
    _Float16* x0l  = (_Float16*)alloc((size_t)NN * 128 * 2);
    _Float16* xh   = (_Float16*)alloc((size_t)NN * 128 * 2);
    _Float16* xl   = (_Float16*)alloc((size_t)NN * 128 * 2);
    _Float16* hbuf = (_Float16*)alloc((size_t)NN * 128 * 2);   // f16 (R17)
    float* ssrc    = (float*)alloc((size_t)NN * 4);
    float* sdst    = (float*)alloc((size_t)NN * 4);
    int*   counts  = (int*)  alloc((size_t)NN * 4);
    int*   offs    = (int*)  alloc((size_t)(NN + 1) * 4);
    int*   cursor  = (int*)  alloc((size_t)NN * 4);
    int*   csr     = (int*)  alloc((size_t)NET * 4);
    int*   part    = (int*)  alloc((size_t)SCAN_NB * 4);
    _Float16* cwh  = (_Float16*)alloc(3 * 128 * 128 * 2);
    _Float16* cwl  = (_Float16*)alloc(3 * 128 * 128 * 2);
    _Float16* w0h  = (_Float16*)alloc(512 * 128 * 2);
    _Float16* w0l  = (_Float16*)alloc(512 * 128 * 2);
    _Float16* w1h  = (_Float16*)alloc(512 * 512 * 2);
    _Float16* w1l  = (_Float16*)alloc(512 * 512 * 2);
    _Float16* w2h  = (_Float16*)alloc(512 * 512 * 2);
    _Float16* w2l  = (_Float16*)alloc(512 * 512 * 2);
    float* hpart   = (float*)alloc((size_t)4 * NN * 4 * 4);   // head partials [4][NN][4]

    size_t used = (size_t)(w - (char*)d_ws);
    size_t rem = (ws_size > used) ? (ws_size - used) : 0;
    int chunk = (int)(rem / (4 * 512 * sizeof(_Float16)));
    if (chunk > NN) chunk = NN;
    if (chunk > 128) chunk &= ~127;
    if (chunk < 1) chunk = 1;
    _Float16* Y0h = (_Float16*)alloc((size_t)chunk * 512 * 2);
    _Float16* Y0l = (_Float16*)alloc((size_t)chunk * 512 * 2);
    _Float16* Y1h = (_Float16*)alloc((size_t)chunk * 512 * 2);
    _Float16* Y1l = (_Float16*)alloc((size_t)chunk * 512 * 2);

    auto gemm = [&](const _Float16* Ah, const _Float16* Al,
                    const _Float16* Bh, const _Float16* Bl,
                    const float* bias, float* Cf, _Float16* Ch, _Float16* Cl,
                    int M, int N, int K, int relu, int split) {
        int nx = N / 128;
        int ntiles = nx * ((M + 127) / 128);
        int nb = ((ntiles + 7) / 8) * 8;
        k_mgemm<<<nb, 512, 0, stream>>>(Ah, Al, Bh, Bl, bias, Cf, Ch, Cl,
                                        M, N, K, relu, split, nx, ntiles);
    };

    // ---- prep: split x, transpose+split weights ----
    k_split<<<2048, 256, 0, stream>>>(x, x0h, x0l, NN * 128);
    for (int L = 0; L < 3; ++L)
        k_prepw<<<dim3(128 / 32, 128 / 32), 256, 0, stream>>>(
            cW + (size_t)L * 128 * 128, cwh + (size_t)L * 128 * 128, cwl + (size_t)L * 128 * 128, 128, 128);
    k_prepw<<<dim3(512 / 32, 128 / 32), 256, 0, stream>>>(W0, w0h, w0l, 128, 512);
    k_prepw<<<dim3(512 / 32, 512 / 32), 256, 0, stream>>>(W1, w1h, w1l, 512, 512);
    k_prepw<<<dim3(512 / 32, 512 / 32), 256, 0, stream>>>(W2, w2h, w2l, 512, 512);

    // ---- build CSR once ----
    hipMemsetAsync(counts, 0, (size_t)NN * 4, stream);
    int eblocks = (NET + 255) / 256;
    k_count <<<eblocks, 256, 0, stream>>>(edst, counts);
    k_scan1 <<<SCAN_NB, 256, 0, stream>>>(counts, part);
    k_scan2 <<<1, 256, 0, stream>>>(part, offs);
    k_scan3 <<<SCAN_NB, 256, 0, stream>>>(counts, part, offs, cursor);
    k_scatter<<<eblocks, 256, 0, stream>>>(esrc, edst, cursor, csr);

    // ---- 3 GAT layers (GEMM fused with attention scalars) ----
    int gat_tiles = (NN + 127) / 128;
    int gat_nb = ((gat_tiles + 7) / 8) * 8;
    for (int L = 0; L < 3; ++L) {
        const _Float16* Ah = (L == 0) ? x0h : xh;
        const _Float16* Al = (L == 0) ? x0l : xl;
        k_mgemm_gat<<<gat_nb, 256, 0, stream>>>(
            Ah, Al, cwh + (size_t)L * 128 * 128, cwl + (size_t)L * 128 * 128,
            caS + L * 128, caD + L * 128, hbuf, ssrc, sdst, NN, gat_tiles);
        k_aggregate<<<NN / 4, 256, 0, stream>>>(hbuf, ssrc, sdst, offs, csr, cB + L * 128, xh, xl);
    }

    // ---- MLP head (chunked over nodes; gemm2 fused with output head) ----
    for (int m0 = 0; m0 < NN; m0 += chunk) {
        int cm = imin(chunk, NN - m0);
        gemm(xh + (size_t)m0 * 128, xl + (size_t)m0 * 128, w0h, w0l, b0,
             nullptr, Y0h, Y0l, cm, 512, 128, 1, 1);
        gemm(Y0h, Y0l, w1h, w1l, b1, nullptr, Y1h, Y1l, cm, 512, 512, 1, 1);
        int nx = 4;
        int ntiles = nx * ((cm + 127) / 128);
        int nb = ((ntiles + 7) / 8) * 8;
        k_mgemm_head<<<nb, 256, 0, stream>>>(Y1h, Y1l, w2h, w2l, b2, Wo,
                                             hpart, cm, 512, nx, ntiles);
        k_headred<<<(cm + 255) / 256, 256, 0, stream>>>(hpart, bo, out + (size_t)m0 * 4, cm);
    }
}

// Round 9
// 649.618 us; speedup vs baseline: 1.3547x; 1.0782x over previous
//
#include <hip/hip_runtime.h>
#include <hip/hip_bf16.h>

#define NN 50000
#define NE 800000
#define NET (NE + NN)
#define SCAN_NB ((NN + 255) / 256)   // 196

static inline int imin(int a, int b) { return a < b ? a : b; }

typedef _Float16 half8 __attribute__((ext_vector_type(8)));
typedef _Float16 half2v __attribute__((ext_vector_type(2)));
typedef float f32x4 __attribute__((ext_vector_type(4)));

// ---------------- CSR build (graph constant across layers) ----------------
__global__ void k_count(const int* __restrict__ edst, int* __restrict__ counts) {
    int e = blockIdx.x * blockDim.x + threadIdx.x;
    if (e >= NET) return;
    int d = (e < NE) ? edst[e] : (e - NE);   // self loops appended
    atomicAdd(&counts[d], 1);
}

__global__ __launch_bounds__(256) void k_scan1(const int* __restrict__ counts,
                                               int* __restrict__ part) {
    __shared__ int s[256];
    int t = threadIdx.x, i = blockIdx.x * 256 + t;
    s[t] = (i < NN) ? counts[i] : 0;
    __syncthreads();
    for (int off = 128; off > 0; off >>= 1) {
        if (t < off) s[t] += s[t + off];
        __syncthreads();
    }
    if (t == 0) part[blockIdx.x] = s[0];
}

__global__ __launch_bounds__(256) void k_scan2(int* __restrict__ part, int* __restrict__ offs) {
    __shared__ int s[256];
    int t = threadIdx.x;
    int v = (t < SCAN_NB) ? part[t] : 0;
    s[t] = v;
    __syncthreads();
    for (int off = 1; off < 256; off <<= 1) {
        int a = (t >= off) ? s[t - off] : 0;
        __syncthreads();
        s[t] += a;
        __syncthreads();
    }
    if (t < SCAN_NB) part[t] = s[t] - v;     // exclusive block offsets
    if (t == 255) offs[NN] = s[255];         // total (= NET)
}

__global__ __launch_bounds__(256) void k_scan3(const int* __restrict__ counts,
                                               const int* __restrict__ part,
                                               int* __restrict__ offs, int* __restrict__ cursor) {
    __shared__ int s[256];
    int t = threadIdx.x, i = blockIdx.x * 256 + t;
    int v = (i < NN) ? counts[i] : 0;
    s[t] = v;
    __syncthreads();
    for (int off = 1; off < 256; off <<= 1) {
        int a = (t >= off) ? s[t - off] : 0;
        __syncthreads();
        s[t] += a;
        __syncthreads();
    }
    if (i < NN) {
        int e = part[blockIdx.x] + s[t] - v;
        offs[i] = e;
        cursor[i] = e;
    }
}

__global__ void k_scatter(const int* __restrict__ esrc, const int* __restrict__ edst,
                          int* __restrict__ cursor, int* __restrict__ csr_src) {
    int e = blockIdx.x * blockDim.x + threadIdx.x;
    if (e >= NET) return;
    int s, d;
    if (e < NE) { s = esrc[e]; d = edst[e]; } else { s = e - NE; d = s; }
    int pos = atomicAdd(&cursor[d], 1);
    csr_src[pos] = s;
}

// ---------------- split fp32 -> f16 hi/lo pair ----------------
__global__ void k_split(const float* __restrict__ in, _Float16* __restrict__ hi,
                        _Float16* __restrict__ lo, int n) {
    int i = blockIdx.x * blockDim.x + threadIdx.x;
    int st = gridDim.x * blockDim.x;
    for (; i < n; i += st) {
        float v = in[i];
        _Float16 h = (_Float16)v;
        hi[i] = h;
        lo[i] = (_Float16)(v - (float)h);
    }
}

// ---------------- transpose + split weights: W[K][N] -> T[N][K] hi/lo (LDS-tiled) ----
__global__ __launch_bounds__(256) void k_prepw(const float* __restrict__ W,
                                               _Float16* __restrict__ Th,
                                               _Float16* __restrict__ Tl, int K, int N) {
    __shared__ float tile[32][33];
    int tx = threadIdx.x & 31, ty = threadIdx.x >> 5;
    int n0 = blockIdx.x * 32, k0 = blockIdx.y * 32;
    #pragma unroll
    for (int r = ty; r < 32; r += 8)
        tile[r][tx] = W[(size_t)(k0 + r) * N + n0 + tx];   // coalesced read
    __syncthreads();
    #pragma unroll
    for (int r = ty; r < 32; r += 8) {
        int n = n0 + r, k = k0 + tx;
        float v = tile[tx][r];
        _Float16 h = (_Float16)v;
        Th[(size_t)n * K + k] = h;                          // coalesced 64B segments
        Tl[(size_t)n * K + k] = (_Float16)(v - (float)h);
    }
}

// ---------------- fused segment-softmax + aggregate + bias + leaky ----------------
// R17: hbuf f16 (gather 435->218 MB/layer; absmax unchanged -> free).
__global__ void k_aggregate(const _Float16* __restrict__ h, const float* __restrict__ s_src,
                            const float* __restrict__ s_dst, const int* __restrict__ offs,
                            const int* __restrict__ csr_src, const float* __restrict__ bias,
                            _Float16* __restrict__ xh, _Float16* __restrict__ xl) {
    int node = blockIdx.x * 4 + (threadIdx.x >> 6);
    int lane = threadIdx.x & 63;
    if (node >= NN) return;
    int p = offs[node], pe = offs[node + 1];
    float sd = s_dst[node];
    float den = 0.f, acc0 = 0.f, acc1 = 0.f;
    for (; p + 4 <= pe; p += 4) {
        int s0 = csr_src[p + 0], s1 = csr_src[p + 1];
        int s2 = csr_src[p + 2], s3 = csr_src[p + 3];
        float e0 = s_src[s0] + sd, e1 = s_src[s1] + sd;
        float e2 = s_src[s2] + sd, e3 = s_src[s3] + sd;
        half2v a0 = *((const half2v*)(h + (size_t)s0 * 128) + lane);
        half2v a1 = *((const half2v*)(h + (size_t)s1 * 128) + lane);
        half2v a2 = *((const half2v*)(h + (size_t)s2 * 128) + lane);
        half2v a3 = *((const half2v*)(h + (size_t)s3 * 128) + lane);
        e0 = (e0 > 0.f) ? e0 : 0.2f * e0;  float w0 = __expf(e0);
        e1 = (e1 > 0.f) ? e1 : 0.2f * e1;  float w1 = __expf(e1);
        e2 = (e2 > 0.f) ? e2 : 0.2f * e2;  float w2 = __expf(e2);
        e3 = (e3 > 0.f) ? e3 : 0.2f * e3;  float w3 = __expf(e3);
        den += (w0 + w1) + (w2 + w3);
        acc0 += w0 * (float)a0[0] + w1 * (float)a1[0] + w2 * (float)a2[0] + w3 * (float)a3[0];
        acc1 += w0 * (float)a0[1] + w1 * (float)a1[1] + w2 * (float)a2[1] + w3 * (float)a3[1];
    }
    for (; p < pe; ++p) {
        int src = csr_src[p];
        float e = s_src[src] + sd;
        e = (e > 0.f) ? e : 0.2f * e;
        float wgt = __expf(e);
        den += wgt;
        half2v av = *((const half2v*)(h + (size_t)src * 128) + lane);
        acc0 += wgt * (float)av[0];
        acc1 += wgt * (float)av[1];
    }
    float inv = 1.f / den;                    // self-loop guarantees den > 0
    float2 bv = *((const float2*)bias + lane);
    float v0 = acc0 * inv + bv.x;
    float v1 = acc1 * inv + bv.y;
    v0 = (v0 > 0.f) ? v0 : 0.2f * v0;
    v1 = (v1 > 0.f) ? v1 : 0.2f * v1;
    _Float16 h0 = (_Float16)v0, h1 = (_Float16)v1;
    size_t base = (size_t)node * 128 + 2 * lane;
    *(half2v*)(xh + base) = (half2v){h0, h1};
    *(half2v*)(xl + base) = (half2v){(_Float16)(v0 - (float)h0), (_Float16)(v1 - (float)h1)};
}

// ---------------- shared GEMM machinery ----------
// R18: 8-wave k_mgemm lifted occupancy 25->39% (register-residency theory
// confirmed: VGPR 140->~80/wave incl. acc) but the win was eaten by WRITE
// inflation 110->204 MB: scattered 2B epilogue stores stop line-merging at
// 8-wave timing (R3 saw the same). R19: restage C through LDS (sm reused as
// 128x128 f16 tile, hi pass then lo pass) -> every global store is a half8
// (16B) with consecutive threads on consecutive segments = full-line
// coalescing, timing-independent.
__device__ __forceinline__ void gload_lds16(const void* g, void* l) {
    __builtin_amdgcn_global_load_lds(
        (const __attribute__((address_space(1))) void*)g,
        (__attribute__((address_space(3))) void*)l, 16, 0, 0);
}

// per-block phase stagger: hash(bid) -> 0..7 sleeps of ~512cy. ~free, tiny win.
__device__ __forceinline__ void phase_stagger(int bid) {
    int ph = (int)(((unsigned)bid * 2654435761u) >> 29);
    for (int i = 0; i < ph; ++i) __builtin_amdgcn_s_sleep(8);
}

// ---------------- generic split-f16 MFMA GEMM (8-wave; gemm0/gemm1) ----
__global__ __launch_bounds__(512) void k_mgemm(
    const _Float16* __restrict__ Ahi, const _Float16* __restrict__ Alo,
    const _Float16* __restrict__ Bhi, const _Float16* __restrict__ Blo,
    const float* __restrict__ bias, float* __restrict__ Cf,
    _Float16* __restrict__ Chi, _Float16* __restrict__ Clo,
    int M, int N, int K, int relu, int split, int nx, int ntiles)
{
    __shared__ _Float16 sm[4][128][32];   // 32 KiB: Ahi, Alo, Bhi, Blo; reused as C tile

    int bid = blockIdx.x;
    int per = (ntiles + 7) >> 3;
    int g = (bid & 7) * per + (bid >> 3);
    if (g >= ntiles) return;
    int col0 = (g % nx) * 128;
    int row0 = (g / nx) * 128;

    phase_stagger(bid);

    int t = threadIdx.x;
    int w = t >> 6, lane = t & 63;
    int wm = (w & 3) * 32, wn = (w >> 2) * 64;   // 8 waves = 4M x 2N, wave tile 32x64
    int fr = lane & 15;
    int fq = lane >> 4, fq8 = fq * 8;

    // staging: 512 threads -> 1 gload_lds per thread per array.
    int srow = t >> 2;                // 0..127
    int scol = (t & 3) << 3;          // halfs
    int lrow = w << 4;                // wave-uniform LDS base row

    f32x4 acc[2][4];
    #pragma unroll
    for (int i = 0; i < 2; i++)
        #pragma unroll
        for (int j = 0; j < 4; j++) acc[i][j] = (f32x4){0.f, 0.f, 0.f, 0.f};

    for (int k0 = 0; k0 < K; k0 += 32) {
        if (k0) __syncthreads();
        {
            int ga = row0 + srow; if (ga > M - 1) ga = M - 1;  // M-tail: dup reads, guarded at store
            int gb = col0 + srow;                               // N % 128 == 0 -> in range
            gload_lds16(Ahi + (size_t)ga * K + k0 + scol, &sm[0][lrow][0]);
            gload_lds16(Alo + (size_t)ga * K + k0 + scol, &sm[1][lrow][0]);
            gload_lds16(Bhi + (size_t)gb * K + k0 + scol, &sm[2][lrow][0]);
            gload_lds16(Blo + (size_t)gb * K + k0 + scol, &sm[3][lrow][0]);
        }
        __syncthreads();   // drains vmcnt -> gload_lds stores visible to all waves

        half8 bh[4], bl[4];
        #pragma unroll
        for (int ni = 0; ni < 4; ++ni) {
            bh[ni] = *(half8*)&sm[2][wn + ni * 16 + fr][fq8];
            bl[ni] = *(half8*)&sm[3][wn + ni * 16 + fr][fq8];
        }
        #pragma unroll
        for (int mi = 0; mi < 2; ++mi) {
            half8 ah = *(half8*)&sm[0][wm + mi * 16 + fr][fq8];
            half8 al = *(half8*)&sm[1][wm + mi * 16 + fr][fq8];
            #pragma unroll
            for (int ni = 0; ni < 4; ++ni) {
                acc[mi][ni] = __builtin_amdgcn_mfma_f32_16x16x32_f16(ah, bh[ni], acc[mi][ni], 0, 0, 0);
                acc[mi][ni] = __builtin_amdgcn_mfma_f32_16x16x32_f16(ah, bl[ni], acc[mi][ni], 0, 0, 0);
                acc[mi][ni] = __builtin_amdgcn_mfma_f32_16x16x32_f16(al, bh[ni], acc[mi][ni], 0, 0, 0);
            }
        }
    }

    // bias per output column (cached once, reused both passes)
    float bv[4];
    #pragma unroll
    for (int ni = 0; ni < 4; ++ni)
        bv[ni] = bias ? bias[col0 + wn + ni * 16 + fr] : 0.f;

    if (split) {
        // R19 epilogue: restage C via LDS -> 16B coalesced stores (pass 0: hi, 1: lo)
        _Float16* sc = &sm[0][0][0];   // [128][128]
        #pragma unroll
        for (int pass = 0; pass < 2; ++pass) {
            __syncthreads();   // pass0: K-loop sm reads done; pass1: prev store reads done
            #pragma unroll
            for (int mi = 0; mi < 2; ++mi) {
                #pragma unroll
                for (int ni = 0; ni < 4; ++ni) {
                    #pragma unroll
                    for (int r = 0; r < 4; ++r) {
                        int row = wm + mi * 16 + fq * 4 + r;
                        int col = wn + ni * 16 + fr;
                        float v = acc[mi][ni][r] + bv[ni];
                        if (relu) v = (v > 0.f) ? v : 0.f;
                        _Float16 hh = (_Float16)v;
                        sc[row * 128 + col] = pass ? (_Float16)(v - (float)hh) : hh;
                    }
                }
            }
            __syncthreads();
            _Float16* dst = pass ? Clo : Chi;
            #pragma unroll
            for (int pp = 0; pp < 4; ++pp) {
                int idx = t + pp * 512;
                int row = idx >> 4, seg = idx & 15;
                int gr = row0 + row;
                if (gr < M)
                    *(half8*)(dst + (size_t)gr * N + col0 + seg * 8) =
                        *(half8*)&sc[row * 128 + seg * 8];
            }
        }
    } else {
        // fp32 path (currently unused): original scattered stores
        #pragma unroll
        for (int ni = 0; ni < 4; ++ni) {
            #pragma unroll
            for (int mi = 0; mi < 2; ++mi) {
                #pragma unroll
                for (int r = 0; r < 4; ++r) {
                    int gr = row0 + wm + mi * 16 + fq * 4 + r;
                    if (gr >= M) continue;
                    float v = acc[mi][ni][r] + bv[ni];
                    if (relu) v = (v > 0.f) ? v : 0.f;
                    Cf[(size_t)gr * N + col0 + wn + ni * 16 + fr] = v;
                }
            }
        }
    }
}

// ---------------- GAT GEMM fused with attention scalars (N=K=128, 4-wave control) ----
__global__ __launch_bounds__(256) void k_mgemm_gat(
    const _Float16* __restrict__ Ahi, const _Float16* __restrict__ Alo,
    const _Float16* __restrict__ Bhi, const _Float16* __restrict__ Blo,
    const float* __restrict__ a_src, const float* __restrict__ a_dst,
    _Float16* __restrict__ hbuf, float* __restrict__ s_src, float* __restrict__ s_dst,
    int M, int ntiles)
{
    __shared__ _Float16 sm[4][128][32];   // 32 KiB
    __shared__ float sps[2][128], spd[2][128];

    const int K = 128;
    int bid = blockIdx.x;
    int per = (ntiles + 7) >> 3;
    int g = (bid & 7) * per + (bid >> 3);
    if (g >= ntiles) return;
    int row0 = g * 128;                    // nx == 1 (N = 128)

    int t = threadIdx.x;
    int w = t >> 6, lane = t & 63;
    int wm = (w & 1) * 64, wn = (w >> 1) * 64;
    int fr = lane & 15;
    int fq = lane >> 4, fq8 = fq * 8;
    int wnIdx = w >> 1;

    int srow = (w << 5) + (lane >> 2);
    int scol = (lane & 3) << 3;

    f32x4 acc[4][4];
    #pragma unroll
    for (int i = 0; i < 4; i++)
        #pragma unroll
        for (int j = 0; j < 4; j++) acc[i][j] = (f32x4){0.f, 0.f, 0.f, 0.f};

    for (int k0 = 0; k0 < K; k0 += 32) {
        if (k0) __syncthreads();
        #pragma unroll
        for (int i = 0; i < 2; ++i) {
            int rr = srow + i * 16;
            int ga = row0 + rr; if (ga > M - 1) ga = M - 1;
            int gb = rr;                                      // col0 = 0, N = 128
            int lr = (w << 5) + i * 16;
            gload_lds16(Ahi + (size_t)ga * K + k0 + scol, &sm[0][lr][0]);
            gload_lds16(Alo + (size_t)ga * K + k0 + scol, &sm[1][lr][0]);
            gload_lds16(Bhi + (size_t)gb * K + k0 + scol, &sm[2][lr][0]);
            gload_lds16(Blo + (size_t)gb * K + k0 + scol, &sm[3][lr][0]);
        }
        __syncthreads();

        half8 bh[4], bl[4];
        #pragma unroll
        for (int ni = 0; ni < 4; ++ni) {
            bh[ni] = *(half8*)&sm[2][wn + ni * 16 + fr][fq8];
            bl[ni] = *(half8*)&sm[3][wn + ni * 16 + fr][fq8];
        }
        #pragma unroll
        for (int mi = 0; mi < 4; ++mi) {
            half8 ah = *(half8*)&sm[0][wm + mi * 16 + fr][fq8];
            half8 al = *(half8*)&sm[1][wm + mi * 16 + fr][fq8];
            #pragma unroll
            for (int ni = 0; ni < 4; ++ni) {
                acc[mi][ni] = __builtin_amdgcn_mfma_f32_16x16x32_f16(ah, bh[ni], acc[mi][ni], 0, 0, 0);
                acc[mi][ni] = __builtin_amdgcn_mfma_f32_16x16x32_f16(ah, bl[ni], acc[mi][ni], 0, 0, 0);
                acc[mi][ni] = __builtin_amdgcn_mfma_f32_16x16x32_f16(al, bh[ni], acc[mi][ni], 0, 0, 0);
            }
        }
    }

    // epilogue: write hbuf (f16) + fused attention scalar dots (fp32 from acc)
    float asv[4], adv[4];
    #pragma unroll
    for (int ni = 0; ni < 4; ++ni) {
        int gc = wn + ni * 16 + fr;
        asv[ni] = a_src[gc];
        adv[ni] = a_dst[gc];
    }
    #pragma unroll
    for (int mi = 0; mi < 4; ++mi) {
        #pragma unroll
        for (int r = 0; r < 4; ++r) {
            int lr = wm + mi * 16 + fq * 4 + r;
            int gr = row0 + lr;
            float vps = 0.f, vpd = 0.f;
            #pragma unroll
            for (int ni = 0; ni < 4; ++ni) {
                float v = acc[mi][ni][r];
                vps += v * asv[ni];
                vpd += v * adv[ni];
                if (gr < M) hbuf[(size_t)gr * 128 + wn + ni * 16 + fr] = (_Float16)v;
            }
            #pragma unroll
            for (int off = 1; off < 16; off <<= 1) {
                vps += __shfl_xor(vps, off);
                vpd += __shfl_xor(vpd, off);
            }
            if (fr == 0) { sps[wnIdx][lr] = vps; spd[wnIdx][lr] = vpd; }
        }
    }
    __syncthreads();
    if (t < 128) {
        int gr = row0 + t;
        if (gr < M) {
            s_src[gr] = sps[0][t] + sps[1][t];
            s_dst[gr] = spd[0][t] + spd[1][t];
        }
    }
}

// ---------------- gemm2 fused with MLP head (N=512, partials out, NO atomics) -----
__global__ __launch_bounds__(256) void k_mgemm_head(
    const _Float16* __restrict__ Ahi, const _Float16* __restrict__ Alo,
    const _Float16* __restrict__ Bhi, const _Float16* __restrict__ Blo,
    const float* __restrict__ bias, const float* __restrict__ Wo,
    float* __restrict__ partial,
    int M, int K, int nx, int ntiles)
{
    __shared__ _Float16 sm[4][128][32];   // 32 KiB
    __shared__ float4 sacc[2][128];       // 4 KiB: per-wn-half row partials

    int bid = blockIdx.x;
    int per = (ntiles + 7) >> 3;
    int g = (bid & 7) * per + (bid >> 3);
    if (g >= ntiles) return;
    int ct = g % nx;
    int col0 = ct * 128;
    int row0 = (g / nx) * 128;

    phase_stagger(bid);

    int t = threadIdx.x;
    int w = t >> 6, lane = t & 63;
    int wm = (w & 1) * 64, wn = (w >> 1) * 64;
    int fr = lane & 15;
    int fq = lane >> 4, fq8 = fq * 8;

    int srow = (w << 5) + (lane >> 2);
    int scol = (lane & 3) << 3;

    f32x4 acc[4][4];
    #pragma unroll
    for (int i = 0; i < 4; i++)
        #pragma unroll
        for (int j = 0; j < 4; j++) acc[i][j] = (f32x4){0.f, 0.f, 0.f, 0.f};

    for (int k0 = 0; k0 < K; k0 += 32) {
        if (k0) __syncthreads();
        #pragma unroll
        for (int i = 0; i < 2; ++i) {
            int rr = srow + i * 16;
            int ga = row0 + rr; if (ga > M - 1) ga = M - 1;
            int gb = col0 + rr;
            int lr = (w << 5) + i * 16;
            gload_lds16(Ahi + (size_t)ga * K + k0 + scol, &sm[0][lr][0]);
            gload_lds16(Alo + (size_t)ga * K + k0 + scol, &sm[1][lr][0]);
            gload_lds16(Bhi + (size_t)gb * K + k0 + scol, &sm[2][lr][0]);
            gload_lds16(Blo + (size_t)gb * K + k0 + scol, &sm[3][lr][0]);
        }
        __syncthreads();

        half8 bh[4], bl[4];
        #pragma unroll
        for (int ni = 0; ni < 4; ++ni) {
            bh[ni] = *(half8*)&sm[2][wn + ni * 16 + fr][fq8];
            bl[ni] = *(half8*)&sm[3][wn + ni * 16 + fr][fq8];
        }
        #pragma unroll
        for (int mi = 0; mi < 4; ++mi) {
            half8 ah = *(half8*)&sm[0][wm + mi * 16 + fr][fq8];
            half8 al = *(half8*)&sm[1][wm + mi * 16 + fr][fq8];
            #pragma unroll
            for (int ni = 0; ni < 4; ++ni) {
                acc[mi][ni] = __builtin_amdgcn_mfma_f32_16x16x32_f16(ah, bh[ni], acc[mi][ni], 0, 0, 0);
                acc[mi][ni] = __builtin_amdgcn_mfma_f32_16x16x32_f16(ah, bl[ni], acc[mi][ni], 0, 0, 0);
                acc[mi][ni] = __builtin_amdgcn_mfma_f32_16x16x32_f16(al, bh[ni], acc[mi][ni], 0, 0, 0);
            }
        }
    }

    // epilogue: relu(acc+b2) contracted with Wo -> LDS combine -> partial write
    float bv[4];
    float4 wv[4];
    #pragma unroll
    for (int ni = 0; ni < 4; ++ni) {
        int gc = col0 + wn + ni * 16 + fr;
        bv[ni] = bias[gc];
        wv[ni] = *(const float4*)(Wo + (size_t)gc * 4);
    }
    #pragma unroll
    for (int mi = 0; mi < 4; ++mi) {
        #pragma unroll
        for (int r = 0; r < 4; ++r) {
            int lr = wm + mi * 16 + fq * 4 + r;
            float o0 = 0.f, o1 = 0.f, o2 = 0.f, o3 = 0.f;
            #pragma unroll
            for (int ni = 0; ni < 4; ++ni) {
                float v = acc[mi][ni][r] + bv[ni];
                v = (v > 0.f) ? v : 0.f;
                o0 += v * wv[ni].x; o1 += v * wv[ni].y;
                o2 += v * wv[ni].z; o3 += v * wv[ni].w;
            }
            #pragma unroll
            for (int off = 1; off < 16; off <<= 1) {
                o0 += __shfl_xor(o0, off); o1 += __shfl_xor(o1, off);
                o2 += __shfl_xor(o2, off); o3 += __shfl_xor(o3, off);
            }
            if (fr == 0) sacc[w >> 1][lr] = (float4){o0, o1, o2, o3};
        }
    }
    __syncthreads();
    if (t < 128) {
        int gr = row0 + t;
        if (gr < M) {
            float4 s0 = sacc[0][t], s1 = sacc[1][t];
            float4 o = (float4){s0.x + s1.x, s0.y + s1.y, s0.z + s1.z, s0.w + s1.w};
            *(float4*)(partial + ((size_t)ct * M + gr) * 4) = o;
        }
    }
}

// ---------------- reduce 4 col-tile partials -> out (adds bo) ----------------
__global__ __launch_bounds__(256) void k_headred(const float* __restrict__ partial,
                                                 const float* __restrict__ bo,
                                                 float* __restrict__ out, int M) {
    int r = blockIdx.x * 256 + threadIdx.x;
    if (r >= M) return;
    float4 a = *(const float4*)(partial + ((size_t)0 * M + r) * 4);
    float4 b = *(const float4*)(partial + ((size_t)1 * M + r) * 4);
    float4 c = *(const float4*)(partial + ((size_t)2 * M + r) * 4);
    float4 d = *(const float4*)(partial + ((size_t)3 * M + r) * 4);
    float4 o;
    o.x = a.x + b.x + c.x + d.x + bo[0];
    o.y = a.y + b.y + c.y + d.y + bo[1];
    o.z = a.z + b.z + c.z + d.z + bo[2];
    o.w = a.w + b.w + c.w + d.w + bo[3];
    *(float4*)(out + (size_t)r * 4) = o;
}

extern "C" void kernel_launch(void* const* d_in, const int* in_sizes, int n_in,
                              void* d_out, int out_size, void* d_ws, size_t ws_size,
                              hipStream_t stream) {
    const float* x    = (const float*)d_in[0];
    const int*   eidx = (const int*)d_in[1];
    const float* cW   = (const float*)d_in[2];
    const float* caS  = (const float*)d_in[3];
    const float* caD  = (const float*)d_in[4];
    const float* cB   = (const float*)d_in[5];
    const float* W0   = (const float*)d_in[6];
    const float* b0   = (const float*)d_in[7];
    const float* W1   = (const float*)d_in[8];
    const float* b1   = (const float*)d_in[9];
    const float* W2   = (const float*)d_in[10];
    const float* b2   = (const float*)d_in[11];
    const float* Wo   = (const float*)d_in[12];
    const float* bo   = (const float*)d_in[13];
    (void)in_sizes; (void)n_in; (void)out_size;

    const int* esrc = eidx;
    const int* edst = eidx + NE;
    float* out = (float*)d_out;

    // ---- workspace bump allocator (256B aligned) ----
    char* w = (char*)d_ws;
    auto alloc = [&](size_t bytes) -> char* {
        char* p = w;
        w += (bytes + 255) & ~(size_t)255;
        return p;
    };
    _Float16* x0h  = (_Float16*)alloc((size_t)NN * 128 * 2);
    _Float16* x0l  = (_Float16*)alloc((size_t)NN * 128 * 2);
    _Float16* xh   = (_Float16*)alloc((size_t)NN * 128 * 2);
    _Float16* xl   = (_Float16*)alloc((size_t)NN * 128 * 2);
    _Float16* hbuf = (_Float16*)alloc((size_t)NN * 128 * 2);   // f16 (R17)
    float* ssrc    = (float*)alloc((size_t)NN * 4);
    float* sdst    = (float*)alloc((size_t)NN * 4);
    int*   counts  = (int*)  alloc((size_t)NN * 4);
    int*   offs    = (int*)  alloc((size_t)(NN + 1) * 4);
    int*   cursor  = (int*)  alloc((size_t)NN * 4);
    int*   csr     = (int*)  alloc((size_t)NET * 4);
    int*   part    = (int*)  alloc((size_t)SCAN_NB * 4);
    _Float16* cwh  = (_Float16*)alloc(3 * 128 * 128 * 2);
    _Float16* cwl  = (_Float16*)alloc(3 * 128 * 128 * 2);
    _Float16* w0h  = (_Float16*)alloc(512 * 128 * 2);
    _Float16* w0l  = (_Float16*)alloc(512 * 128 * 2);
    _Float16* w1h  = (_Float16*)alloc(512 * 512 * 2);
    _Float16* w1l  = (_Float16*)alloc(512 * 512 * 2);
    _Float16* w2h  = (_Float16*)alloc(512 * 512 * 2);
    _Float16* w2l  = (_Float16*)alloc(512 * 512 * 2);
    float* hpart   = (float*)alloc((size_t)4 * NN * 4 * 4);   // head partials [4][NN][4]

    size_t used = (size_t)(w - (char*)d_ws);
    size_t rem = (ws_size > used) ? (ws_size - used) : 0;
    int chunk = (int)(rem / (4 * 512 * sizeof(_Float16)));
    if (chunk > NN) chunk = NN;
    if (chunk > 128) chunk &= ~127;
    if (chunk < 1) chunk = 1;
    _Float16* Y0h = (_Float16*)alloc((size_t)chunk * 512 * 2);
    _Float16* Y0l = (_Float16*)alloc((size_t)chunk * 512 * 2);
    _Float16* Y1h = (_Float16*)alloc((size_t)chunk * 512 * 2);
    _Float16* Y1l = (_Float16*)alloc((size_t)chunk * 512 * 2);

    auto gemm = [&](const _Float16* Ah, const _Float16* Al,
                    const _Float16* Bh, const _Float16* Bl,
                    const float* bias, float* Cf, _Float16* Ch, _Float16* Cl,
                    int M, int N, int K, int relu, int split) {
        int nx = N / 128;
        int ntiles = nx * ((M + 127) / 128);
        int nb = ((ntiles + 7) / 8) * 8;
        k_mgemm<<<nb, 512, 0, stream>>>(Ah, Al, Bh, Bl, bias, Cf, Ch, Cl,
                                        M, N, K, relu, split, nx, ntiles);
    };

    // ---- prep: split x, transpose+split weights ----
    k_split<<<2048, 256, 0, stream>>>(x, x0h, x0l, NN * 128);
    for (int L = 0; L < 3; ++L)
        k_prepw<<<dim3(128 / 32, 128 / 32), 256, 0, stream>>>(
            cW + (size_t)L * 128 * 128, cwh + (size_t)L * 128 * 128, cwl + (size_t)L * 128 * 128, 128, 128);
    k_prepw<<<dim3(512 / 32, 128 / 32), 256, 0, stream>>>(W0, w0h, w0l, 128, 512);
    k_prepw<<<dim3(512 / 32, 512 / 32), 256, 0, stream>>>(W1, w1h, w1l, 512, 512);
    k_prepw<<<dim3(512 / 32, 512 / 32), 256, 0, stream>>>(W2, w2h, w2l, 512, 512);

    // ---- build CSR once ----
    hipMemsetAsync(counts, 0, (size_t)NN * 4, stream);
    int eblocks = (NET + 255) / 256;
    k_count <<<eblocks, 256, 0, stream>>>(edst, counts);
    k_scan1 <<<SCAN_NB, 256, 0, stream>>>(counts, part);
    k_scan2 <<<1, 256, 0, stream>>>(part, offs);
    k_scan3 <<<SCAN_NB, 256, 0, stream>>>(counts, part, offs, cursor);
    k_scatter<<<eblocks, 256, 0, stream>>>(esrc, edst, cursor, csr);

    // ---- 3 GAT layers (GEMM fused with attention scalars) ----
    int gat_tiles = (NN + 127) / 128;
    int gat_nb = ((gat_tiles + 7) / 8) * 8;
    for (int L = 0; L < 3; ++L) {
        const _Float16* Ah = (L == 0) ? x0h : xh;
        const _Float16* Al = (L == 0) ? x0l : xl;
        k_mgemm_gat<<<gat_nb, 256, 0, stream>>>(
            Ah, Al, cwh + (size_t)L * 128 * 128, cwl + (size_t)L * 128 * 128,
            caS + L * 128, caD + L * 128, hbuf, ssrc, sdst, NN, gat_tiles);
        k_aggregate<<<NN / 4, 256, 0, stream>>>(hbuf, ssrc, sdst, offs, csr, cB + L * 128, xh, xl);
    }

    // ---- MLP head (chunked over nodes; gemm2 fused with output head) ----
    for (int m0 = 0; m0 < NN; m0 += chunk) {
        int cm = imin(chunk, NN - m0);
        gemm(xh + (size_t)m0 * 128, xl + (size_t)m0 * 128, w0h, w0l, b0,
             nullptr, Y0h, Y0l, cm, 512, 128, 1, 1);
        gemm(Y0h, Y0l, w1h, w1l, b1, nullptr, Y1h, Y1l, cm, 512, 512, 1, 1);
        int nx = 4;
        int ntiles = nx * ((cm + 127) / 128);
        int nb = ((ntiles + 7) / 8) * 8;
        k_mgemm_head<<<nb, 256, 0, stream>>>(Y1h, Y1l, w2h, w2l, b2, Wo,
                                             hpart, cm, 512, nx, ntiles);
        k_headred<<<(cm + 255) / 256, 256, 0, stream>>>(hpart, bo, out + (size_t)m0 * 4, cm);
    }
}